// Round 4
// baseline (636.450 us; speedup 1.0000x reference)
//
#include <hip/hip_runtime.h>
#include <hip/hip_fp16.h>
#include <math.h>

#define DEVINL __device__ __forceinline__

// ---------------------------------------------------------------------------
// SplineCNN net, round 3: 27-dispatch pipeline.
//  - pooling via monotone-u32 atomicMax; consumers decode in place (no finalize)
//  - one upfront fill + batched hist/scan prep for all levels
//  - per level: counting-sort entries by kernel idx (for W reuse in LDS GEMM)
//    AND by dst (entperm) so aggregation is a contiguous, atomic-free gather
//  - msgs in fp16, Cout-sliced so every level is single-chunk in ~23MB scratch
//  - aggregation fused with degree-norm + root + bias + ELU
// ---------------------------------------------------------------------------

DEVINL unsigned f2mono(float f) {
    unsigned u = __float_as_uint(f);
    return (u & 0x80000000u) ? ~u : (u | 0x80000000u);
}
DEVINL float mono2x(unsigned m) {  // sentinel 0 == empty segment -> 0.0
    if (m == 0u) return 0.f;
    unsigned u = (m & 0x80000000u) ? (m & 0x7FFFFFFFu) : ~m;
    return __uint_as_float(u);
}
DEVINL unsigned short f2h(float f) {
    union { __half h; unsigned short u; } c;
    c.h = __float2half_rn(f);
    return c.u;
}
DEVINL float h2f(unsigned short s) {
    union { unsigned short u; __half h; } c;
    c.u = s;
    return __half2float(c.h);
}

__global__ void fill_u32(unsigned* __restrict__ p, int n, unsigned v) {
    int i = blockIdx.x * blockDim.x + threadIdx.x;
    if (i < n) p[i] = v;
}

__global__ void pool_scatter(const float* __restrict__ x, const int* __restrict__ cl,
                             unsigned* __restrict__ mono, int n_in, int C) {
    int i = blockIdx.x * blockDim.x + threadIdx.x;
    if (i >= n_in * C) return;
    int node = i / C;
    int c = i - node * C;
    atomicMax(&mono[cl[node] * C + c], f2mono(x[i]));
}

DEVINL void pseudo_decode(const float* __restrict__ ps, int e, int ff[3], float fr[3]) {
#pragma unroll
    for (int d = 0; d < 3; ++d) {
        float p = ps[(size_t)e * 3 + d] * 4.0f;  // (K-1) = 4
        float f = floorf(p);
        ff[d] = (int)f;
        fr[d] = p - f;
    }
}

DEVINL void corner_iw(const int ff[3], const float fr[3], int bits, float& w, int& idx) {
    w = 1.f;
    idx = 0;
    int pw = 1;
#pragma unroll
    for (int d = 0; d < 3; ++d) {
        int b = (bits >> d) & 1;
        w *= b ? fr[d] : (1.f - fr[d]);
        int fd = ff[d] + b;
        fd = fd < 0 ? 0 : (fd > 4 ? 4 : fd);
        idx += fd * pw;
        pw *= 5;
    }
}

// ---------------- batched hist (levels 2-5) + degree (all levels) -------------
DEVINL void hist_seg(const float* __restrict__ ps, const int* __restrict__ dst, int E,
                     int* __restrict__ hist, int* __restrict__ ideg, int bofs, int t,
                     int* __restrict__ lh) {
    for (int i = t; i < 125; i += 256) lh[i] = 0;
    __syncthreads();
    int e = bofs * 256 + t;
    if (e < E) {
        int ff[3];
        float fr[3];
        pseudo_decode(ps, e, ff, fr);
#pragma unroll
        for (int b = 0; b < 8; ++b) {
            float w;
            int k;
            corner_iw(ff, fr, b, w, k);
            atomicAdd(&lh[k], 1);
        }
        atomicAdd(&ideg[dst[e]], 1);
    }
    __syncthreads();
    for (int i = t; i < 125; i += 256)
        if (lh[i]) atomicAdd(&hist[i], lh[i]);
}

__global__ void hist_all(const float* ps2, const int* dst2, int E2, int* hist2, int* ideg2,
                         const float* ps3, const int* dst3, int E3, int* hist3, int* ideg3,
                         const float* ps4, const int* dst4, int E4, int* hist4, int* ideg4,
                         const float* ps5, const int* dst5, int E5, int* hist5, int* ideg5,
                         const int* dst1, int E1, int* ideg1, int B2, int B23, int B234,
                         int B2345) {
    __shared__ int lh[125];
    int b = blockIdx.x, t = threadIdx.x;
    if (b < B2) hist_seg(ps2, dst2, E2, hist2, ideg2, b, t, lh);
    else if (b < B23) hist_seg(ps3, dst3, E3, hist3, ideg3, b - B2, t, lh);
    else if (b < B234) hist_seg(ps4, dst4, E4, hist4, ideg4, b - B23, t, lh);
    else if (b < B2345) hist_seg(ps5, dst5, E5, hist5, ideg5, b - B234, t, lh);
    else {
        int e = (b - B2345) * 256 + t;
        if (e < E1) atomicAdd(&ideg1[dst1[e]], 1);
    }
}

// ---------------- batched prefix/scan prep -----------------------------------
// blocks 0-3: bin prefix + tile lists (levels 2-5); blocks 4-8: node scans L1-L5
__global__ void prep_all(const int* h2, int* bs2, int* cu2, int* tk2, int* tl2, int* nt2,
                         const int* h3, int* bs3, int* cu3, int* tk3, int* tl3, int* nt3,
                         const int* h4, int* bs4, int* cu4, int* tk4, int* tl4, int* nt4,
                         const int* h5, int* bs5, int* cu5, int* tk5, int* tl5, int* nt5,
                         const int* ideg1, int N1, int* erow1, int* ecur1, const int* ideg2,
                         int N2, int* erow2, int* entc2, const int* ideg3, int N3, int* erow3,
                         int* entc3, const int* ideg4, int N4, int* erow4, int* entc4,
                         const int* ideg5, int N5, int* erow5, int* entc5) {
    __shared__ int sA[126], sB[126];
    __shared__ int part[256];
    int b = blockIdx.x, t = threadIdx.x;
    if (b < 4) {
        const int* hist;
        int *bs, *cu, *tk, *tl, *ntp;
        if (b == 0) { hist = h2; bs = bs2; cu = cu2; tk = tk2; tl = tl2; ntp = nt2; }
        else if (b == 1) { hist = h3; bs = bs3; cu = cu3; tk = tk3; tl = tl3; ntp = nt3; }
        else if (b == 2) { hist = h4; bs = bs4; cu = cu4; tk = tk4; tl = tl4; ntp = nt4; }
        else { hist = h5; bs = bs5; cu = cu5; tk = tk5; tl = tl5; ntp = nt5; }
        if (t == 0) {
            int run = 0, trun = 0;
            for (int k = 0; k < 125; ++k) {
                sA[k] = run;
                sB[k] = trun;
                run += hist[k];
                trun += (hist[k] + 63) / 64;
            }
            sA[125] = run;
            sB[125] = trun;
            *ntp = trun;
        }
        __syncthreads();
        if (t < 126) bs[t] = sA[t];
        if (t < 125) {
            cu[t] = sA[t];
            int nt = sB[t + 1] - sB[t];
            for (int j = 0; j < nt; ++j) {
                tk[sB[t] + j] = t;
                tl[sB[t] + j] = sA[t] + 64 * j;
            }
        }
    } else {
        const int* cnt;
        int N, mult;
        int *row, *cur;
        int s = b - 4;
        if (s == 0) { cnt = ideg1; N = N1; row = erow1; cur = ecur1; mult = 1; }
        else if (s == 1) { cnt = ideg2; N = N2; row = erow2; cur = entc2; mult = 8; }
        else if (s == 2) { cnt = ideg3; N = N3; row = erow3; cur = entc3; mult = 8; }
        else if (s == 3) { cnt = ideg4; N = N4; row = erow4; cur = entc4; mult = 8; }
        else { cnt = ideg5; N = N5; row = erow5; cur = entc5; mult = 8; }
        int chunk = (N + 255) / 256;
        int lo = t * chunk, hi = min(lo + chunk, N);
        int sum = 0;
        for (int i = lo; i < hi; ++i) sum += cnt[i];
        part[t] = sum;
        __syncthreads();
        if (t == 0) {
            int run = 0;
            for (int i = 0; i < 256; ++i) {
                int v = part[i];
                part[i] = run;
                run += v;
            }
            row[N] = run;
        }
        __syncthreads();
        int run = part[t];
        for (int i = lo; i < hi; ++i) {
            row[i] = run;
            cur[i] = mult * run;
            run += cnt[i];
        }
    }
}

// counting-sort edges by dst (level 1)
__global__ void scatter_dst(const int* __restrict__ dst, int E, int* __restrict__ ecur,
                            int* __restrict__ eperm) {
    int e = blockIdx.x * blockDim.x + threadIdx.x;
    if (e < E) eperm[atomicAdd(&ecur[dst[e]], 1)] = e;
}

// per-level entry scatter: k-sorted position (cursor) + dst-sorted perm (entcur)
__global__ void scatter_lvl(const float* __restrict__ ps, const int* __restrict__ src,
                            const int* __restrict__ dst, int E, int* __restrict__ cursor,
                            int* __restrict__ entcur, unsigned* __restrict__ spack,
                            int* __restrict__ entperm) {
    __shared__ int lh[125], lbase[125];
    int t = threadIdx.x;
    for (int i = t; i < 125; i += 256) lh[i] = 0;
    __syncthreads();
    int e = blockIdx.x * 256 + t;
    int mk[8], ml[8];
    float mw[8];
    if (e < E) {
        int ff[3];
        float fr[3];
        pseudo_decode(ps, e, ff, fr);
#pragma unroll
        for (int b = 0; b < 8; ++b) {
            corner_iw(ff, fr, b, mw[b], mk[b]);
            ml[b] = atomicAdd(&lh[mk[b]], 1);
        }
    }
    __syncthreads();
    for (int i = t; i < 125; i += 256) {
        int c = lh[i];
        lbase[i] = c ? atomicAdd(&cursor[i], c) : 0;
    }
    __syncthreads();
    if (e < E) {
        int s = src[e];
        int qbase = atomicAdd(&entcur[dst[e]], 8);
#pragma unroll
        for (int b = 0; b < 8; ++b) {
            int p = lbase[mk[b]] + ml[b];
            spack[p] = ((unsigned)s << 16) | (unsigned)f2h(mw[b]);
            entperm[qbase + b] = p;
        }
    }
}

// k-binned GEMM: W[k] Cout-slice in LDS (reused 64x), w-scaled x rows in LDS,
// fp16 msgs row per entry at its k-sorted position.
template <int CIN, int COUT, int S>
__global__ __launch_bounds__(256) void bin_gemm(
    const unsigned* __restrict__ xm, const float* __restrict__ W, int c0,
    const unsigned* __restrict__ spack, const int* __restrict__ tk, const int* __restrict__ tl,
    const int* __restrict__ bs, const int* __restrict__ ntp, unsigned* __restrict__ msgs) {
    constexpr int C4 = S / 4;
    constexpr int NTR = 256 / C4;
    constexpr int RT = 64 / NTR;
    constexpr int XST = CIN + 4;
    __shared__ float Wl[CIN * S];
    __shared__ float xs[64 * XST];
    int t = threadIdx.x;
    int ntiles = *ntp;
    int tc = t % C4, tr = t / C4;
    int rr = t >> 2, g = t & 3;
    for (int tile = blockIdx.x; tile < ntiles; tile += gridDim.x) {
        int k = tk[tile], lo = tl[tile];
        int m = min(64, bs[k + 1] - lo);
        __syncthreads();
        float4* Wl4 = (float4*)Wl;
        const float* Wk = W + (size_t)k * CIN * COUT + c0;
        for (int i4 = t; i4 < CIN * C4; i4 += 256) {
            int row = i4 / C4, cg = i4 % C4;
            Wl4[i4] = ((const float4*)(Wk + (size_t)row * COUT))[cg];
        }
        if (rr < m) {
            unsigned sp = spack[lo + rr];
            int s = sp >> 16;
            float wv = h2f((unsigned short)(sp & 0xFFFFu));
            const uint4* xr = (const uint4*)(xm + (size_t)s * CIN);
            float4* xd = (float4*)(xs + rr * XST);
#pragma unroll
            for (int i = g; i < CIN / 4; i += 4) {
                uint4 mv = xr[i];
                float4 v;
                v.x = mono2x(mv.x) * wv;
                v.y = mono2x(mv.y) * wv;
                v.z = mono2x(mv.z) * wv;
                v.w = mono2x(mv.w) * wv;
                xd[i] = v;
            }
        }
        __syncthreads();
        float4 acc[RT];
#pragma unroll
        for (int r = 0; r < RT; ++r) acc[r] = make_float4(0.f, 0.f, 0.f, 0.f);
#pragma unroll 4
        for (int i = 0; i < CIN; ++i) {
            float4 wv = Wl4[i * C4 + tc];
#pragma unroll
            for (int r = 0; r < RT; ++r) {
                float xv = xs[(tr + r * NTR) * XST + i];
                acc[r].x += xv * wv.x;
                acc[r].y += xv * wv.y;
                acc[r].z += xv * wv.z;
                acc[r].w += xv * wv.w;
            }
        }
#pragma unroll
        for (int r = 0; r < RT; ++r) {
            int row = tr + r * NTR;
            if (row < m) {
                uint2 pv;
                pv.x = (unsigned)f2h(acc[r].x) | ((unsigned)f2h(acc[r].y) << 16);
                pv.y = (unsigned)f2h(acc[r].z) | ((unsigned)f2h(acc[r].w) << 16);
                ((uint2*)(msgs + (size_t)(lo + row) * (S / 2)))[tc] = pv;
            }
        }
    }
}

// wave per node: contiguous dst-sorted gather of msgs + deg-norm + root + bias + ELU
template <int CIN, int COUT, int S>
__global__ __launch_bounds__(256) void agg_finish(
    const unsigned* __restrict__ msgsU, const int* __restrict__ entperm,
    const int* __restrict__ erow, const unsigned* __restrict__ xm, const float* __restrict__ root,
    const float* __restrict__ bias, float* __restrict__ y, int N, int c0) {
    const unsigned short* msgs = (const unsigned short*)msgsU;
    constexpr int EP = (S < 64) ? (64 / S) : 1;
    constexpr int CPL = (S > 64) ? (S / 64) : 1;
    int t = threadIdx.x;
    int lane = t & 63;
    int wid = blockIdx.x * 4 + (t >> 6);
    int nw = gridDim.x * 4;
    int sub = (S < 64) ? (lane / S) : 0;
    int col = (S < 64) ? (lane % S) : lane;
    for (int d = wid; d < N; d += nw) {
        int lo8 = 8 * erow[d], hi8 = 8 * erow[d + 1];
        float acc[CPL];
#pragma unroll
        for (int cp = 0; cp < CPL; ++cp) acc[cp] = 0.f;
        for (int q = lo8 + sub; q < hi8; q += EP) {
            int p = entperm[q];
            const unsigned short* mr = msgs + (size_t)p * S;
            if (CPL == 1) acc[0] += h2f(mr[col]);
            else {
                acc[0] += h2f(mr[lane]);
                acc[1] += h2f(mr[lane + 64]);
            }
        }
        if (S == 16) {
            acc[0] += __shfl_down(acc[0], 32);
            acc[0] += __shfl_down(acc[0], 16);
        } else if (S == 32) {
            acc[0] += __shfl_down(acc[0], 32);
        }
        bool writer = (S < 64) ? (lane < S) : true;
        if (writer) {
            float dv = (float)max((hi8 - lo8) >> 3, 1);
#pragma unroll
            for (int cp = 0; cp < CPL; ++cp) {
                int c = c0 + col + cp * 64;
                float v = acc[cp] / dv;
                for (int i = 0; i < CIN; ++i)
                    v += mono2x(xm[(size_t)d * CIN + i]) * root[(size_t)i * COUT + c];
                v += bias[c];
                y[(size_t)d * COUT + c] = v > 0.f ? v : expm1f(v);
            }
        }
    }
}

// ---------------- level 1 (Cin=1, Cout=32): CSR + W1 in LDS, fully fused ------
__global__ __launch_bounds__(256) void l1_aggregate(
    const unsigned* __restrict__ xm, const float* __restrict__ ps, const int* __restrict__ src,
    const float* __restrict__ W, const int* __restrict__ erow, const int* __restrict__ eperm,
    const float* __restrict__ root, const float* __restrict__ bias, float* __restrict__ y,
    int N) {
    __shared__ float Wl[125 * 32];
    int t = threadIdx.x;
    {
        const float4* Wg = (const float4*)W;
        float4* Wd = (float4*)Wl;
        for (int i = t; i < 125 * 32 / 4; i += 256) Wd[i] = Wg[i];
    }
    __syncthreads();
    int lane = t & 63, c = lane & 31, half = lane >> 5;
    int wid = blockIdx.x * 4 + (t >> 6);
    int nw = gridDim.x * 4;
    for (int d = wid; d < N; d += nw) {
        int lo = erow[d], hi = erow[d + 1];
        float acc = 0.f;
        for (int j = lo + half; j < hi; j += 2) {
            int e = eperm[j];
            int ff[3];
            float fr[3];
            pseudo_decode(ps, e, ff, fr);
            float wsum = 0.f;
#pragma unroll
            for (int b = 0; b < 8; ++b) {
                float w;
                int idx;
                corner_iw(ff, fr, b, w, idx);
                wsum += w * Wl[idx * 32 + c];
            }
            acc += mono2x(xm[src[e]]) * wsum;
        }
        acc += __shfl_down(acc, 32);
        if (half == 0) {
            float dv = (float)max(hi - lo, 1);
            float v = acc / dv + mono2x(xm[d]) * root[c] + bias[c];
            y[(size_t)d * 32 + c] = v > 0.f ? v : expm1f(v);
        }
    }
}

// fc1: [1024] @ [1024,512] + b, ELU — K-split across 8 blocks x 256 threads
__global__ __launch_bounds__(256) void fc1_kernel(const unsigned* __restrict__ xm,
                                                  const float* __restrict__ w,
                                                  const float* __restrict__ b,
                                                  float* __restrict__ out) {
    __shared__ float xsh[1024];
    __shared__ float sh[4][64];
    int t = threadIdx.x;
    for (int i = t; i < 1024; i += 256) xsh[i] = mono2x(xm[i]);
    __syncthreads();
    int ol = t & 63, kk = t >> 6;
    int o = blockIdx.x * 64 + ol;
    int i0 = kk * 256;
    float acc = 0.f;
#pragma unroll 8
    for (int i = 0; i < 256; ++i) acc += xsh[i0 + i] * w[(size_t)(i0 + i) * 512 + o];
    sh[kk][ol] = acc;
    __syncthreads();
    if (kk == 0) {
        float v = sh[0][ol] + sh[1][ol] + sh[2][ol] + sh[3][ol] + b[o];
        out[o] = v > 0.f ? v : expm1f(v);
    }
}

__global__ void fc2_lsm(const float* __restrict__ x, const float* __restrict__ w,
                        const float* __restrict__ b, float* __restrict__ out) {
    __shared__ float z[10];
    int t = threadIdx.x;
    if (t < 10) {
        float acc = b[t];
        for (int i = 0; i < 512; ++i) acc += x[i] * w[(size_t)i * 10 + t];
        z[t] = acc;
    }
    __syncthreads();
    if (t == 0) {
        float m = z[0];
        for (int i = 1; i < 10; ++i) m = fmaxf(m, z[i]);
        float s = 0.f;
        for (int i = 0; i < 10; ++i) s += expf(z[i] - m);
        float l = logf(s);
        for (int i = 0; i < 10; ++i) out[i] = z[i] - m - l;
    }
}

// ---------------------------------------------------------------------------

extern "C" void kernel_launch(void* const* d_in, const int* in_sizes, int n_in,
                              void* d_out, int out_size, void* d_ws, size_t ws_size,
                              hipStream_t stream) {
    const float* x0 = (const float*)d_in[0];
    const int* cl[6];
    for (int i = 0; i < 6; ++i) cl[i] = (const int*)d_in[1 + i];
    const int* src[5];
    const int* dst[5];
    const float* ps[5];
    const float* W[5];
    const float* root[5];
    const float* bias[5];
    for (int i = 0; i < 5; ++i) {
        src[i] = (const int*)d_in[7 + 6 * i];
        dst[i] = (const int*)d_in[8 + 6 * i];
        ps[i] = (const float*)d_in[9 + 6 * i];
        W[i] = (const float*)d_in[10 + 6 * i];
        root[i] = (const float*)d_in[11 + 6 * i];
        bias[i] = (const float*)d_in[12 + 6 * i];
    }
    const float* fc1_w = (const float*)d_in[37];
    const float* fc1_b = (const float*)d_in[38];
    const float* fc2_w = (const float*)d_in[39];
    const float* fc2_b = (const float*)d_in[40];

    const int N1 = 20000, N2 = 6000, N3 = 2000, N4 = 700, N5 = 256;
    const int E1 = 160000, E2 = 48000, E3 = 16000, E4 = 5600, E5 = 2048;
    const int UB2 = E2 * 8 / 64 + 126, UB3 = E3 * 8 / 64 + 126;
    const int UB4 = E4 * 8 / 64 + 126, UB5 = E5 * 8 / 64 + 126;

    unsigned* base = (unsigned*)d_ws;
    size_t o = 0;
    auto alloc = [&](size_t n) { unsigned* p = base + o; o += n; return p; };
    // ---- zero block (single fill) ----
    unsigned* xp1m = alloc(N1);
    unsigned* xp2m = alloc((size_t)N2 * 32);
    unsigned* xp3m = alloc((size_t)N3 * 64);
    unsigned* xp4m = alloc((size_t)N4 * 64);
    unsigned* xp5m = alloc((size_t)N5 * 64);
    unsigned* xp6m = alloc(8 * 128);
    int* hist2 = (int*)alloc(125);
    int* hist3 = (int*)alloc(125);
    int* hist4 = (int*)alloc(125);
    int* hist5 = (int*)alloc(125);
    int* ideg1 = (int*)alloc(N1);
    int* ideg2 = (int*)alloc(N2);
    int* ideg3 = (int*)alloc(N3);
    int* ideg4 = (int*)alloc(N4);
    int* ideg5 = (int*)alloc(N5);
    size_t zero_words = o;
    // ---- non-zeroed dedicated ----
    int* erow1 = (int*)alloc(N1 + 1);
    int* erow2 = (int*)alloc(N2 + 1);
    int* erow3 = (int*)alloc(N3 + 1);
    int* erow4 = (int*)alloc(N4 + 1);
    int* erow5 = (int*)alloc(N5 + 1);
    int* ecur1 = (int*)alloc(N1);
    int* entc2 = (int*)alloc(N2);
    int* entc3 = (int*)alloc(N3);
    int* entc4 = (int*)alloc(N4);
    int* entc5 = (int*)alloc(N5);
    int* bs2 = (int*)alloc(126);
    int* bs3 = (int*)alloc(126);
    int* bs4 = (int*)alloc(126);
    int* bs5 = (int*)alloc(126);
    int* cu2 = (int*)alloc(125);
    int* cu3 = (int*)alloc(125);
    int* cu4 = (int*)alloc(125);
    int* cu5 = (int*)alloc(125);
    int* nt2 = (int*)alloc(1);
    int* nt3 = (int*)alloc(1);
    int* nt4 = (int*)alloc(1);
    int* nt5 = (int*)alloc(1);
    int* tk2 = (int*)alloc(UB2);
    int* tl2 = (int*)alloc(UB2);
    int* tk3 = (int*)alloc(UB3);
    int* tl3 = (int*)alloc(UB3);
    int* tk4 = (int*)alloc(UB4);
    int* tl4 = (int*)alloc(UB4);
    int* tk5 = (int*)alloc(UB5);
    int* tl5 = (int*)alloc(UB5);
    int* eperm1 = (int*)alloc(E1);
    float* y1 = (float*)alloc((size_t)N1 * 32);
    float* y2 = (float*)alloc((size_t)N2 * 64);
    float* y3 = (float*)alloc((size_t)N3 * 64);
    float* y4 = (float*)alloc((size_t)N4 * 64);
    float* y5 = (float*)alloc((size_t)N5 * 128);
    float* fc1o = (float*)alloc(512);
    unsigned* arena = base + o;

    // ---- 1. one fill for monos + hists + idegs ----
    fill_u32<<<((int)zero_words + 255) / 256, 256, 0, stream>>>(base, (int)zero_words, 0u);

    // ---- 2. batched hist/deg ----
    int nb2 = (E2 + 255) / 256, nb3 = (E3 + 255) / 256, nb4 = (E4 + 255) / 256,
        nb5 = (E5 + 255) / 256, nb1 = (E1 + 255) / 256;
    int B2 = nb2, B23 = B2 + nb3, B234 = B23 + nb4, B2345 = B234 + nb5;
    hist_all<<<B2345 + nb1, 256, 0, stream>>>(ps[1], dst[1], E2, hist2, ideg2, ps[2], dst[2], E3,
                                              hist3, ideg3, ps[3], dst[3], E4, hist4, ideg4,
                                              ps[4], dst[4], E5, hist5, ideg5, dst[0], E1, ideg1,
                                              B2, B23, B234, B2345);

    // ---- 3. batched prefix/scan ----
    prep_all<<<9, 256, 0, stream>>>(hist2, bs2, cu2, tk2, tl2, nt2, hist3, bs3, cu3, tk3, tl3,
                                    nt3, hist4, bs4, cu4, tk4, tl4, nt4, hist5, bs5, cu5, tk5,
                                    tl5, nt5, ideg1, N1, erow1, ecur1, ideg2, N2, erow2, entc2,
                                    ideg3, N3, erow3, entc3, ideg4, N4, erow4, entc4, ideg5, N5,
                                    erow5, entc5);

    // ---- level 1 ----
    pool_scatter<<<(80000 + 255) / 256, 256, 0, stream>>>(x0, cl[0], xp1m, 80000, 1);
    scatter_dst<<<nb1, 256, 0, stream>>>(dst[0], E1, ecur1, eperm1);
    l1_aggregate<<<2048, 256, 0, stream>>>(xp1m, ps[0], src[0], W[0], erow1, eperm1, root[0],
                                           bias[0], y1, N1);

    // ---- generic level driver ----
    auto run_level = [&](auto cinT, auto coutT, auto sT, const float* yin, int n_yin, int Cprev,
                         const int* clp, unsigned* xpm, const float* psl, const int* srcl,
                         const int* dstl, const float* Wl, const float* rootl, const float* biasl,
                         float* yout, int N, int E, int* cur, int* entc, int* tkl, int* tll,
                         int* bsl, int* ntl, int ub) {
        constexpr int CIN = decltype(cinT)::value;
        constexpr int COUT = decltype(coutT)::value;
        constexpr int S = decltype(sT)::value;
        pool_scatter<<<(n_yin * Cprev + 255) / 256, 256, 0, stream>>>(yin, clp, xpm, n_yin,
                                                                      Cprev);
        unsigned* spack = arena;
        int* entperm = (int*)(arena + (size_t)8 * E);
        unsigned* msgs = arena + (size_t)16 * E;  // fp16 rows: 8E * S/2 u32 words
        scatter_lvl<<<(E + 255) / 256, 256, 0, stream>>>(psl, srcl, dstl, E, cur, entc, spack,
                                                         entperm);
        int grid = ub < 2048 ? ub : 2048;
        int agrid = (N + 3) / 4;
        for (int s = 0; s < COUT / S; ++s) {
            bin_gemm<CIN, COUT, S><<<grid, 256, 0, stream>>>(xpm, Wl, s * S, spack, tkl, tll, bsl,
                                                             ntl, msgs);
            agg_finish<CIN, COUT, S><<<agrid, 256, 0, stream>>>(msgs, entperm, erow2 == nullptr
                                                                                   ? nullptr
                                                                                   : nullptr,
                                                                nullptr, xpm, rootl, biasl, yout,
                                                                N, s * S);
        }
    };
    (void)run_level;  // (lambda template trick unused; explicit calls below)

    // ---- level 2: Cin32 Cout64, 4 x S=16 slices ----
    {
        pool_scatter<<<((size_t)N1 * 32 + 255) / 256, 256, 0, stream>>>(y1, cl[1], xp2m, N1, 32);
        unsigned* spack = arena;
        int* entperm = (int*)(arena + (size_t)8 * E2);
        unsigned* msgs = arena + (size_t)16 * E2;
        scatter_lvl<<<nb2, 256, 0, stream>>>(ps[1], src[1], dst[1], E2, cu2, entc2, spack,
                                             entperm);
        int grid = UB2 < 2048 ? UB2 : 2048;
        for (int s = 0; s < 4; ++s) {
            bin_gemm<32, 64, 16><<<grid, 256, 0, stream>>>(xp2m, W[1], s * 16, spack, tk2, tl2,
                                                           bs2, nt2, msgs);
            agg_finish<32, 64, 16><<<(N2 + 3) / 4, 256, 0, stream>>>(msgs, entperm, erow2, xp2m,
                                                                     root[1], bias[1], y2, N2,
                                                                     s * 16);
        }
    }
    // ---- level 3: Cin64 Cout64, 2 x S=32 slices ----
    {
        pool_scatter<<<((size_t)N2 * 64 + 255) / 256, 256, 0, stream>>>(y2, cl[2], xp3m, N2, 64);
        unsigned* spack = arena;
        int* entperm = (int*)(arena + (size_t)8 * E3);
        unsigned* msgs = arena + (size_t)16 * E3;
        scatter_lvl<<<nb3, 256, 0, stream>>>(ps[2], src[2], dst[2], E3, cu3, entc3, spack,
                                             entperm);
        int grid = UB3 < 2048 ? UB3 : 2048;
        for (int s = 0; s < 2; ++s) {
            bin_gemm<64, 64, 32><<<grid, 256, 0, stream>>>(xp3m, W[2], s * 32, spack, tk3, tl3,
                                                           bs3, nt3, msgs);
            agg_finish<64, 64, 32><<<(N3 + 3) / 4, 256, 0, stream>>>(msgs, entperm, erow3, xp3m,
                                                                     root[2], bias[2], y3, N3,
                                                                     s * 32);
        }
    }
    // ---- level 4: Cin64 Cout64, single S=64 ----
    {
        pool_scatter<<<((size_t)N3 * 64 + 255) / 256, 256, 0, stream>>>(y3, cl[3], xp4m, N3, 64);
        unsigned* spack = arena;
        int* entperm = (int*)(arena + (size_t)8 * E4);
        unsigned* msgs = arena + (size_t)16 * E4;
        scatter_lvl<<<nb4, 256, 0, stream>>>(ps[3], src[3], dst[3], E4, cu4, entc4, spack,
                                             entperm);
        bin_gemm<64, 64, 64><<<UB4, 256, 0, stream>>>(xp4m, W[3], 0, spack, tk4, tl4, bs4, nt4,
                                                      msgs);
        agg_finish<64, 64, 64><<<(N4 + 3) / 4, 256, 0, stream>>>(msgs, entperm, erow4, xp4m,
                                                                 root[3], bias[3], y4, N4, 0);
    }
    // ---- level 5: Cin64 Cout128, single S=128 ----
    {
        pool_scatter<<<((size_t)N4 * 64 + 255) / 256, 256, 0, stream>>>(y4, cl[4], xp5m, N4, 64);
        unsigned* spack = arena;
        int* entperm = (int*)(arena + (size_t)8 * E5);
        unsigned* msgs = arena + (size_t)16 * E5;
        scatter_lvl<<<nb5, 256, 0, stream>>>(ps[4], src[4], dst[4], E5, cu5, entc5, spack,
                                             entperm);
        bin_gemm<64, 128, 128><<<UB5, 256, 0, stream>>>(xp5m, W[4], 0, spack, tk5, tl5, bs5, nt5,
                                                        msgs);
        agg_finish<64, 128, 128><<<(N5 + 3) / 4, 256, 0, stream>>>(msgs, entperm, erow5, xp5m,
                                                                   root[4], bias[4], y5, N5, 0);
    }
    // ---- final dense pool + FC head ----
    pool_scatter<<<((size_t)N5 * 128 + 255) / 256, 256, 0, stream>>>(y5, cl[5], xp6m, N5, 128);
    fc1_kernel<<<8, 256, 0, stream>>>(xp6m, fc1_w, fc1_b, fc1o);
    fc2_lsm<<<1, 64, 0, stream>>>(fc1o, fc2_w, fc2_b, (float*)d_out);
}

// Round 5
// 357.057 us; speedup vs baseline: 1.7825x; 1.7825x over previous
//
#include <hip/hip_runtime.h>
#include <hip/hip_fp16.h>
#include <math.h>

#define DEVINL __device__ __forceinline__

// ---------------------------------------------------------------------------
// SplineCNN net, round 4: write-side dst-ordering.
//  - bin_gemm scatter-WRITES message rows to dst-sorted positions (sq[p]);
//    aggregation reads each node's messages as a contiguous coalesced stream
//    (round 3's agg_finish was a latency-bound random 32B gather, ~350us).
//  - level 1: (pseudo,src) records materialized in dst-sorted order, so the
//    per-node loop streams 16B records instead of eperm->pseudo random hops.
//  - slice width S picked at host from the real ws_size.
// ---------------------------------------------------------------------------

DEVINL unsigned f2mono(float f) {
    unsigned u = __float_as_uint(f);
    return (u & 0x80000000u) ? ~u : (u | 0x80000000u);
}
DEVINL float mono2x(unsigned m) {  // sentinel 0 == empty segment -> 0.0
    if (m == 0u) return 0.f;
    unsigned u = (m & 0x80000000u) ? (m & 0x7FFFFFFFu) : ~m;
    return __uint_as_float(u);
}
DEVINL unsigned short f2h(float f) {
    union { __half h; unsigned short u; } c;
    c.h = __float2half_rn(f);
    return c.u;
}
DEVINL float h2f(unsigned short s) {
    union { unsigned short u; __half h; } c;
    c.u = s;
    return __half2float(c.h);
}

__global__ void fill_u32(unsigned* __restrict__ p, int n, unsigned v) {
    int i = blockIdx.x * blockDim.x + threadIdx.x;
    if (i < n) p[i] = v;
}

__global__ void pool_scatter(const float* __restrict__ x, const int* __restrict__ cl,
                             unsigned* __restrict__ mono, int n_in, int C) {
    int i = blockIdx.x * blockDim.x + threadIdx.x;
    if (i >= n_in * C) return;
    int node = i / C;
    int c = i - node * C;
    atomicMax(&mono[cl[node] * C + c], f2mono(x[i]));
}

DEVINL void decode3(float p0, float p1, float p2, int ff[3], float fr[3]) {
    float pp[3] = {p0 * 4.f, p1 * 4.f, p2 * 4.f};  // (K-1) = 4
#pragma unroll
    for (int d = 0; d < 3; ++d) {
        float f = floorf(pp[d]);
        ff[d] = (int)f;
        fr[d] = pp[d] - f;
    }
}
DEVINL void pseudo_decode(const float* __restrict__ ps, int e, int ff[3], float fr[3]) {
    decode3(ps[(size_t)e * 3], ps[(size_t)e * 3 + 1], ps[(size_t)e * 3 + 2], ff, fr);
}

DEVINL void corner_iw(const int ff[3], const float fr[3], int bits, float& w, int& idx) {
    w = 1.f;
    idx = 0;
    int pw = 1;
#pragma unroll
    for (int d = 0; d < 3; ++d) {
        int b = (bits >> d) & 1;
        w *= b ? fr[d] : (1.f - fr[d]);
        int fd = ff[d] + b;
        fd = fd < 0 ? 0 : (fd > 4 ? 4 : fd);
        idx += fd * pw;
        pw *= 5;
    }
}

// ---------------- batched hist (levels 2-5) + degree (all levels) -------------
DEVINL void hist_seg(const float* __restrict__ ps, const int* __restrict__ dst, int E,
                     int* __restrict__ hist, int* __restrict__ ideg, int bofs, int t,
                     int* __restrict__ lh) {
    for (int i = t; i < 125; i += 256) lh[i] = 0;
    __syncthreads();
    int e = bofs * 256 + t;
    if (e < E) {
        int ff[3];
        float fr[3];
        pseudo_decode(ps, e, ff, fr);
#pragma unroll
        for (int b = 0; b < 8; ++b) {
            float w;
            int k;
            corner_iw(ff, fr, b, w, k);
            atomicAdd(&lh[k], 1);
        }
        atomicAdd(&ideg[dst[e]], 1);
    }
    __syncthreads();
    for (int i = t; i < 125; i += 256)
        if (lh[i]) atomicAdd(&hist[i], lh[i]);
}

__global__ void hist_all(const float* ps2, const int* dst2, int E2, int* hist2, int* ideg2,
                         const float* ps3, const int* dst3, int E3, int* hist3, int* ideg3,
                         const float* ps4, const int* dst4, int E4, int* hist4, int* ideg4,
                         const float* ps5, const int* dst5, int E5, int* hist5, int* ideg5,
                         const int* dst1, int E1, int* ideg1, int B2, int B23, int B234,
                         int B2345) {
    __shared__ int lh[125];
    int b = blockIdx.x, t = threadIdx.x;
    if (b < B2) hist_seg(ps2, dst2, E2, hist2, ideg2, b, t, lh);
    else if (b < B23) hist_seg(ps3, dst3, E3, hist3, ideg3, b - B2, t, lh);
    else if (b < B234) hist_seg(ps4, dst4, E4, hist4, ideg4, b - B23, t, lh);
    else if (b < B2345) hist_seg(ps5, dst5, E5, hist5, ideg5, b - B234, t, lh);
    else {
        int e = (b - B2345) * 256 + t;
        if (e < E1) atomicAdd(&ideg1[dst1[e]], 1);
    }
}

// ---------------- batched prefix/scan prep -----------------------------------
// blocks 0-3: bin prefix + tile lists (levels 2-5); blocks 4-8: node scans L1-L5
__global__ void prep_all(const int* h2, int* bs2, int* cu2, int* tk2, int* tl2, int* nt2,
                         const int* h3, int* bs3, int* cu3, int* tk3, int* tl3, int* nt3,
                         const int* h4, int* bs4, int* cu4, int* tk4, int* tl4, int* nt4,
                         const int* h5, int* bs5, int* cu5, int* tk5, int* tl5, int* nt5,
                         const int* ideg1, int N1, int* erow1, int* ecur1, const int* ideg2,
                         int N2, int* erow2, int* entc2, const int* ideg3, int N3, int* erow3,
                         int* entc3, const int* ideg4, int N4, int* erow4, int* entc4,
                         const int* ideg5, int N5, int* erow5, int* entc5) {
    __shared__ int sA[126], sB[126];
    __shared__ int part[256];
    int b = blockIdx.x, t = threadIdx.x;
    if (b < 4) {
        const int* hist;
        int *bs, *cu, *tk, *tl, *ntp;
        if (b == 0) { hist = h2; bs = bs2; cu = cu2; tk = tk2; tl = tl2; ntp = nt2; }
        else if (b == 1) { hist = h3; bs = bs3; cu = cu3; tk = tk3; tl = tl3; ntp = nt3; }
        else if (b == 2) { hist = h4; bs = bs4; cu = cu4; tk = tk4; tl = tl4; ntp = nt4; }
        else { hist = h5; bs = bs5; cu = cu5; tk = tk5; tl = tl5; ntp = nt5; }
        if (t == 0) {
            int run = 0, trun = 0;
            for (int k = 0; k < 125; ++k) {
                sA[k] = run;
                sB[k] = trun;
                run += hist[k];
                trun += (hist[k] + 63) / 64;
            }
            sA[125] = run;
            sB[125] = trun;
            *ntp = trun;
        }
        __syncthreads();
        if (t < 126) bs[t] = sA[t];
        if (t < 125) {
            cu[t] = sA[t];
            int nt = sB[t + 1] - sB[t];
            for (int j = 0; j < nt; ++j) {
                tk[sB[t] + j] = t;
                tl[sB[t] + j] = sA[t] + 64 * j;
            }
        }
    } else {
        const int* cnt;
        int N, mult;
        int *row, *cur;
        int s = b - 4;
        if (s == 0) { cnt = ideg1; N = N1; row = erow1; cur = ecur1; mult = 1; }
        else if (s == 1) { cnt = ideg2; N = N2; row = erow2; cur = entc2; mult = 8; }
        else if (s == 2) { cnt = ideg3; N = N3; row = erow3; cur = entc3; mult = 8; }
        else if (s == 3) { cnt = ideg4; N = N4; row = erow4; cur = entc4; mult = 8; }
        else { cnt = ideg5; N = N5; row = erow5; cur = entc5; mult = 8; }
        int chunk = (N + 255) / 256;
        int lo = t * chunk, hi = min(lo + chunk, N);
        int sum = 0;
        for (int i = lo; i < hi; ++i) sum += cnt[i];
        part[t] = sum;
        __syncthreads();
        if (t == 0) {
            int run = 0;
            for (int i = 0; i < 256; ++i) {
                int v = part[i];
                part[i] = run;
                run += v;
            }
            row[N] = run;
        }
        __syncthreads();
        int run = part[t];
        for (int i = lo; i < hi; ++i) {
            row[i] = run;
            cur[i] = mult * run;
            run += cnt[i];
        }
    }
}

// level 1: counting-sort edge payloads (ps0,ps1,ps2,src) into dst order
__global__ void scatter_dst1(const int* __restrict__ dst, const int* __restrict__ src,
                             const float* __restrict__ ps, int E, int* __restrict__ ecur,
                             uint4* __restrict__ psrc) {
    int e = blockIdx.x * blockDim.x + threadIdx.x;
    if (e >= E) return;
    int q = atomicAdd(&ecur[dst[e]], 1);
    uint4 v;
    v.x = __float_as_uint(ps[(size_t)e * 3 + 0]);
    v.y = __float_as_uint(ps[(size_t)e * 3 + 1]);
    v.z = __float_as_uint(ps[(size_t)e * 3 + 2]);
    v.w = (unsigned)src[e];
    psrc[q] = v;
}

// per-level entry scatter: spack at k-sorted pos p; sq[p] = dst-sorted pos q
__global__ void scatter_lvl(const float* __restrict__ ps, const int* __restrict__ src,
                            const int* __restrict__ dst, int E, int* __restrict__ cursor,
                            int* __restrict__ entcur, unsigned* __restrict__ spack,
                            int* __restrict__ sq) {
    __shared__ int lh[125], lbase[125];
    int t = threadIdx.x;
    for (int i = t; i < 125; i += 256) lh[i] = 0;
    __syncthreads();
    int e = blockIdx.x * 256 + t;
    int mk[8], ml[8];
    float mw[8];
    if (e < E) {
        int ff[3];
        float fr[3];
        pseudo_decode(ps, e, ff, fr);
#pragma unroll
        for (int b = 0; b < 8; ++b) {
            corner_iw(ff, fr, b, mw[b], mk[b]);
            ml[b] = atomicAdd(&lh[mk[b]], 1);
        }
    }
    __syncthreads();
    for (int i = t; i < 125; i += 256) {
        int c = lh[i];
        lbase[i] = c ? atomicAdd(&cursor[i], c) : 0;
    }
    __syncthreads();
    if (e < E) {
        int s = src[e];
        int qbase = atomicAdd(&entcur[dst[e]], 8);
#pragma unroll
        for (int b = 0; b < 8; ++b) {
            int p = lbase[mk[b]] + ml[b];
            spack[p] = ((unsigned)s << 16) | (unsigned)f2h(mw[b]);
            sq[p] = qbase + b;
        }
    }
}

// k-binned GEMM: W[k] Cout-slice in LDS (reused 64x), w-scaled x rows in LDS;
// each output row is scatter-WRITTEN (fp16) to its dst-sorted position sq[p].
template <int CIN, int COUT, int S>
__global__ __launch_bounds__(256) void bin_gemm(
    const unsigned* __restrict__ xm, const float* __restrict__ W, int c0,
    const unsigned* __restrict__ spack, const int* __restrict__ sq, const int* __restrict__ tk,
    const int* __restrict__ tl, const int* __restrict__ bs, const int* __restrict__ ntp,
    unsigned* __restrict__ msgs) {
    constexpr int C4 = S / 4;
    constexpr int NTR = 256 / C4;
    constexpr int RT = 64 / NTR;
    constexpr int XST = CIN + 4;
    __shared__ float Wl[CIN * S];
    __shared__ float xs[64 * XST];
    int t = threadIdx.x;
    int ntiles = *ntp;
    int tc = t % C4, tr = t / C4;
    int rr = t >> 2, g = t & 3;
    for (int tile = blockIdx.x; tile < ntiles; tile += gridDim.x) {
        int k = tk[tile], lo = tl[tile];
        int m = min(64, bs[k + 1] - lo);
        __syncthreads();
        float4* Wl4 = (float4*)Wl;
        const float* Wk = W + (size_t)k * CIN * COUT + c0;
        for (int i4 = t; i4 < CIN * C4; i4 += 256) {
            int row = i4 / C4, cg = i4 % C4;
            Wl4[i4] = ((const float4*)(Wk + (size_t)row * COUT))[cg];
        }
        if (rr < m) {
            unsigned sp = spack[lo + rr];
            int s = sp >> 16;
            float wv = h2f((unsigned short)(sp & 0xFFFFu));
            const uint4* xr = (const uint4*)(xm + (size_t)s * CIN);
            float4* xd = (float4*)(xs + rr * XST);
#pragma unroll
            for (int i = g; i < CIN / 4; i += 4) {
                uint4 mv = xr[i];
                float4 v;
                v.x = mono2x(mv.x) * wv;
                v.y = mono2x(mv.y) * wv;
                v.z = mono2x(mv.z) * wv;
                v.w = mono2x(mv.w) * wv;
                xd[i] = v;
            }
        }
        __syncthreads();
        float4 acc[RT];
#pragma unroll
        for (int r = 0; r < RT; ++r) acc[r] = make_float4(0.f, 0.f, 0.f, 0.f);
#pragma unroll 4
        for (int i = 0; i < CIN; ++i) {
            float4 wv = Wl4[i * C4 + tc];
#pragma unroll
            for (int r = 0; r < RT; ++r) {
                float xv = xs[(tr + r * NTR) * XST + i];
                acc[r].x += xv * wv.x;
                acc[r].y += xv * wv.y;
                acc[r].z += xv * wv.z;
                acc[r].w += xv * wv.w;
            }
        }
#pragma unroll
        for (int r = 0; r < RT; ++r) {
            int row = tr + r * NTR;
            if (row < m) {
                int q = sq[lo + row];
                uint2 pv;
                pv.x = (unsigned)f2h(acc[r].x) | ((unsigned)f2h(acc[r].y) << 16);
                pv.y = (unsigned)f2h(acc[r].z) | ((unsigned)f2h(acc[r].w) << 16);
                ((uint2*)(msgs + (size_t)q * (S / 2)))[tc] = pv;
            }
        }
    }
}

// wave per node: CONTIGUOUS stream of the node's dst-sorted message rows,
// butterfly column-reduce, + deg-norm + root + bias + ELU.
template <int CIN, int COUT, int S>
__global__ __launch_bounds__(256) void agg_finish(
    const unsigned* __restrict__ msgsU, const int* __restrict__ erow,
    const unsigned* __restrict__ xm, const float* __restrict__ root,
    const float* __restrict__ bias, float* __restrict__ y, int N, int c0) {
    const unsigned short* msgs = (const unsigned short*)msgsU;
    constexpr int WPC = S / 4;  // writer lanes; lane grp owns cols 4*grp..4*grp+3
    constexpr int G = 64 / WPC; // lanes sharing one column group
    int t = threadIdx.x;
    int lane = t & 63;
    int wid = blockIdx.x * 4 + (t >> 6);
    int nw = gridDim.x * 4;
    int grp = lane & (WPC - 1);
    int sub = lane / WPC;
    for (int d = wid; d < N; d += nw) {
        int lo = erow[d], hi = erow[d + 1];
        float dv = (float)max(hi - lo, 1);
        float4 acc = make_float4(0.f, 0.f, 0.f, 0.f);
        // root term, pre-scaled by dv (split over the G lanes sharing cols)
        const float* rbase = root + c0 + 4 * grp;
        for (int i = sub; i < CIN; i += G) {
            float xv = mono2x(xm[(size_t)d * CIN + i]) * dv;
            const float* rp = rbase + (size_t)i * COUT;
            acc.x += xv * rp[0];
            acc.y += xv * rp[1];
            acc.z += xv * rp[2];
            acc.w += xv * rp[3];
        }
        // contiguous message stream: 64 lanes x 4 halfs = 256 halfs per step
        size_t h1 = (size_t)hi * 8 * S;
        for (size_t h = (size_t)lo * 8 * S + (size_t)lane * 4; h < h1; h += 256) {
            uint2 u = *(const uint2*)(msgs + h);
            acc.x += h2f((unsigned short)(u.x & 0xFFFFu));
            acc.y += h2f((unsigned short)(u.x >> 16));
            acc.z += h2f((unsigned short)(u.y & 0xFFFFu));
            acc.w += h2f((unsigned short)(u.y >> 16));
        }
#pragma unroll
        for (int s = WPC; s < 64; s <<= 1) {
            acc.x += __shfl_xor(acc.x, s);
            acc.y += __shfl_xor(acc.y, s);
            acc.z += __shfl_xor(acc.z, s);
            acc.w += __shfl_xor(acc.w, s);
        }
        if (lane < WPC) {
            const float* bp = bias + c0 + 4 * grp;
            float4 v;
            v.x = acc.x / dv + bp[0];
            v.y = acc.y / dv + bp[1];
            v.z = acc.z / dv + bp[2];
            v.w = acc.w / dv + bp[3];
            v.x = v.x > 0.f ? v.x : expm1f(v.x);
            v.y = v.y > 0.f ? v.y : expm1f(v.y);
            v.z = v.z > 0.f ? v.z : expm1f(v.z);
            v.w = v.w > 0.f ? v.w : expm1f(v.w);
            *(float4*)(y + (size_t)d * COUT + c0 + 4 * grp) = v;
        }
    }
}

// ---------------- level 1 (Cin=1, Cout=32): dst-sorted payload stream ---------
__global__ __launch_bounds__(256) void l1_aggregate(
    const unsigned* __restrict__ xm, const uint4* __restrict__ psrc,
    const float* __restrict__ W, const int* __restrict__ erow, const float* __restrict__ root,
    const float* __restrict__ bias, float* __restrict__ y, int N) {
    __shared__ float Wl[125 * 32];
    int t = threadIdx.x;
    {
        const float4* Wg = (const float4*)W;
        float4* Wd = (float4*)Wl;
        for (int i = t; i < 125 * 32 / 4; i += 256) Wd[i] = Wg[i];
    }
    __syncthreads();
    int lane = t & 63, c = lane & 31, half = lane >> 5;
    int wid = blockIdx.x * 4 + (t >> 6);
    int nw = gridDim.x * 4;
    for (int d = wid; d < N; d += nw) {
        int lo = erow[d], hi = erow[d + 1];
        float acc = 0.f;
        for (int j = lo + half; j < hi; j += 2) {
            uint4 pv = psrc[j];
            int ff[3];
            float fr[3];
            decode3(__uint_as_float(pv.x), __uint_as_float(pv.y), __uint_as_float(pv.z), ff, fr);
            float wsum = 0.f;
#pragma unroll
            for (int b = 0; b < 8; ++b) {
                float w;
                int idx;
                corner_iw(ff, fr, b, w, idx);
                wsum += w * Wl[idx * 32 + c];
            }
            acc += mono2x(xm[pv.w]) * wsum;
        }
        acc += __shfl_down(acc, 32);
        if (half == 0) {
            float dv = (float)max(hi - lo, 1);
            float v = acc / dv + mono2x(xm[d]) * root[c] + bias[c];
            y[(size_t)d * 32 + c] = v > 0.f ? v : expm1f(v);
        }
    }
}

// fc1: [1024] @ [1024,512] + b, ELU — K-split across 8 blocks x 256 threads
__global__ __launch_bounds__(256) void fc1_kernel(const unsigned* __restrict__ xm,
                                                  const float* __restrict__ w,
                                                  const float* __restrict__ b,
                                                  float* __restrict__ out) {
    __shared__ float xsh[1024];
    __shared__ float sh[4][64];
    int t = threadIdx.x;
    for (int i = t; i < 1024; i += 256) xsh[i] = mono2x(xm[i]);
    __syncthreads();
    int ol = t & 63, kk = t >> 6;
    int o = blockIdx.x * 64 + ol;
    int i0 = kk * 256;
    float acc = 0.f;
#pragma unroll 8
    for (int i = 0; i < 256; ++i) acc += xsh[i0 + i] * w[(size_t)(i0 + i) * 512 + o];
    sh[kk][ol] = acc;
    __syncthreads();
    if (kk == 0) {
        float v = sh[0][ol] + sh[1][ol] + sh[2][ol] + sh[3][ol] + b[o];
        out[o] = v > 0.f ? v : expm1f(v);
    }
}

__global__ void fc2_lsm(const float* __restrict__ x, const float* __restrict__ w,
                        const float* __restrict__ b, float* __restrict__ out) {
    __shared__ float z[10];
    int t = threadIdx.x;
    if (t < 10) {
        float acc = b[t];
        for (int i = 0; i < 512; ++i) acc += x[i] * w[(size_t)i * 10 + t];
        z[t] = acc;
    }
    __syncthreads();
    if (t == 0) {
        float m = z[0];
        for (int i = 1; i < 10; ++i) m = fmaxf(m, z[i]);
        float s = 0.f;
        for (int i = 0; i < 10; ++i) s += expf(z[i] - m);
        float l = logf(s);
        for (int i = 0; i < 10; ++i) out[i] = z[i] - m - l;
    }
}

// ---------------------------------------------------------------------------

extern "C" void kernel_launch(void* const* d_in, const int* in_sizes, int n_in,
                              void* d_out, int out_size, void* d_ws, size_t ws_size,
                              hipStream_t stream) {
    (void)in_sizes; (void)n_in; (void)out_size;
    const float* x0 = (const float*)d_in[0];
    const int* cl[6];
    for (int i = 0; i < 6; ++i) cl[i] = (const int*)d_in[1 + i];
    const int* src[5];
    const int* dst[5];
    const float* ps[5];
    const float* W[5];
    const float* root[5];
    const float* bias[5];
    for (int i = 0; i < 5; ++i) {
        src[i] = (const int*)d_in[7 + 6 * i];
        dst[i] = (const int*)d_in[8 + 6 * i];
        ps[i] = (const float*)d_in[9 + 6 * i];
        W[i] = (const float*)d_in[10 + 6 * i];
        root[i] = (const float*)d_in[11 + 6 * i];
        bias[i] = (const float*)d_in[12 + 6 * i];
    }
    const float* fc1_w = (const float*)d_in[37];
    const float* fc1_b = (const float*)d_in[38];
    const float* fc2_w = (const float*)d_in[39];
    const float* fc2_b = (const float*)d_in[40];

    const int N1 = 20000, N2 = 6000, N3 = 2000, N4 = 700, N5 = 256;
    const int E1 = 160000, E2 = 48000, E3 = 16000, E4 = 5600, E5 = 2048;
    const int UB2 = E2 * 8 / 64 + 126, UB3 = E3 * 8 / 64 + 126;
    const int UB4 = E4 * 8 / 64 + 126, UB5 = E5 * 8 / 64 + 126;

    unsigned* base = (unsigned*)d_ws;
    size_t o = 0;
    auto alloc = [&](size_t n) { unsigned* p = base + o; o += n; return p; };
    // ---- zero block (single fill) ----
    unsigned* xp1m = alloc(N1);
    unsigned* xp2m = alloc((size_t)N2 * 32);
    unsigned* xp3m = alloc((size_t)N3 * 64);
    unsigned* xp4m = alloc((size_t)N4 * 64);
    unsigned* xp5m = alloc((size_t)N5 * 64);
    unsigned* xp6m = alloc(8 * 128);
    int* hist2 = (int*)alloc(125);
    int* hist3 = (int*)alloc(125);
    int* hist4 = (int*)alloc(125);
    int* hist5 = (int*)alloc(125);
    int* ideg1 = (int*)alloc(N1);
    int* ideg2 = (int*)alloc(N2);
    int* ideg3 = (int*)alloc(N3);
    int* ideg4 = (int*)alloc(N4);
    int* ideg5 = (int*)alloc(N5);
    size_t zero_words = o;
    // ---- non-zeroed dedicated ----
    int* erow1 = (int*)alloc(N1 + 1);
    int* erow2 = (int*)alloc(N2 + 1);
    int* erow3 = (int*)alloc(N3 + 1);
    int* erow4 = (int*)alloc(N4 + 1);
    int* erow5 = (int*)alloc(N5 + 1);
    int* ecur1 = (int*)alloc(N1);
    int* entc2 = (int*)alloc(N2);
    int* entc3 = (int*)alloc(N3);
    int* entc4 = (int*)alloc(N4);
    int* entc5 = (int*)alloc(N5);
    int* bs2 = (int*)alloc(126);
    int* bs3 = (int*)alloc(126);
    int* bs4 = (int*)alloc(126);
    int* bs5 = (int*)alloc(126);
    int* cu2 = (int*)alloc(125);
    int* cu3 = (int*)alloc(125);
    int* cu4 = (int*)alloc(125);
    int* cu5 = (int*)alloc(125);
    int* nt2 = (int*)alloc(1);
    int* nt3 = (int*)alloc(1);
    int* nt4 = (int*)alloc(1);
    int* nt5 = (int*)alloc(1);
    int* tk2 = (int*)alloc(UB2);
    int* tl2 = (int*)alloc(UB2);
    int* tk3 = (int*)alloc(UB3);
    int* tl3 = (int*)alloc(UB3);
    int* tk4 = (int*)alloc(UB4);
    int* tl4 = (int*)alloc(UB4);
    int* tk5 = (int*)alloc(UB5);
    int* tl5 = (int*)alloc(UB5);
    float* y1 = (float*)alloc((size_t)N1 * 32);
    float* y2 = (float*)alloc((size_t)N2 * 64);
    float* y3 = (float*)alloc((size_t)N3 * 64);
    float* y4 = (float*)alloc((size_t)N4 * 64);
    float* y5 = (float*)alloc((size_t)N5 * 128);
    float* fc1o = (float*)alloc(512);
    unsigned* arena = base + o;
    size_t arenaWords = (ws_size / 4 > o) ? (ws_size / 4 - o) : 0;

    // slice width per level: need 8E*(2 + S/2) words in the arena
    auto fitS = [&](int E, int maxS, int minS) {
        int S = maxS;
        while (S > minS && (size_t)8 * E * (size_t)(2 + S / 2) > arenaWords) S >>= 1;
        return S;
    };
    int S2 = fitS(E2, 64, 16);
    int S3 = fitS(E3, 64, 16);
    int S4 = fitS(E4, 64, 16);
    int S5 = fitS(E5, 128, 32);

    // ---- 1. one fill for monos + hists + idegs ----
    fill_u32<<<((int)zero_words + 255) / 256, 256, 0, stream>>>(base, (int)zero_words, 0u);

    // ---- 2. batched hist/deg ----
    int nb2 = (E2 + 255) / 256, nb3 = (E3 + 255) / 256, nb4 = (E4 + 255) / 256,
        nb5 = (E5 + 255) / 256, nb1 = (E1 + 255) / 256;
    int B2 = nb2, B23 = B2 + nb3, B234 = B23 + nb4, B2345 = B234 + nb5;
    hist_all<<<B2345 + nb1, 256, 0, stream>>>(ps[1], dst[1], E2, hist2, ideg2, ps[2], dst[2], E3,
                                              hist3, ideg3, ps[3], dst[3], E4, hist4, ideg4,
                                              ps[4], dst[4], E5, hist5, ideg5, dst[0], E1, ideg1,
                                              B2, B23, B234, B2345);

    // ---- 3. batched prefix/scan ----
    prep_all<<<9, 256, 0, stream>>>(hist2, bs2, cu2, tk2, tl2, nt2, hist3, bs3, cu3, tk3, tl3,
                                    nt3, hist4, bs4, cu4, tk4, tl4, nt4, hist5, bs5, cu5, tk5,
                                    tl5, nt5, ideg1, N1, erow1, ecur1, ideg2, N2, erow2, entc2,
                                    ideg3, N3, erow3, entc3, ideg4, N4, erow4, entc4, ideg5, N5,
                                    erow5, entc5);

    // ---- level 1 (psrc payload sort lives in the arena) ----
    pool_scatter<<<(80000 + 255) / 256, 256, 0, stream>>>(x0, cl[0], xp1m, 80000, 1);
    {
        uint4* psrc = (uint4*)arena;  // 4*E1 words, free before level 2 begins
        scatter_dst1<<<nb1, 256, 0, stream>>>(dst[0], src[0], ps[0], E1, ecur1, psrc);
        l1_aggregate<<<2048, 256, 0, stream>>>(xp1m, psrc, W[0], erow1, root[0], bias[0], y1, N1);
    }

#define RUN_SLICES(CIN, COUT, SS, xpm, Wl, rootl, biasl, yout, N, tk, tl, bs, nt, erowL, ub)   \
    for (int s = 0; s < (COUT) / (SS); ++s) {                                                  \
        bin_gemm<CIN, COUT, SS><<<((ub) < 2048 ? (ub) : 2048), 256, 0, stream>>>(              \
            xpm, Wl, s * (SS), spack, sq, tk, tl, bs, nt, msgs);                               \
        agg_finish<CIN, COUT, SS><<<((N) + 3) / 4, 256, 0, stream>>>(msgs, erowL, xpm, rootl,  \
                                                                     biasl, yout, N, s * (SS)); \
    }

    // ---- level 2: Cin32 Cout64 ----
    {
        pool_scatter<<<((size_t)N1 * 32 + 255) / 256, 256, 0, stream>>>(y1, cl[1], xp2m, N1, 32);
        unsigned* spack = arena;
        int* sq = (int*)(arena + (size_t)8 * E2);
        unsigned* msgs = arena + (size_t)16 * E2;
        scatter_lvl<<<nb2, 256, 0, stream>>>(ps[1], src[1], dst[1], E2, cu2, entc2, spack, sq);
        if (S2 == 64) {
            RUN_SLICES(32, 64, 64, xp2m, W[1], root[1], bias[1], y2, N2, tk2, tl2, bs2, nt2, erow2, UB2)
        } else if (S2 == 32) {
            RUN_SLICES(32, 64, 32, xp2m, W[1], root[1], bias[1], y2, N2, tk2, tl2, bs2, nt2, erow2, UB2)
        } else {
            RUN_SLICES(32, 64, 16, xp2m, W[1], root[1], bias[1], y2, N2, tk2, tl2, bs2, nt2, erow2, UB2)
        }
    }
    // ---- level 3: Cin64 Cout64 ----
    {
        pool_scatter<<<((size_t)N2 * 64 + 255) / 256, 256, 0, stream>>>(y2, cl[2], xp3m, N2, 64);
        unsigned* spack = arena;
        int* sq = (int*)(arena + (size_t)8 * E3);
        unsigned* msgs = arena + (size_t)16 * E3;
        scatter_lvl<<<nb3, 256, 0, stream>>>(ps[2], src[2], dst[2], E3, cu3, entc3, spack, sq);
        if (S3 == 64) {
            RUN_SLICES(64, 64, 64, xp3m, W[2], root[2], bias[2], y3, N3, tk3, tl3, bs3, nt3, erow3, UB3)
        } else if (S3 == 32) {
            RUN_SLICES(64, 64, 32, xp3m, W[2], root[2], bias[2], y3, N3, tk3, tl3, bs3, nt3, erow3, UB3)
        } else {
            RUN_SLICES(64, 64, 16, xp3m, W[2], root[2], bias[2], y3, N3, tk3, tl3, bs3, nt3, erow3, UB3)
        }
    }
    // ---- level 4: Cin64 Cout64 ----
    {
        pool_scatter<<<((size_t)N3 * 64 + 255) / 256, 256, 0, stream>>>(y3, cl[3], xp4m, N3, 64);
        unsigned* spack = arena;
        int* sq = (int*)(arena + (size_t)8 * E4);
        unsigned* msgs = arena + (size_t)16 * E4;
        scatter_lvl<<<nb4, 256, 0, stream>>>(ps[3], src[3], dst[3], E4, cu4, entc4, spack, sq);
        if (S4 == 64) {
            RUN_SLICES(64, 64, 64, xp4m, W[3], root[3], bias[3], y4, N4, tk4, tl4, bs4, nt4, erow4, UB4)
        } else if (S4 == 32) {
            RUN_SLICES(64, 64, 32, xp4m, W[3], root[3], bias[3], y4, N4, tk4, tl4, bs4, nt4, erow4, UB4)
        } else {
            RUN_SLICES(64, 64, 16, xp4m, W[3], root[3], bias[3], y4, N4, tk4, tl4, bs4, nt4, erow4, UB4)
        }
    }
    // ---- level 5: Cin64 Cout128 ----
    {
        pool_scatter<<<((size_t)N4 * 64 + 255) / 256, 256, 0, stream>>>(y4, cl[4], xp5m, N4, 64);
        unsigned* spack = arena;
        int* sq = (int*)(arena + (size_t)8 * E5);
        unsigned* msgs = arena + (size_t)16 * E5;
        scatter_lvl<<<nb5, 256, 0, stream>>>(ps[4], src[4], dst[4], E5, cu5, entc5, spack, sq);
        if (S5 == 128) {
            RUN_SLICES(64, 128, 128, xp5m, W[4], root[4], bias[4], y5, N5, tk5, tl5, bs5, nt5, erow5, UB5)
        } else if (S5 == 64) {
            RUN_SLICES(64, 128, 64, xp5m, W[4], root[4], bias[4], y5, N5, tk5, tl5, bs5, nt5, erow5, UB5)
        } else {
            RUN_SLICES(64, 128, 32, xp5m, W[4], root[4], bias[4], y5, N5, tk5, tl5, bs5, nt5, erow5, UB5)
        }
    }
#undef RUN_SLICES

    // ---- final dense pool + FC head ----
    pool_scatter<<<((size_t)N5 * 128 + 255) / 256, 256, 0, stream>>>(y5, cl[5], xp6m, N5, 128);
    fc1_kernel<<<8, 256, 0, stream>>>(xp6m, fc1_w, fc1_b, fc1o);
    fc2_lsm<<<1, 64, 0, stream>>>(fc1o, fc2_w, fc2_b, (float*)d_out);
}

// Round 6
// 314.402 us; speedup vs baseline: 2.0243x; 1.1357x over previous
//
#include <hip/hip_runtime.h>
#include <hip/hip_fp16.h>
#include <math.h>

#define DEVINL __device__ __forceinline__

// ---------------------------------------------------------------------------
// SplineCNN net, round 5:
//  - fc2 + prefix scans parallelized (were 54us + 48us of serial latency)
//  - pooling fused into the conv epilogues: agg_finish / l1_aggregate
//    atomicMax(f2mono(v)) straight into the next level's mono buffer
//    (no pool_scatter kernels, no y buffers)
//  - pool of x0 folded into hist_all as an extra block segment
// ---------------------------------------------------------------------------

DEVINL unsigned f2mono(float f) {
    unsigned u = __float_as_uint(f);
    return (u & 0x80000000u) ? ~u : (u | 0x80000000u);
}
DEVINL float mono2x(unsigned m) {  // sentinel 0 == empty segment -> 0.0
    if (m == 0u) return 0.f;
    unsigned u = (m & 0x80000000u) ? (m & 0x7FFFFFFFu) : ~m;
    return __uint_as_float(u);
}
DEVINL unsigned short f2h(float f) {
    union { __half h; unsigned short u; } c;
    c.h = __float2half_rn(f);
    return c.u;
}
DEVINL float h2f(unsigned short s) {
    union { unsigned short u; __half h; } c;
    c.u = s;
    return __half2float(c.h);
}

__global__ void fill_u32(unsigned* __restrict__ p, int n, unsigned v) {
    int i = blockIdx.x * blockDim.x + threadIdx.x;
    if (i < n) p[i] = v;
}

DEVINL void decode3(float p0, float p1, float p2, int ff[3], float fr[3]) {
    float pp[3] = {p0 * 4.f, p1 * 4.f, p2 * 4.f};  // (K-1) = 4
#pragma unroll
    for (int d = 0; d < 3; ++d) {
        float f = floorf(pp[d]);
        ff[d] = (int)f;
        fr[d] = pp[d] - f;
    }
}
DEVINL void pseudo_decode(const float* __restrict__ ps, int e, int ff[3], float fr[3]) {
    decode3(ps[(size_t)e * 3], ps[(size_t)e * 3 + 1], ps[(size_t)e * 3 + 2], ff, fr);
}

DEVINL void corner_iw(const int ff[3], const float fr[3], int bits, float& w, int& idx) {
    w = 1.f;
    idx = 0;
    int pw = 1;
#pragma unroll
    for (int d = 0; d < 3; ++d) {
        int b = (bits >> d) & 1;
        w *= b ? fr[d] : (1.f - fr[d]);
        int fd = ff[d] + b;
        fd = fd < 0 ? 0 : (fd > 4 ? 4 : fd);
        idx += fd * pw;
        pw *= 5;
    }
}

// ---------------- batched hist (L2-5) + deg (all) + pool0 --------------------
DEVINL void hist_seg(const float* __restrict__ ps, const int* __restrict__ dst, int E,
                     int* __restrict__ hist, int* __restrict__ ideg, int bofs, int t,
                     int* __restrict__ lh) {
    for (int i = t; i < 125; i += 256) lh[i] = 0;
    __syncthreads();
    int e = bofs * 256 + t;
    if (e < E) {
        int ff[3];
        float fr[3];
        pseudo_decode(ps, e, ff, fr);
#pragma unroll
        for (int b = 0; b < 8; ++b) {
            float w;
            int k;
            corner_iw(ff, fr, b, w, k);
            atomicAdd(&lh[k], 1);
        }
        atomicAdd(&ideg[dst[e]], 1);
    }
    __syncthreads();
    for (int i = t; i < 125; i += 256)
        if (lh[i]) atomicAdd(&hist[i], lh[i]);
}

__global__ void hist_all(const float* ps2, const int* dst2, int E2, int* hist2, int* ideg2,
                         const float* ps3, const int* dst3, int E3, int* hist3, int* ideg3,
                         const float* ps4, const int* dst4, int E4, int* hist4, int* ideg4,
                         const float* ps5, const int* dst5, int E5, int* hist5, int* ideg5,
                         const int* dst1, int E1, int* ideg1, const float* x0, const int* cl1,
                         int n0, unsigned* xp1m, int B2, int B23, int B234, int B2345,
                         int B1end) {
    __shared__ int lh[125];
    int b = blockIdx.x, t = threadIdx.x;
    if (b < B2) hist_seg(ps2, dst2, E2, hist2, ideg2, b, t, lh);
    else if (b < B23) hist_seg(ps3, dst3, E3, hist3, ideg3, b - B2, t, lh);
    else if (b < B234) hist_seg(ps4, dst4, E4, hist4, ideg4, b - B23, t, lh);
    else if (b < B2345) hist_seg(ps5, dst5, E5, hist5, ideg5, b - B234, t, lh);
    else if (b < B1end) {
        int e = (b - B2345) * 256 + t;
        if (e < E1) atomicAdd(&ideg1[dst1[e]], 1);
    } else {
        int i = (b - B1end) * 256 + t;
        if (i < n0) atomicMax(&xp1m[cl1[i]], f2mono(x0[i]));
    }
}

// ---------------- batched prefix/scan prep (wave-parallel) --------------------
// blocks 0-3: bin prefix + tile lists (L2-5); blocks 4-8: node scans L1-L5
__global__ void prep_all(const int* h2, int* bs2, int* cu2, int* tk2, int* tl2, int* nt2,
                         const int* h3, int* bs3, int* cu3, int* tk3, int* tl3, int* nt3,
                         const int* h4, int* bs4, int* cu4, int* tk4, int* tl4, int* nt4,
                         const int* h5, int* bs5, int* cu5, int* tk5, int* tl5, int* nt5,
                         const int* ideg1, int N1, int* erow1, int* ecur1, const int* ideg2,
                         int N2, int* erow2, int* entc2, const int* ideg3, int N3, int* erow3,
                         int* entc3, const int* ideg4, int N4, int* erow4, int* entc4,
                         const int* ideg5, int N5, int* erow5, int* entc5) {
    int b = blockIdx.x, t = threadIdx.x;
    int lane = t & 63, wv = t >> 6;
    if (b < 4) {
        const int* hist;
        int *bs, *cu, *tk, *tl, *ntp;
        if (b == 0) { hist = h2; bs = bs2; cu = cu2; tk = tk2; tl = tl2; ntp = nt2; }
        else if (b == 1) { hist = h3; bs = bs3; cu = cu3; tk = tk3; tl = tl3; ntp = nt3; }
        else if (b == 2) { hist = h4; bs = bs4; cu = cu4; tk = tk4; tl = tl4; ntp = nt4; }
        else { hist = h5; bs = bs5; cu = cu5; tk = tk5; tl = tl5; ntp = nt5; }
        int h = 0, th = 0;
        if (t < 125) {
            h = hist[t];
            th = (h + 63) >> 6;
        }
        unsigned long long v = (unsigned long long)(unsigned)h |
                               ((unsigned long long)(unsigned)th << 32);
#pragma unroll
        for (int s = 1; s < 64; s <<= 1) {
            unsigned long long u = __shfl_up(v, s);
            if (lane >= s) v += u;
        }
        __shared__ unsigned long long wtot[4];
        if (lane == 63) wtot[wv] = v;
        __syncthreads();
        unsigned long long woff = 0;
        for (int w2 = 0; w2 < wv; ++w2) woff += wtot[w2];
        unsigned long long incl = v + woff;
        int eh = (int)(incl & 0xFFFFFFFFull) - h;
        int eth = (int)(incl >> 32) - th;
        if (t < 125) {
            bs[t] = eh;
            cu[t] = eh;
            for (int j = 0; j < th; ++j) {
                tk[eth + j] = t;
                tl[eth + j] = eh + 64 * j;
            }
        }
        if (t == 124) {
            bs[125] = eh + h;
            *ntp = eth + th;
        }
    } else {
        const int* cnt;
        int N, mult;
        int *row, *cur;
        int s = b - 4;
        if (s == 0) { cnt = ideg1; N = N1; row = erow1; cur = ecur1; mult = 1; }
        else if (s == 1) { cnt = ideg2; N = N2; row = erow2; cur = entc2; mult = 8; }
        else if (s == 2) { cnt = ideg3; N = N3; row = erow3; cur = entc3; mult = 8; }
        else if (s == 3) { cnt = ideg4; N = N4; row = erow4; cur = entc4; mult = 8; }
        else { cnt = ideg5; N = N5; row = erow5; cur = entc5; mult = 8; }
        int chunk = (N + 255) / 256;
        int lo = t * chunk, hi = min(lo + chunk, N);
        int psum = 0;
        for (int i = lo; i < hi; ++i) psum += cnt[i];
        int v = psum;
#pragma unroll
        for (int st = 1; st < 64; st <<= 1) {
            int u = __shfl_up(v, st);
            if (lane >= st) v += u;
        }
        __shared__ int wsum[4];
        if (lane == 63) wsum[wv] = v;
        __syncthreads();
        int woff = 0;
        for (int w2 = 0; w2 < wv; ++w2) woff += wsum[w2];
        int run = v + woff - psum;
        if (t == 255) row[N] = v + woff;
        for (int i = lo; i < hi; ++i) {
            row[i] = run;
            cur[i] = mult * run;
            run += cnt[i];
        }
    }
}

// level 1: counting-sort edge payloads (ps0,ps1,ps2,src) into dst order
__global__ void scatter_dst1(const int* __restrict__ dst, const int* __restrict__ src,
                             const float* __restrict__ ps, int E, int* __restrict__ ecur,
                             uint4* __restrict__ psrc) {
    int e = blockIdx.x * blockDim.x + threadIdx.x;
    if (e >= E) return;
    int q = atomicAdd(&ecur[dst[e]], 1);
    uint4 v;
    v.x = __float_as_uint(ps[(size_t)e * 3 + 0]);
    v.y = __float_as_uint(ps[(size_t)e * 3 + 1]);
    v.z = __float_as_uint(ps[(size_t)e * 3 + 2]);
    v.w = (unsigned)src[e];
    psrc[q] = v;
}

// per-level entry scatter: spack at k-sorted pos p; sq[p] = dst-sorted pos q
__global__ void scatter_lvl(const float* __restrict__ ps, const int* __restrict__ src,
                            const int* __restrict__ dst, int E, int* __restrict__ cursor,
                            int* __restrict__ entcur, unsigned* __restrict__ spack,
                            int* __restrict__ sq) {
    __shared__ int lh[125], lbase[125];
    int t = threadIdx.x;
    for (int i = t; i < 125; i += 256) lh[i] = 0;
    __syncthreads();
    int e = blockIdx.x * 256 + t;
    int mk[8], ml[8];
    float mw[8];
    if (e < E) {
        int ff[3];
        float fr[3];
        pseudo_decode(ps, e, ff, fr);
#pragma unroll
        for (int b = 0; b < 8; ++b) {
            corner_iw(ff, fr, b, mw[b], mk[b]);
            ml[b] = atomicAdd(&lh[mk[b]], 1);
        }
    }
    __syncthreads();
    for (int i = t; i < 125; i += 256) {
        int c = lh[i];
        lbase[i] = c ? atomicAdd(&cursor[i], c) : 0;
    }
    __syncthreads();
    if (e < E) {
        int s = src[e];
        int qbase = atomicAdd(&entcur[dst[e]], 8);
#pragma unroll
        for (int b = 0; b < 8; ++b) {
            int p = lbase[mk[b]] + ml[b];
            spack[p] = ((unsigned)s << 16) | (unsigned)f2h(mw[b]);
            sq[p] = qbase + b;
        }
    }
}

// k-binned GEMM: W[k] Cout-slice in LDS (reused 64x), w-scaled x rows in LDS;
// each output row is scatter-WRITTEN (fp16) to its dst-sorted position sq[p].
template <int CIN, int COUT, int S>
__global__ __launch_bounds__(256) void bin_gemm(
    const unsigned* __restrict__ xm, const float* __restrict__ W, int c0,
    const unsigned* __restrict__ spack, const int* __restrict__ sq, const int* __restrict__ tk,
    const int* __restrict__ tl, const int* __restrict__ bs, const int* __restrict__ ntp,
    unsigned* __restrict__ msgs) {
    constexpr int C4 = S / 4;
    constexpr int NTR = 256 / C4;
    constexpr int RT = 64 / NTR;
    constexpr int XST = CIN + 4;
    __shared__ float Wl[CIN * S];
    __shared__ float xs[64 * XST];
    int t = threadIdx.x;
    int ntiles = *ntp;
    int tc = t % C4, tr = t / C4;
    int rr = t >> 2, g = t & 3;
    for (int tile = blockIdx.x; tile < ntiles; tile += gridDim.x) {
        int k = tk[tile], lo = tl[tile];
        int m = min(64, bs[k + 1] - lo);
        __syncthreads();
        float4* Wl4 = (float4*)Wl;
        const float* Wk = W + (size_t)k * CIN * COUT + c0;
        for (int i4 = t; i4 < CIN * C4; i4 += 256) {
            int row = i4 / C4, cg = i4 % C4;
            Wl4[i4] = ((const float4*)(Wk + (size_t)row * COUT))[cg];
        }
        if (rr < m) {
            unsigned sp = spack[lo + rr];
            int s = sp >> 16;
            float wv = h2f((unsigned short)(sp & 0xFFFFu));
            const uint4* xr = (const uint4*)(xm + (size_t)s * CIN);
            float4* xd = (float4*)(xs + rr * XST);
#pragma unroll
            for (int i = g; i < CIN / 4; i += 4) {
                uint4 mv = xr[i];
                float4 v;
                v.x = mono2x(mv.x) * wv;
                v.y = mono2x(mv.y) * wv;
                v.z = mono2x(mv.z) * wv;
                v.w = mono2x(mv.w) * wv;
                xd[i] = v;
            }
        }
        __syncthreads();
        float4 acc[RT];
#pragma unroll
        for (int r = 0; r < RT; ++r) acc[r] = make_float4(0.f, 0.f, 0.f, 0.f);
#pragma unroll 4
        for (int i = 0; i < CIN; ++i) {
            float4 wv = Wl4[i * C4 + tc];
#pragma unroll
            for (int r = 0; r < RT; ++r) {
                float xv = xs[(tr + r * NTR) * XST + i];
                acc[r].x += xv * wv.x;
                acc[r].y += xv * wv.y;
                acc[r].z += xv * wv.z;
                acc[r].w += xv * wv.w;
            }
        }
#pragma unroll
        for (int r = 0; r < RT; ++r) {
            int row = tr + r * NTR;
            if (row < m) {
                int q = sq[lo + row];
                uint2 pv;
                pv.x = (unsigned)f2h(acc[r].x) | ((unsigned)f2h(acc[r].y) << 16);
                pv.y = (unsigned)f2h(acc[r].z) | ((unsigned)f2h(acc[r].w) << 16);
                ((uint2*)(msgs + (size_t)q * (S / 2)))[tc] = pv;
            }
        }
    }
}

// wave per node: contiguous dst-sorted message stream, butterfly column-reduce,
// deg-norm + root + bias + ELU, then POOL: atomicMax into next level's mono buf.
template <int CIN, int COUT, int S>
__global__ __launch_bounds__(256) void agg_finish(
    const unsigned* __restrict__ msgsU, const int* __restrict__ erow,
    const unsigned* __restrict__ xm, const float* __restrict__ root,
    const float* __restrict__ bias, const int* __restrict__ clnext,
    unsigned* __restrict__ xnext, int N, int c0) {
    const unsigned short* msgs = (const unsigned short*)msgsU;
    constexpr int WPC = S / 4;  // writer lanes; lane grp owns cols 4*grp..4*grp+3
    constexpr int G = 64 / WPC; // lanes sharing one column group
    int t = threadIdx.x;
    int lane = t & 63;
    int wid = blockIdx.x * 4 + (t >> 6);
    int nw = gridDim.x * 4;
    int grp = lane & (WPC - 1);
    int sub = lane / WPC;
    for (int d = wid; d < N; d += nw) {
        int lo = erow[d], hi = erow[d + 1];
        float dv = (float)max(hi - lo, 1);
        float4 acc = make_float4(0.f, 0.f, 0.f, 0.f);
        // root term, pre-scaled by dv (split over the G lanes sharing cols)
        const float* rbase = root + c0 + 4 * grp;
        for (int i = sub; i < CIN; i += G) {
            float xv = mono2x(xm[(size_t)d * CIN + i]) * dv;
            const float* rp = rbase + (size_t)i * COUT;
            acc.x += xv * rp[0];
            acc.y += xv * rp[1];
            acc.z += xv * rp[2];
            acc.w += xv * rp[3];
        }
        // contiguous message stream: 64 lanes x 4 halfs = 256 halfs per step
        size_t h1 = (size_t)hi * 8 * S;
        for (size_t h = (size_t)lo * 8 * S + (size_t)lane * 4; h < h1; h += 256) {
            uint2 u = *(const uint2*)(msgs + h);
            acc.x += h2f((unsigned short)(u.x & 0xFFFFu));
            acc.y += h2f((unsigned short)(u.x >> 16));
            acc.z += h2f((unsigned short)(u.y & 0xFFFFu));
            acc.w += h2f((unsigned short)(u.y >> 16));
        }
#pragma unroll
        for (int s = WPC; s < 64; s <<= 1) {
            acc.x += __shfl_xor(acc.x, s);
            acc.y += __shfl_xor(acc.y, s);
            acc.z += __shfl_xor(acc.z, s);
            acc.w += __shfl_xor(acc.w, s);
        }
        if (lane < WPC) {
            const float* bp = bias + c0 + 4 * grp;
            float4 v;
            v.x = acc.x / dv + bp[0];
            v.y = acc.y / dv + bp[1];
            v.z = acc.z / dv + bp[2];
            v.w = acc.w / dv + bp[3];
            v.x = v.x > 0.f ? v.x : expm1f(v.x);
            v.y = v.y > 0.f ? v.y : expm1f(v.y);
            v.z = v.z > 0.f ? v.z : expm1f(v.z);
            v.w = v.w > 0.f ? v.w : expm1f(v.w);
            unsigned* xp = xnext + (size_t)clnext[d] * COUT + c0 + 4 * grp;
            atomicMax(&xp[0], f2mono(v.x));
            atomicMax(&xp[1], f2mono(v.y));
            atomicMax(&xp[2], f2mono(v.z));
            atomicMax(&xp[3], f2mono(v.w));
        }
    }
}

// ---------------- level 1 (Cin=1, Cout=32): fused conv + pool into xp2m -------
__global__ __launch_bounds__(256) void l1_aggregate(
    const unsigned* __restrict__ xm, const uint4* __restrict__ psrc,
    const float* __restrict__ W, const int* __restrict__ erow, const float* __restrict__ root,
    const float* __restrict__ bias, const int* __restrict__ cl2, unsigned* __restrict__ xp2m,
    int N) {
    __shared__ float Wl[125 * 32];
    int t = threadIdx.x;
    {
        const float4* Wg = (const float4*)W;
        float4* Wd = (float4*)Wl;
        for (int i = t; i < 125 * 32 / 4; i += 256) Wd[i] = Wg[i];
    }
    __syncthreads();
    int lane = t & 63, c = lane & 31, half = lane >> 5;
    int wid = blockIdx.x * 4 + (t >> 6);
    int nw = gridDim.x * 4;
    for (int d = wid; d < N; d += nw) {
        int lo = erow[d], hi = erow[d + 1];
        float acc = 0.f;
        for (int j = lo + half; j < hi; j += 2) {
            uint4 pv = psrc[j];
            int ff[3];
            float fr[3];
            decode3(__uint_as_float(pv.x), __uint_as_float(pv.y), __uint_as_float(pv.z), ff, fr);
            float wsum = 0.f;
#pragma unroll
            for (int b = 0; b < 8; ++b) {
                float w;
                int idx;
                corner_iw(ff, fr, b, w, idx);
                wsum += w * Wl[idx * 32 + c];
            }
            acc += mono2x(xm[pv.w]) * wsum;
        }
        acc += __shfl_down(acc, 32);
        if (half == 0) {
            float dv = (float)max(hi - lo, 1);
            float v = acc / dv + mono2x(xm[d]) * root[c] + bias[c];
            v = v > 0.f ? v : expm1f(v);
            atomicMax(&xp2m[(size_t)cl2[d] * 32 + c], f2mono(v));
        }
    }
}

// fc1: [1024] @ [1024,512] + b, ELU — K-split across 8 blocks x 256 threads
__global__ __launch_bounds__(256) void fc1_kernel(const unsigned* __restrict__ xm,
                                                  const float* __restrict__ w,
                                                  const float* __restrict__ b,
                                                  float* __restrict__ out) {
    __shared__ float xsh[1024];
    __shared__ float sh[4][64];
    int t = threadIdx.x;
    for (int i = t; i < 1024; i += 256) xsh[i] = mono2x(xm[i]);
    __syncthreads();
    int ol = t & 63, kk = t >> 6;
    int o = blockIdx.x * 64 + ol;
    int i0 = kk * 256;
    float acc = 0.f;
#pragma unroll 8
    for (int i = 0; i < 256; ++i) acc += xsh[i0 + i] * w[(size_t)(i0 + i) * 512 + o];
    sh[kk][ol] = acc;
    __syncthreads();
    if (kk == 0) {
        float v = sh[0][ol] + sh[1][ol] + sh[2][ol] + sh[3][ol] + b[o];
        out[o] = v > 0.f ? v : expm1f(v);
    }
}

// fc2 (512->10) + log_softmax, parallel: thread i owns row i
__global__ __launch_bounds__(512) void fc2_lsm(const float* __restrict__ x,
                                               const float* __restrict__ w,
                                               const float* __restrict__ b,
                                               float* __restrict__ out) {
    __shared__ float red[8][10];
    int t = threadIdx.x, lane = t & 63, wv = t >> 6;
    float xv = x[t];
    const float* wr = w + (size_t)t * 10;
    float acc[10];
#pragma unroll
    for (int c = 0; c < 10; ++c) acc[c] = xv * wr[c];
#pragma unroll
    for (int s = 32; s > 0; s >>= 1) {
#pragma unroll
        for (int c = 0; c < 10; ++c) acc[c] += __shfl_down(acc[c], s);
    }
    if (lane == 0) {
#pragma unroll
        for (int c = 0; c < 10; ++c) red[wv][c] = acc[c];
    }
    __syncthreads();
    if (t == 0) {
        float z[10];
        for (int c = 0; c < 10; ++c) {
            float s2 = b[c];
            for (int w2 = 0; w2 < 8; ++w2) s2 += red[w2][c];
            z[c] = s2;
        }
        float m = z[0];
        for (int i = 1; i < 10; ++i) m = fmaxf(m, z[i]);
        float s2 = 0.f;
        for (int i = 0; i < 10; ++i) s2 += expf(z[i] - m);
        float l = logf(s2);
        for (int i = 0; i < 10; ++i) out[i] = z[i] - m - l;
    }
}

// ---------------------------------------------------------------------------

extern "C" void kernel_launch(void* const* d_in, const int* in_sizes, int n_in,
                              void* d_out, int out_size, void* d_ws, size_t ws_size,
                              hipStream_t stream) {
    (void)in_sizes; (void)n_in; (void)out_size;
    const float* x0 = (const float*)d_in[0];
    const int* cl[6];
    for (int i = 0; i < 6; ++i) cl[i] = (const int*)d_in[1 + i];
    const int* src[5];
    const int* dst[5];
    const float* ps[5];
    const float* W[5];
    const float* root[5];
    const float* bias[5];
    for (int i = 0; i < 5; ++i) {
        src[i] = (const int*)d_in[7 + 6 * i];
        dst[i] = (const int*)d_in[8 + 6 * i];
        ps[i] = (const float*)d_in[9 + 6 * i];
        W[i] = (const float*)d_in[10 + 6 * i];
        root[i] = (const float*)d_in[11 + 6 * i];
        bias[i] = (const float*)d_in[12 + 6 * i];
    }
    const float* fc1_w = (const float*)d_in[37];
    const float* fc1_b = (const float*)d_in[38];
    const float* fc2_w = (const float*)d_in[39];
    const float* fc2_b = (const float*)d_in[40];

    const int N1 = 20000, N2 = 6000, N3 = 2000, N4 = 700, N5 = 256;
    const int E1 = 160000, E2 = 48000, E3 = 16000, E4 = 5600, E5 = 2048;
    const int UB2 = E2 * 8 / 64 + 126, UB3 = E3 * 8 / 64 + 126;
    const int UB4 = E4 * 8 / 64 + 126, UB5 = E5 * 8 / 64 + 126;

    unsigned* base = (unsigned*)d_ws;
    size_t o = 0;
    auto alloc = [&](size_t n) { unsigned* p = base + o; o += n; return p; };
    // ---- zero block (single fill) ----
    unsigned* xp1m = alloc(N1);
    unsigned* xp2m = alloc((size_t)N2 * 32);
    unsigned* xp3m = alloc((size_t)N3 * 64);
    unsigned* xp4m = alloc((size_t)N4 * 64);
    unsigned* xp5m = alloc((size_t)N5 * 64);
    unsigned* xp6m = alloc(8 * 128);
    int* hist2 = (int*)alloc(125);
    int* hist3 = (int*)alloc(125);
    int* hist4 = (int*)alloc(125);
    int* hist5 = (int*)alloc(125);
    int* ideg1 = (int*)alloc(N1);
    int* ideg2 = (int*)alloc(N2);
    int* ideg3 = (int*)alloc(N3);
    int* ideg4 = (int*)alloc(N4);
    int* ideg5 = (int*)alloc(N5);
    size_t zero_words = o;
    // ---- non-zeroed dedicated ----
    int* erow1 = (int*)alloc(N1 + 1);
    int* erow2 = (int*)alloc(N2 + 1);
    int* erow3 = (int*)alloc(N3 + 1);
    int* erow4 = (int*)alloc(N4 + 1);
    int* erow5 = (int*)alloc(N5 + 1);
    int* ecur1 = (int*)alloc(N1);
    int* entc2 = (int*)alloc(N2);
    int* entc3 = (int*)alloc(N3);
    int* entc4 = (int*)alloc(N4);
    int* entc5 = (int*)alloc(N5);
    int* bs2 = (int*)alloc(126);
    int* bs3 = (int*)alloc(126);
    int* bs4 = (int*)alloc(126);
    int* bs5 = (int*)alloc(126);
    int* cu2 = (int*)alloc(125);
    int* cu3 = (int*)alloc(125);
    int* cu4 = (int*)alloc(125);
    int* cu5 = (int*)alloc(125);
    int* nt2 = (int*)alloc(1);
    int* nt3 = (int*)alloc(1);
    int* nt4 = (int*)alloc(1);
    int* nt5 = (int*)alloc(1);
    int* tk2 = (int*)alloc(UB2);
    int* tl2 = (int*)alloc(UB2);
    int* tk3 = (int*)alloc(UB3);
    int* tl3 = (int*)alloc(UB3);
    int* tk4 = (int*)alloc(UB4);
    int* tl4 = (int*)alloc(UB4);
    int* tk5 = (int*)alloc(UB5);
    int* tl5 = (int*)alloc(UB5);
    float* fc1o = (float*)alloc(512);
    unsigned* arena = base + o;
    size_t arenaWords = (ws_size / 4 > o) ? (ws_size / 4 - o) : 0;

    // slice width per level: need 8E*(2 + S/2) words in the arena
    auto fitS = [&](int E, int maxS, int minS) {
        int S = maxS;
        while (S > minS && (size_t)8 * E * (size_t)(2 + S / 2) > arenaWords) S >>= 1;
        return S;
    };
    int S2 = fitS(E2, 64, 16);
    int S3 = fitS(E3, 64, 16);
    int S4 = fitS(E4, 64, 16);
    int S5 = fitS(E5, 128, 32);

    // ---- 1. one fill for monos + hists + idegs ----
    fill_u32<<<((int)zero_words + 255) / 256, 256, 0, stream>>>(base, (int)zero_words, 0u);

    // ---- 2. batched hist/deg + pool0 ----
    int nb2 = (E2 + 255) / 256, nb3 = (E3 + 255) / 256, nb4 = (E4 + 255) / 256,
        nb5 = (E5 + 255) / 256, nb1 = (E1 + 255) / 256, nb0 = (80000 + 255) / 256;
    int B2 = nb2, B23 = B2 + nb3, B234 = B23 + nb4, B2345 = B234 + nb5;
    int B1end = B2345 + nb1;
    hist_all<<<B1end + nb0, 256, 0, stream>>>(ps[1], dst[1], E2, hist2, ideg2, ps[2], dst[2], E3,
                                              hist3, ideg3, ps[3], dst[3], E4, hist4, ideg4,
                                              ps[4], dst[4], E5, hist5, ideg5, dst[0], E1, ideg1,
                                              x0, cl[0], 80000, xp1m, B2, B23, B234, B2345,
                                              B1end);

    // ---- 3. batched prefix/scan ----
    prep_all<<<9, 256, 0, stream>>>(hist2, bs2, cu2, tk2, tl2, nt2, hist3, bs3, cu3, tk3, tl3,
                                    nt3, hist4, bs4, cu4, tk4, tl4, nt4, hist5, bs5, cu5, tk5,
                                    tl5, nt5, ideg1, N1, erow1, ecur1, ideg2, N2, erow2, entc2,
                                    ideg3, N3, erow3, entc3, ideg4, N4, erow4, entc4, ideg5, N5,
                                    erow5, entc5);

    // ---- level 1 (psrc payload sort lives in the arena) ----
    {
        uint4* psrc = (uint4*)arena;  // 4*E1 words, free before level 2 begins
        scatter_dst1<<<nb1, 256, 0, stream>>>(dst[0], src[0], ps[0], E1, ecur1, psrc);
        l1_aggregate<<<2048, 256, 0, stream>>>(xp1m, psrc, W[0], erow1, root[0], bias[0], cl[1],
                                               xp2m, N1);
    }

#define RUN_SLICES(CIN, COUT, SS, xpm, Wl, rootl, biasl, clnx, xnx, N, tk, tl, bs, nt, erowL, ub) \
    for (int s = 0; s < (COUT) / (SS); ++s) {                                                     \
        bin_gemm<CIN, COUT, SS><<<((ub) < 2048 ? (ub) : 2048), 256, 0, stream>>>(                 \
            xpm, Wl, s * (SS), spack, sq, tk, tl, bs, nt, msgs);                                  \
        agg_finish<CIN, COUT, SS><<<((N) + 3) / 4, 256, 0, stream>>>(                             \
            msgs, erowL, xpm, rootl, biasl, clnx, xnx, N, s * (SS));                              \
    }

    // ---- level 2: Cin32 Cout64 -> pool into xp3m ----
    {
        unsigned* spack = arena;
        int* sq = (int*)(arena + (size_t)8 * E2);
        unsigned* msgs = arena + (size_t)16 * E2;
        scatter_lvl<<<nb2, 256, 0, stream>>>(ps[1], src[1], dst[1], E2, cu2, entc2, spack, sq);
        if (S2 == 64) {
            RUN_SLICES(32, 64, 64, xp2m, W[1], root[1], bias[1], cl[2], xp3m, N2, tk2, tl2, bs2, nt2, erow2, UB2)
        } else if (S2 == 32) {
            RUN_SLICES(32, 64, 32, xp2m, W[1], root[1], bias[1], cl[2], xp3m, N2, tk2, tl2, bs2, nt2, erow2, UB2)
        } else {
            RUN_SLICES(32, 64, 16, xp2m, W[1], root[1], bias[1], cl[2], xp3m, N2, tk2, tl2, bs2, nt2, erow2, UB2)
        }
    }
    // ---- level 3: Cin64 Cout64 -> pool into xp4m ----
    {
        unsigned* spack = arena;
        int* sq = (int*)(arena + (size_t)8 * E3);
        unsigned* msgs = arena + (size_t)16 * E3;
        scatter_lvl<<<nb3, 256, 0, stream>>>(ps[2], src[2], dst[2], E3, cu3, entc3, spack, sq);
        if (S3 == 64) {
            RUN_SLICES(64, 64, 64, xp3m, W[2], root[2], bias[2], cl[3], xp4m, N3, tk3, tl3, bs3, nt3, erow3, UB3)
        } else if (S3 == 32) {
            RUN_SLICES(64, 64, 32, xp3m, W[2], root[2], bias[2], cl[3], xp4m, N3, tk3, tl3, bs3, nt3, erow3, UB3)
        } else {
            RUN_SLICES(64, 64, 16, xp3m, W[2], root[2], bias[2], cl[3], xp4m, N3, tk3, tl3, bs3, nt3, erow3, UB3)
        }
    }
    // ---- level 4: Cin64 Cout64 -> pool into xp5m ----
    {
        unsigned* spack = arena;
        int* sq = (int*)(arena + (size_t)8 * E4);
        unsigned* msgs = arena + (size_t)16 * E4;
        scatter_lvl<<<nb4, 256, 0, stream>>>(ps[3], src[3], dst[3], E4, cu4, entc4, spack, sq);
        if (S4 == 64) {
            RUN_SLICES(64, 64, 64, xp4m, W[3], root[3], bias[3], cl[4], xp5m, N4, tk4, tl4, bs4, nt4, erow4, UB4)
        } else if (S4 == 32) {
            RUN_SLICES(64, 64, 32, xp4m, W[3], root[3], bias[3], cl[4], xp5m, N4, tk4, tl4, bs4, nt4, erow4, UB4)
        } else {
            RUN_SLICES(64, 64, 16, xp4m, W[3], root[3], bias[3], cl[4], xp5m, N4, tk4, tl4, bs4, nt4, erow4, UB4)
        }
    }
    // ---- level 5: Cin64 Cout128 -> pool into xp6m ----
    {
        unsigned* spack = arena;
        int* sq = (int*)(arena + (size_t)8 * E5);
        unsigned* msgs = arena + (size_t)16 * E5;
        scatter_lvl<<<nb5, 256, 0, stream>>>(ps[4], src[4], dst[4], E5, cu5, entc5, spack, sq);
        if (S5 == 128) {
            RUN_SLICES(64, 128, 128, xp5m, W[4], root[4], bias[4], cl[5], xp6m, N5, tk5, tl5, bs5, nt5, erow5, UB5)
        } else if (S5 == 64) {
            RUN_SLICES(64, 128, 64, xp5m, W[4], root[4], bias[4], cl[5], xp6m, N5, tk5, tl5, bs5, nt5, erow5, UB5)
        } else {
            RUN_SLICES(64, 128, 32, xp5m, W[4], root[4], bias[4], cl[5], xp6m, N5, tk5, tl5, bs5, nt5, erow5, UB5)
        }
    }
#undef RUN_SLICES

    // ---- FC head ----
    fc1_kernel<<<8, 256, 0, stream>>>(xp6m, fc1_w, fc1_b, fc1o);
    fc2_lsm<<<1, 512, 0, stream>>>(fc1o, fc2_w, fc2_b, (float*)d_out);
}

// Round 7
// 281.638 us; speedup vs baseline: 2.2598x; 1.1163x over previous
//
#include <hip/hip_runtime.h>
#include <hip/hip_fp16.h>
#include <math.h>

#define DEVINL __device__ __forceinline__

// ---------------------------------------------------------------------------
// SplineCNN net, round 6:
//  - ordered prefix scans replaced by wave-claimed node ranges (atomicAdd per
//    wave + shfl scan): round 5's prep_all spent 47us in per-thread chunked
//    loops (one cold-read latency per element); claiming needs no ordering.
//  - everything else as round 5: fused pool-into-next-level epilogues, fp16
//    dst-positioned msgs, k-binned LDS GEMM, batched hist, parallel FC head.
// ---------------------------------------------------------------------------

DEVINL unsigned f2mono(float f) {
    unsigned u = __float_as_uint(f);
    return (u & 0x80000000u) ? ~u : (u | 0x80000000u);
}
DEVINL float mono2x(unsigned m) {  // sentinel 0 == empty segment -> 0.0
    if (m == 0u) return 0.f;
    unsigned u = (m & 0x80000000u) ? (m & 0x7FFFFFFFu) : ~m;
    return __uint_as_float(u);
}
DEVINL unsigned short f2h(float f) {
    union { __half h; unsigned short u; } c;
    c.h = __float2half_rn(f);
    return c.u;
}
DEVINL float h2f(unsigned short s) {
    union { unsigned short u; __half h; } c;
    c.u = s;
    return __half2float(c.h);
}

__global__ void fill_u32(unsigned* __restrict__ p, int n, unsigned v) {
    int i = blockIdx.x * blockDim.x + threadIdx.x;
    if (i < n) p[i] = v;
}

DEVINL void decode3(float p0, float p1, float p2, int ff[3], float fr[3]) {
    float pp[3] = {p0 * 4.f, p1 * 4.f, p2 * 4.f};  // (K-1) = 4
#pragma unroll
    for (int d = 0; d < 3; ++d) {
        float f = floorf(pp[d]);
        ff[d] = (int)f;
        fr[d] = pp[d] - f;
    }
}
DEVINL void pseudo_decode(const float* __restrict__ ps, int e, int ff[3], float fr[3]) {
    decode3(ps[(size_t)e * 3], ps[(size_t)e * 3 + 1], ps[(size_t)e * 3 + 2], ff, fr);
}

DEVINL void corner_iw(const int ff[3], const float fr[3], int bits, float& w, int& idx) {
    w = 1.f;
    idx = 0;
    int pw = 1;
#pragma unroll
    for (int d = 0; d < 3; ++d) {
        int b = (bits >> d) & 1;
        w *= b ? fr[d] : (1.f - fr[d]);
        int fd = ff[d] + b;
        fd = fd < 0 ? 0 : (fd > 4 ? 4 : fd);
        idx += fd * pw;
        pw *= 5;
    }
}

// ---------------- batched hist (L2-5) + deg (all) + pool0 --------------------
DEVINL void hist_seg(const float* __restrict__ ps, const int* __restrict__ dst, int E,
                     int* __restrict__ hist, int* __restrict__ ideg, int bofs, int t,
                     int* __restrict__ lh) {
    for (int i = t; i < 125; i += 256) lh[i] = 0;
    __syncthreads();
    int e = bofs * 256 + t;
    if (e < E) {
        int ff[3];
        float fr[3];
        pseudo_decode(ps, e, ff, fr);
#pragma unroll
        for (int b = 0; b < 8; ++b) {
            float w;
            int k;
            corner_iw(ff, fr, b, w, k);
            atomicAdd(&lh[k], 1);
        }
        atomicAdd(&ideg[dst[e]], 1);
    }
    __syncthreads();
    for (int i = t; i < 125; i += 256)
        if (lh[i]) atomicAdd(&hist[i], lh[i]);
}

__global__ void hist_all(const float* ps2, const int* dst2, int E2, int* hist2, int* ideg2,
                         const float* ps3, const int* dst3, int E3, int* hist3, int* ideg3,
                         const float* ps4, const int* dst4, int E4, int* hist4, int* ideg4,
                         const float* ps5, const int* dst5, int E5, int* hist5, int* ideg5,
                         const int* dst1, int E1, int* ideg1, const float* x0, const int* cl1,
                         int n0, unsigned* xp1m, int B2, int B23, int B234, int B2345,
                         int B1end) {
    __shared__ int lh[125];
    int b = blockIdx.x, t = threadIdx.x;
    if (b < B2) hist_seg(ps2, dst2, E2, hist2, ideg2, b, t, lh);
    else if (b < B23) hist_seg(ps3, dst3, E3, hist3, ideg3, b - B2, t, lh);
    else if (b < B234) hist_seg(ps4, dst4, E4, hist4, ideg4, b - B23, t, lh);
    else if (b < B2345) hist_seg(ps5, dst5, E5, hist5, ideg5, b - B234, t, lh);
    else if (b < B1end) {
        int e = (b - B2345) * 256 + t;
        if (e < E1) atomicAdd(&ideg1[dst1[e]], 1);
    } else {
        int i = (b - B1end) * 256 + t;
        if (i < n0) atomicMax(&xp1m[cl1[i]], f2mono(x0[i]));
    }
}

// ---------------- claim + bin-prefix (all wave-parallel, no long loops) ------
// node ranges: coalesced ideg load, wave shfl-scan, one atomicAdd per wave.
DEVINL void claim_seg(const int* __restrict__ cnt, int N, int* __restrict__ gcur,
                      int* __restrict__ ebase, int* __restrict__ cur, int mult, int bofs,
                      int t) {
    int i = bofs * 256 + t;
    int lane = t & 63;
    int v = (i < N) ? cnt[i] : 0;
    int s = v;
#pragma unroll
    for (int st = 1; st < 64; st <<= 1) {
        int u = __shfl_up(s, st);
        if (lane >= st) s += u;
    }
    int wtot = __shfl(s, 63);
    int base = 0;
    if (lane == 0 && wtot > 0) base = atomicAdd(gcur, wtot);
    base = __shfl(base, 0);
    int start = base + s - v;
    if (i < N) {
        ebase[i] = start;
        cur[i] = mult * start;
    }
}

__global__ void claim_all(const int* ideg1, int N1, int* g1, int* eb1, int* cur1,
                          const int* ideg2, int N2, int* g2, int* eb2, int* cur2,
                          const int* ideg3, int N3, int* g3, int* eb3, int* cur3,
                          const int* ideg4, int N4, int* g4, int* eb4, int* cur4,
                          const int* ideg5, int N5, int* g5, int* eb5, int* cur5,
                          const int* h2, int* bs2, int* cu2, int* tk2, int* tl2, int* nt2,
                          const int* h3, int* bs3, int* cu3, int* tk3, int* tl3, int* nt3,
                          const int* h4, int* bs4, int* cu4, int* tk4, int* tl4, int* nt4,
                          const int* h5, int* bs5, int* cu5, int* tk5, int* tl5, int* nt5,
                          int C1, int C12, int C123, int C1234, int C12345) {
    int b = blockIdx.x, t = threadIdx.x;
    if (b < C1) { claim_seg(ideg1, N1, g1, eb1, cur1, 1, b, t); return; }
    if (b < C12) { claim_seg(ideg2, N2, g2, eb2, cur2, 8, b - C1, t); return; }
    if (b < C123) { claim_seg(ideg3, N3, g3, eb3, cur3, 8, b - C12, t); return; }
    if (b < C1234) { claim_seg(ideg4, N4, g4, eb4, cur4, 8, b - C123, t); return; }
    if (b < C12345) { claim_seg(ideg5, N5, g5, eb5, cur5, 8, b - C1234, t); return; }
    // bin prefix + tile lists (125 bins, one wave-scan, short store loops)
    int s = b - C12345;
    const int* hist;
    int *bs, *cu, *tk, *tl, *ntp;
    if (s == 0) { hist = h2; bs = bs2; cu = cu2; tk = tk2; tl = tl2; ntp = nt2; }
    else if (s == 1) { hist = h3; bs = bs3; cu = cu3; tk = tk3; tl = tl3; ntp = nt3; }
    else if (s == 2) { hist = h4; bs = bs4; cu = cu4; tk = tk4; tl = tl4; ntp = nt4; }
    else { hist = h5; bs = bs5; cu = cu5; tk = tk5; tl = tl5; ntp = nt5; }
    int lane = t & 63, wv = t >> 6;
    int h = 0, th = 0;
    if (t < 125) {
        h = hist[t];
        th = (h + 63) >> 6;
    }
    unsigned long long v = (unsigned long long)(unsigned)h |
                           ((unsigned long long)(unsigned)th << 32);
#pragma unroll
    for (int st = 1; st < 64; st <<= 1) {
        unsigned long long u = __shfl_up(v, st);
        if (lane >= st) v += u;
    }
    __shared__ unsigned long long wtot[4];
    if (lane == 63) wtot[wv] = v;
    __syncthreads();
    unsigned long long woff = 0;
    for (int w2 = 0; w2 < wv; ++w2) woff += wtot[w2];
    unsigned long long incl = v + woff;
    int eh = (int)(incl & 0xFFFFFFFFull) - h;
    int eth = (int)(incl >> 32) - th;
    if (t < 125) {
        bs[t] = eh;
        cu[t] = eh;
        for (int j = 0; j < th; ++j) {
            tk[eth + j] = t;
            tl[eth + j] = eh + 64 * j;
        }
    }
    if (t == 124) {
        bs[125] = eh + h;
        *ntp = eth + th;
    }
}

// level 1: counting-sort edge payloads (ps0,ps1,ps2,src) into claimed ranges
__global__ void scatter_dst1(const int* __restrict__ dst, const int* __restrict__ src,
                             const float* __restrict__ ps, int E, int* __restrict__ ecur,
                             uint4* __restrict__ psrc) {
    int e = blockIdx.x * blockDim.x + threadIdx.x;
    if (e >= E) return;
    int q = atomicAdd(&ecur[dst[e]], 1);
    uint4 v;
    v.x = __float_as_uint(ps[(size_t)e * 3 + 0]);
    v.y = __float_as_uint(ps[(size_t)e * 3 + 1]);
    v.z = __float_as_uint(ps[(size_t)e * 3 + 2]);
    v.w = (unsigned)src[e];
    psrc[q] = v;
}

// per-level entry scatter: spack at k-sorted pos p; sq[p] = dst-claimed pos q
__global__ void scatter_lvl(const float* __restrict__ ps, const int* __restrict__ src,
                            const int* __restrict__ dst, int E, int* __restrict__ cursor,
                            int* __restrict__ entcur, unsigned* __restrict__ spack,
                            int* __restrict__ sq) {
    __shared__ int lh[125], lbase[125];
    int t = threadIdx.x;
    for (int i = t; i < 125; i += 256) lh[i] = 0;
    __syncthreads();
    int e = blockIdx.x * 256 + t;
    int mk[8], ml[8];
    float mw[8];
    if (e < E) {
        int ff[3];
        float fr[3];
        pseudo_decode(ps, e, ff, fr);
#pragma unroll
        for (int b = 0; b < 8; ++b) {
            corner_iw(ff, fr, b, mw[b], mk[b]);
            ml[b] = atomicAdd(&lh[mk[b]], 1);
        }
    }
    __syncthreads();
    for (int i = t; i < 125; i += 256) {
        int c = lh[i];
        lbase[i] = c ? atomicAdd(&cursor[i], c) : 0;
    }
    __syncthreads();
    if (e < E) {
        int s = src[e];
        int qbase = atomicAdd(&entcur[dst[e]], 8);
#pragma unroll
        for (int b = 0; b < 8; ++b) {
            int p = lbase[mk[b]] + ml[b];
            spack[p] = ((unsigned)s << 16) | (unsigned)f2h(mw[b]);
            sq[p] = qbase + b;
        }
    }
}

// k-binned GEMM: W[k] Cout-slice in LDS (reused 64x), w-scaled x rows in LDS;
// each output row is scatter-WRITTEN (fp16) to its dst-claimed position sq[p].
template <int CIN, int COUT, int S>
__global__ __launch_bounds__(256) void bin_gemm(
    const unsigned* __restrict__ xm, const float* __restrict__ W, int c0,
    const unsigned* __restrict__ spack, const int* __restrict__ sq, const int* __restrict__ tk,
    const int* __restrict__ tl, const int* __restrict__ bs, const int* __restrict__ ntp,
    unsigned* __restrict__ msgs) {
    constexpr int C4 = S / 4;
    constexpr int NTR = 256 / C4;
    constexpr int RT = 64 / NTR;
    constexpr int XST = CIN + 4;
    __shared__ float Wl[CIN * S];
    __shared__ float xs[64 * XST];
    int t = threadIdx.x;
    int ntiles = *ntp;
    int tc = t % C4, tr = t / C4;
    int rr = t >> 2, g = t & 3;
    for (int tile = blockIdx.x; tile < ntiles; tile += gridDim.x) {
        int k = tk[tile], lo = tl[tile];
        int m = min(64, bs[k + 1] - lo);
        __syncthreads();
        float4* Wl4 = (float4*)Wl;
        const float* Wk = W + (size_t)k * CIN * COUT + c0;
        for (int i4 = t; i4 < CIN * C4; i4 += 256) {
            int row = i4 / C4, cg = i4 % C4;
            Wl4[i4] = ((const float4*)(Wk + (size_t)row * COUT))[cg];
        }
        if (rr < m) {
            unsigned sp = spack[lo + rr];
            int s = sp >> 16;
            float wv = h2f((unsigned short)(sp & 0xFFFFu));
            const uint4* xr = (const uint4*)(xm + (size_t)s * CIN);
            float4* xd = (float4*)(xs + rr * XST);
#pragma unroll
            for (int i = g; i < CIN / 4; i += 4) {
                uint4 mv = xr[i];
                float4 v;
                v.x = mono2x(mv.x) * wv;
                v.y = mono2x(mv.y) * wv;
                v.z = mono2x(mv.z) * wv;
                v.w = mono2x(mv.w) * wv;
                xd[i] = v;
            }
        }
        __syncthreads();
        float4 acc[RT];
#pragma unroll
        for (int r = 0; r < RT; ++r) acc[r] = make_float4(0.f, 0.f, 0.f, 0.f);
#pragma unroll 4
        for (int i = 0; i < CIN; ++i) {
            float4 wv = Wl4[i * C4 + tc];
#pragma unroll
            for (int r = 0; r < RT; ++r) {
                float xv = xs[(tr + r * NTR) * XST + i];
                acc[r].x += xv * wv.x;
                acc[r].y += xv * wv.y;
                acc[r].z += xv * wv.z;
                acc[r].w += xv * wv.w;
            }
        }
#pragma unroll
        for (int r = 0; r < RT; ++r) {
            int row = tr + r * NTR;
            if (row < m) {
                int q = sq[lo + row];
                uint2 pv;
                pv.x = (unsigned)f2h(acc[r].x) | ((unsigned)f2h(acc[r].y) << 16);
                pv.y = (unsigned)f2h(acc[r].z) | ((unsigned)f2h(acc[r].w) << 16);
                ((uint2*)(msgs + (size_t)q * (S / 2)))[tc] = pv;
            }
        }
    }
}

// wave per node: contiguous claimed-range message stream, butterfly reduce,
// deg-norm + root + bias + ELU, then POOL: atomicMax into next level's mono buf.
template <int CIN, int COUT, int S>
__global__ __launch_bounds__(256) void agg_finish(
    const unsigned* __restrict__ msgsU, const int* __restrict__ ebase,
    const int* __restrict__ ideg, const unsigned* __restrict__ xm,
    const float* __restrict__ root, const float* __restrict__ bias,
    const int* __restrict__ clnext, unsigned* __restrict__ xnext, int N, int c0) {
    const unsigned short* msgs = (const unsigned short*)msgsU;
    constexpr int WPC = S / 4;  // writer lanes; lane grp owns cols 4*grp..4*grp+3
    constexpr int G = 64 / WPC; // lanes sharing one column group
    int t = threadIdx.x;
    int lane = t & 63;
    int wid = blockIdx.x * 4 + (t >> 6);
    int nw = gridDim.x * 4;
    int grp = lane & (WPC - 1);
    int sub = lane / WPC;
    for (int d = wid; d < N; d += nw) {
        int lo = ebase[d];
        int len = ideg[d];
        float dv = (float)max(len, 1);
        float4 acc = make_float4(0.f, 0.f, 0.f, 0.f);
        // root term, pre-scaled by dv (split over the G lanes sharing cols)
        const float* rbase = root + c0 + 4 * grp;
        for (int i = sub; i < CIN; i += G) {
            float xv = mono2x(xm[(size_t)d * CIN + i]) * dv;
            const float* rp = rbase + (size_t)i * COUT;
            acc.x += xv * rp[0];
            acc.y += xv * rp[1];
            acc.z += xv * rp[2];
            acc.w += xv * rp[3];
        }
        // contiguous message stream: 64 lanes x 4 halfs = 256 halfs per step
        size_t h1 = (size_t)(lo + len) * 8 * S;
        for (size_t h = (size_t)lo * 8 * S + (size_t)lane * 4; h < h1; h += 256) {
            uint2 u = *(const uint2*)(msgs + h);
            acc.x += h2f((unsigned short)(u.x & 0xFFFFu));
            acc.y += h2f((unsigned short)(u.x >> 16));
            acc.z += h2f((unsigned short)(u.y & 0xFFFFu));
            acc.w += h2f((unsigned short)(u.y >> 16));
        }
#pragma unroll
        for (int s = WPC; s < 64; s <<= 1) {
            acc.x += __shfl_xor(acc.x, s);
            acc.y += __shfl_xor(acc.y, s);
            acc.z += __shfl_xor(acc.z, s);
            acc.w += __shfl_xor(acc.w, s);
        }
        if (lane < WPC) {
            const float* bp = bias + c0 + 4 * grp;
            float4 v;
            v.x = acc.x / dv + bp[0];
            v.y = acc.y / dv + bp[1];
            v.z = acc.z / dv + bp[2];
            v.w = acc.w / dv + bp[3];
            v.x = v.x > 0.f ? v.x : expm1f(v.x);
            v.y = v.y > 0.f ? v.y : expm1f(v.y);
            v.z = v.z > 0.f ? v.z : expm1f(v.z);
            v.w = v.w > 0.f ? v.w : expm1f(v.w);
            unsigned* xp = xnext + (size_t)clnext[d] * COUT + c0 + 4 * grp;
            atomicMax(&xp[0], f2mono(v.x));
            atomicMax(&xp[1], f2mono(v.y));
            atomicMax(&xp[2], f2mono(v.z));
            atomicMax(&xp[3], f2mono(v.w));
        }
    }
}

// ---------------- level 1 (Cin=1, Cout=32): fused conv + pool into xp2m -------
__global__ __launch_bounds__(256) void l1_aggregate(
    const unsigned* __restrict__ xm, const uint4* __restrict__ psrc,
    const float* __restrict__ W, const int* __restrict__ ebase, const int* __restrict__ ideg,
    const float* __restrict__ root, const float* __restrict__ bias,
    const int* __restrict__ cl2, unsigned* __restrict__ xp2m, int N) {
    __shared__ float Wl[125 * 32];
    int t = threadIdx.x;
    {
        const float4* Wg = (const float4*)W;
        float4* Wd = (float4*)Wl;
        for (int i = t; i < 125 * 32 / 4; i += 256) Wd[i] = Wg[i];
    }
    __syncthreads();
    int lane = t & 63, c = lane & 31, half = lane >> 5;
    int wid = blockIdx.x * 4 + (t >> 6);
    int nw = gridDim.x * 4;
    for (int d = wid; d < N; d += nw) {
        int lo = ebase[d], hi = lo + ideg[d];
        float acc = 0.f;
        for (int j = lo + half; j < hi; j += 2) {
            uint4 pv = psrc[j];
            int ff[3];
            float fr[3];
            decode3(__uint_as_float(pv.x), __uint_as_float(pv.y), __uint_as_float(pv.z), ff, fr);
            float wsum = 0.f;
#pragma unroll
            for (int b = 0; b < 8; ++b) {
                float w;
                int idx;
                corner_iw(ff, fr, b, w, idx);
                wsum += w * Wl[idx * 32 + c];
            }
            acc += mono2x(xm[pv.w]) * wsum;
        }
        acc += __shfl_down(acc, 32);
        if (half == 0) {
            float dv = (float)max(hi - lo, 1);
            float v = acc / dv + mono2x(xm[d]) * root[c] + bias[c];
            v = v > 0.f ? v : expm1f(v);
            atomicMax(&xp2m[(size_t)cl2[d] * 32 + c], f2mono(v));
        }
    }
}

// fc1: [1024] @ [1024,512] + b, ELU — K-split across 8 blocks x 256 threads
__global__ __launch_bounds__(256) void fc1_kernel(const unsigned* __restrict__ xm,
                                                  const float* __restrict__ w,
                                                  const float* __restrict__ b,
                                                  float* __restrict__ out) {
    __shared__ float xsh[1024];
    __shared__ float sh[4][64];
    int t = threadIdx.x;
    for (int i = t; i < 1024; i += 256) xsh[i] = mono2x(xm[i]);
    __syncthreads();
    int ol = t & 63, kk = t >> 6;
    int o = blockIdx.x * 64 + ol;
    int i0 = kk * 256;
    float acc = 0.f;
#pragma unroll 8
    for (int i = 0; i < 256; ++i) acc += xsh[i0 + i] * w[(size_t)(i0 + i) * 512 + o];
    sh[kk][ol] = acc;
    __syncthreads();
    if (kk == 0) {
        float v = sh[0][ol] + sh[1][ol] + sh[2][ol] + sh[3][ol] + b[o];
        out[o] = v > 0.f ? v : expm1f(v);
    }
}

// fc2 (512->10) + log_softmax, parallel: thread i owns row i
__global__ __launch_bounds__(512) void fc2_lsm(const float* __restrict__ x,
                                               const float* __restrict__ w,
                                               const float* __restrict__ b,
                                               float* __restrict__ out) {
    __shared__ float red[8][10];
    int t = threadIdx.x, lane = t & 63, wv = t >> 6;
    float xv = x[t];
    const float* wr = w + (size_t)t * 10;
    float acc[10];
#pragma unroll
    for (int c = 0; c < 10; ++c) acc[c] = xv * wr[c];
#pragma unroll
    for (int s = 32; s > 0; s >>= 1) {
#pragma unroll
        for (int c = 0; c < 10; ++c) acc[c] += __shfl_down(acc[c], s);
    }
    if (lane == 0) {
#pragma unroll
        for (int c = 0; c < 10; ++c) red[wv][c] = acc[c];
    }
    __syncthreads();
    if (t == 0) {
        float z[10];
        for (int c = 0; c < 10; ++c) {
            float s2 = b[c];
            for (int w2 = 0; w2 < 8; ++w2) s2 += red[w2][c];
            z[c] = s2;
        }
        float m = z[0];
        for (int i = 1; i < 10; ++i) m = fmaxf(m, z[i]);
        float s2 = 0.f;
        for (int i = 0; i < 10; ++i) s2 += expf(z[i] - m);
        float l = logf(s2);
        for (int i = 0; i < 10; ++i) out[i] = z[i] - m - l;
    }
}

// ---------------------------------------------------------------------------

extern "C" void kernel_launch(void* const* d_in, const int* in_sizes, int n_in,
                              void* d_out, int out_size, void* d_ws, size_t ws_size,
                              hipStream_t stream) {
    (void)in_sizes; (void)n_in; (void)out_size;
    const float* x0 = (const float*)d_in[0];
    const int* cl[6];
    for (int i = 0; i < 6; ++i) cl[i] = (const int*)d_in[1 + i];
    const int* src[5];
    const int* dst[5];
    const float* ps[5];
    const float* W[5];
    const float* root[5];
    const float* bias[5];
    for (int i = 0; i < 5; ++i) {
        src[i] = (const int*)d_in[7 + 6 * i];
        dst[i] = (const int*)d_in[8 + 6 * i];
        ps[i] = (const float*)d_in[9 + 6 * i];
        W[i] = (const float*)d_in[10 + 6 * i];
        root[i] = (const float*)d_in[11 + 6 * i];
        bias[i] = (const float*)d_in[12 + 6 * i];
    }
    const float* fc1_w = (const float*)d_in[37];
    const float* fc1_b = (const float*)d_in[38];
    const float* fc2_w = (const float*)d_in[39];
    const float* fc2_b = (const float*)d_in[40];

    const int N1 = 20000, N2 = 6000, N3 = 2000, N4 = 700, N5 = 256;
    const int E1 = 160000, E2 = 48000, E3 = 16000, E4 = 5600, E5 = 2048;
    const int UB2 = E2 * 8 / 64 + 126, UB3 = E3 * 8 / 64 + 126;
    const int UB4 = E4 * 8 / 64 + 126, UB5 = E5 * 8 / 64 + 126;

    unsigned* base = (unsigned*)d_ws;
    size_t o = 0;
    auto alloc = [&](size_t n) { unsigned* p = base + o; o += n; return p; };
    // ---- zero block (single fill) ----
    unsigned* xp1m = alloc(N1);
    unsigned* xp2m = alloc((size_t)N2 * 32);
    unsigned* xp3m = alloc((size_t)N3 * 64);
    unsigned* xp4m = alloc((size_t)N4 * 64);
    unsigned* xp5m = alloc((size_t)N5 * 64);
    unsigned* xp6m = alloc(8 * 128);
    int* hist2 = (int*)alloc(125);
    int* hist3 = (int*)alloc(125);
    int* hist4 = (int*)alloc(125);
    int* hist5 = (int*)alloc(125);
    int* ideg1 = (int*)alloc(N1);
    int* ideg2 = (int*)alloc(N2);
    int* ideg3 = (int*)alloc(N3);
    int* ideg4 = (int*)alloc(N4);
    int* ideg5 = (int*)alloc(N5);
    int* gcur = (int*)alloc(5);  // per-level claim cursors
    size_t zero_words = o;
    // ---- non-zeroed dedicated ----
    int* eb1 = (int*)alloc(N1);
    int* eb2 = (int*)alloc(N2);
    int* eb3 = (int*)alloc(N3);
    int* eb4 = (int*)alloc(N4);
    int* eb5 = (int*)alloc(N5);
    int* ecur1 = (int*)alloc(N1);
    int* entc2 = (int*)alloc(N2);
    int* entc3 = (int*)alloc(N3);
    int* entc4 = (int*)alloc(N4);
    int* entc5 = (int*)alloc(N5);
    int* bs2 = (int*)alloc(126);
    int* bs3 = (int*)alloc(126);
    int* bs4 = (int*)alloc(126);
    int* bs5 = (int*)alloc(126);
    int* cu2 = (int*)alloc(125);
    int* cu3 = (int*)alloc(125);
    int* cu4 = (int*)alloc(125);
    int* cu5 = (int*)alloc(125);
    int* nt2 = (int*)alloc(1);
    int* nt3 = (int*)alloc(1);
    int* nt4 = (int*)alloc(1);
    int* nt5 = (int*)alloc(1);
    int* tk2 = (int*)alloc(UB2);
    int* tl2 = (int*)alloc(UB2);
    int* tk3 = (int*)alloc(UB3);
    int* tl3 = (int*)alloc(UB3);
    int* tk4 = (int*)alloc(UB4);
    int* tl4 = (int*)alloc(UB4);
    int* tk5 = (int*)alloc(UB5);
    int* tl5 = (int*)alloc(UB5);
    float* fc1o = (float*)alloc(512);
    unsigned* arena = base + o;
    size_t arenaWords = (ws_size / 4 > o) ? (ws_size / 4 - o) : 0;

    // slice width per level: need 8E*(2 + S/2) words in the arena
    auto fitS = [&](int E, int maxS, int minS) {
        int S = maxS;
        while (S > minS && (size_t)8 * E * (size_t)(2 + S / 2) > arenaWords) S >>= 1;
        return S;
    };
    int S2 = fitS(E2, 64, 16);
    int S3 = fitS(E3, 64, 16);
    int S4 = fitS(E4, 64, 16);
    int S5 = fitS(E5, 128, 32);

    // ---- 1. one fill for monos + hists + idegs + cursors ----
    fill_u32<<<((int)zero_words + 255) / 256, 256, 0, stream>>>(base, (int)zero_words, 0u);

    // ---- 2. batched hist/deg + pool0 ----
    int nb2 = (E2 + 255) / 256, nb3 = (E3 + 255) / 256, nb4 = (E4 + 255) / 256,
        nb5 = (E5 + 255) / 256, nb1 = (E1 + 255) / 256, nb0 = (80000 + 255) / 256;
    int B2 = nb2, B23 = B2 + nb3, B234 = B23 + nb4, B2345 = B234 + nb5;
    int B1end = B2345 + nb1;
    hist_all<<<B1end + nb0, 256, 0, stream>>>(ps[1], dst[1], E2, hist2, ideg2, ps[2], dst[2], E3,
                                              hist3, ideg3, ps[3], dst[3], E4, hist4, ideg4,
                                              ps[4], dst[4], E5, hist5, ideg5, dst[0], E1, ideg1,
                                              x0, cl[0], 80000, xp1m, B2, B23, B234, B2345,
                                              B1end);

    // ---- 3. claims + bin prefixes (wave-parallel) ----
    int nc1 = (N1 + 255) / 256, nc2 = (N2 + 255) / 256, nc3 = (N3 + 255) / 256,
        nc4 = (N4 + 255) / 256, nc5 = (N5 + 255) / 256;
    int C1 = nc1, C12 = C1 + nc2, C123 = C12 + nc3, C1234 = C123 + nc4, C12345 = C1234 + nc5;
    claim_all<<<C12345 + 4, 256, 0, stream>>>(
        ideg1, N1, gcur + 0, eb1, ecur1, ideg2, N2, gcur + 1, eb2, entc2, ideg3, N3, gcur + 2,
        eb3, entc3, ideg4, N4, gcur + 3, eb4, entc4, ideg5, N5, gcur + 4, eb5, entc5, hist2, bs2,
        cu2, tk2, tl2, nt2, hist3, bs3, cu3, tk3, tl3, nt3, hist4, bs4, cu4, tk4, tl4, nt4,
        hist5, bs5, cu5, tk5, tl5, nt5, C1, C12, C123, C1234, C12345);

    // ---- level 1 (psrc payload sort lives in the arena) ----
    {
        uint4* psrc = (uint4*)arena;  // 4*E1 words, free before level 2 begins
        scatter_dst1<<<nb1, 256, 0, stream>>>(dst[0], src[0], ps[0], E1, ecur1, psrc);
        l1_aggregate<<<2048, 256, 0, stream>>>(xp1m, psrc, W[0], eb1, ideg1, root[0], bias[0],
                                               cl[1], xp2m, N1);
    }

#define RUN_SLICES(CIN, COUT, SS, xpm, Wl, rootl, biasl, clnx, xnx, N, tk, tl, bs, nt, ebL, idL, ub) \
    for (int s = 0; s < (COUT) / (SS); ++s) {                                                        \
        bin_gemm<CIN, COUT, SS><<<((ub) < 2048 ? (ub) : 2048), 256, 0, stream>>>(                    \
            xpm, Wl, s * (SS), spack, sq, tk, tl, bs, nt, msgs);                                     \
        agg_finish<CIN, COUT, SS><<<((N) + 3) / 4, 256, 0, stream>>>(                                \
            msgs, ebL, idL, xpm, rootl, biasl, clnx, xnx, N, s * (SS));                              \
    }

    // ---- level 2: Cin32 Cout64 -> pool into xp3m ----
    {
        unsigned* spack = arena;
        int* sq = (int*)(arena + (size_t)8 * E2);
        unsigned* msgs = arena + (size_t)16 * E2;
        scatter_lvl<<<nb2, 256, 0, stream>>>(ps[1], src[1], dst[1], E2, cu2, entc2, spack, sq);
        if (S2 == 64) {
            RUN_SLICES(32, 64, 64, xp2m, W[1], root[1], bias[1], cl[2], xp3m, N2, tk2, tl2, bs2, nt2, eb2, ideg2, UB2)
        } else if (S2 == 32) {
            RUN_SLICES(32, 64, 32, xp2m, W[1], root[1], bias[1], cl[2], xp3m, N2, tk2, tl2, bs2, nt2, eb2, ideg2, UB2)
        } else {
            RUN_SLICES(32, 64, 16, xp2m, W[1], root[1], bias[1], cl[2], xp3m, N2, tk2, tl2, bs2, nt2, eb2, ideg2, UB2)
        }
    }
    // ---- level 3: Cin64 Cout64 -> pool into xp4m ----
    {
        unsigned* spack = arena;
        int* sq = (int*)(arena + (size_t)8 * E3);
        unsigned* msgs = arena + (size_t)16 * E3;
        scatter_lvl<<<nb3, 256, 0, stream>>>(ps[2], src[2], dst[2], E3, cu3, entc3, spack, sq);
        if (S3 == 64) {
            RUN_SLICES(64, 64, 64, xp3m, W[2], root[2], bias[2], cl[3], xp4m, N3, tk3, tl3, bs3, nt3, eb3, ideg3, UB3)
        } else if (S3 == 32) {
            RUN_SLICES(64, 64, 32, xp3m, W[2], root[2], bias[2], cl[3], xp4m, N3, tk3, tl3, bs3, nt3, eb3, ideg3, UB3)
        } else {
            RUN_SLICES(64, 64, 16, xp3m, W[2], root[2], bias[2], cl[3], xp4m, N3, tk3, tl3, bs3, nt3, eb3, ideg3, UB3)
        }
    }
    // ---- level 4: Cin64 Cout64 -> pool into xp5m ----
    {
        unsigned* spack = arena;
        int* sq = (int*)(arena + (size_t)8 * E4);
        unsigned* msgs = arena + (size_t)16 * E4;
        scatter_lvl<<<nb4, 256, 0, stream>>>(ps[3], src[3], dst[3], E4, cu4, entc4, spack, sq);
        if (S4 == 64) {
            RUN_SLICES(64, 64, 64, xp4m, W[3], root[3], bias[3], cl[4], xp5m, N4, tk4, tl4, bs4, nt4, eb4, ideg4, UB4)
        } else if (S4 == 32) {
            RUN_SLICES(64, 64, 32, xp4m, W[3], root[3], bias[3], cl[4], xp5m, N4, tk4, tl4, bs4, nt4, eb4, ideg4, UB4)
        } else {
            RUN_SLICES(64, 64, 16, xp4m, W[3], root[3], bias[3], cl[4], xp5m, N4, tk4, tl4, bs4, nt4, eb4, ideg4, UB4)
        }
    }
    // ---- level 5: Cin64 Cout128 -> pool into xp6m ----
    {
        unsigned* spack = arena;
        int* sq = (int*)(arena + (size_t)8 * E5);
        unsigned* msgs = arena + (size_t)16 * E5;
        scatter_lvl<<<nb5, 256, 0, stream>>>(ps[4], src[4], dst[4], E5, cu5, entc5, spack, sq);
        if (S5 == 128) {
            RUN_SLICES(64, 128, 128, xp5m, W[4], root[4], bias[4], cl[5], xp6m, N5, tk5, tl5, bs5, nt5, eb5, ideg5, UB5)
        } else if (S5 == 64) {
            RUN_SLICES(64, 128, 64, xp5m, W[4], root[4], bias[4], cl[5], xp6m, N5, tk5, tl5, bs5, nt5, eb5, ideg5, UB5)
        } else {
            RUN_SLICES(64, 128, 32, xp5m, W[4], root[4], bias[4], cl[5], xp6m, N5, tk5, tl5, bs5, nt5, eb5, ideg5, UB5)
        }
    }
#undef RUN_SLICES

    // ---- FC head ----
    fc1_kernel<<<8, 256, 0, stream>>>(xp6m, fc1_w, fc1_b, fc1o);
    fc2_lsm<<<1, 512, 0, stream>>>(fc1o, fc2_w, fc2_b, (float*)d_out);
}

// Round 8
// 279.250 us; speedup vs baseline: 2.2791x; 1.0085x over previous
//
#include <hip/hip_runtime.h>
#include <hip/hip_fp16.h>
#include <math.h>

#define DEVINL __device__ __forceinline__

// ---------------------------------------------------------------------------
// SplineCNN net, round 7: cell-binned conv (1 entry per EDGE, not per corner).
//  - edges grouped by f-cell (all 8 corner kernel indices shared); bin_gemm
//    stages 8 W-slices in LDS and emits one Cout row per edge -> msgs traffic,
//    x gathers, scatter stores and hist atomics all /8 vs round 6.
//  - xs stored transposed in LDS so each thread's RT rows load as one float4;
//    every W ds_read_b128 is shared across RT rows (register blocking).
//  - all level scatters merged into one dispatch; ~15 dispatches total.
// ---------------------------------------------------------------------------

DEVINL unsigned f2mono(float f) {
    unsigned u = __float_as_uint(f);
    return (u & 0x80000000u) ? ~u : (u | 0x80000000u);
}
DEVINL float mono2x(unsigned m) {  // sentinel 0 == empty segment -> 0.0
    if (m == 0u) return 0.f;
    unsigned u = (m & 0x80000000u) ? (m & 0x7FFFFFFFu) : ~m;
    return __uint_as_float(u);
}
DEVINL unsigned short f2h(float f) {
    union { __half h; unsigned short u; } c;
    c.h = __float2half_rn(f);
    return c.u;
}
DEVINL float h2f(unsigned short s) {
    union { unsigned short u; __half h; } c;
    c.u = s;
    return __half2float(c.h);
}

__global__ void fill_u32(unsigned* __restrict__ p, int n, unsigned v) {
    int i = blockIdx.x * blockDim.x + threadIdx.x;
    if (i < n) p[i] = v;
}

DEVINL void decode3(float p0, float p1, float p2, int ff[3], float fr[3]) {
    float pp[3] = {p0 * 4.f, p1 * 4.f, p2 * 4.f};  // (K-1) = 4
#pragma unroll
    for (int d = 0; d < 3; ++d) {
        int fi = (int)floorf(pp[d]);
        fi = fi < 0 ? 0 : (fi > 4 ? 4 : fi);
        ff[d] = fi;
        fr[d] = pp[d] - (float)fi;
    }
}
DEVINL void pseudo_decode(const float* __restrict__ ps, int e, int ff[3], float fr[3]) {
    decode3(ps[(size_t)e * 3], ps[(size_t)e * 3 + 1], ps[(size_t)e * 3 + 2], ff, fr);
}

DEVINL void corner_iw(const int ff[3], const float fr[3], int bits, float& w, int& idx) {
    w = 1.f;
    idx = 0;
    int pw = 1;
#pragma unroll
    for (int d = 0; d < 3; ++d) {
        int b = (bits >> d) & 1;
        w *= b ? fr[d] : (1.f - fr[d]);
        int fd = ff[d] + b;
        fd = fd < 0 ? 0 : (fd > 4 ? 4 : fd);
        idx += fd * pw;
        pw *= 5;
    }
}

// ---------------- batched hist (cell id, L2-5) + deg (all) + pool0 -----------
DEVINL void hist_seg(const float* __restrict__ ps, const int* __restrict__ dst, int E,
                     int* __restrict__ hist, int* __restrict__ ideg, int bofs, int t,
                     int* __restrict__ lh) {
    for (int i = t; i < 125; i += 256) lh[i] = 0;
    __syncthreads();
    int e = bofs * 256 + t;
    if (e < E) {
        int ff[3];
        float fr[3];
        pseudo_decode(ps, e, ff, fr);
        int cid = ff[0] + 5 * ff[1] + 25 * ff[2];
        atomicAdd(&lh[cid], 1);
        atomicAdd(&ideg[dst[e]], 1);
    }
    __syncthreads();
    for (int i = t; i < 125; i += 256)
        if (lh[i]) atomicAdd(&hist[i], lh[i]);
}

__global__ void hist_all(const float* ps2, const int* dst2, int E2, int* hist2, int* ideg2,
                         const float* ps3, const int* dst3, int E3, int* hist3, int* ideg3,
                         const float* ps4, const int* dst4, int E4, int* hist4, int* ideg4,
                         const float* ps5, const int* dst5, int E5, int* hist5, int* ideg5,
                         const int* dst1, int E1, int* ideg1, const float* x0, const int* cl1,
                         int n0, unsigned* xp1m, int B2, int B23, int B234, int B2345,
                         int B1end) {
    __shared__ int lh[125];
    int b = blockIdx.x, t = threadIdx.x;
    if (b < B2) hist_seg(ps2, dst2, E2, hist2, ideg2, b, t, lh);
    else if (b < B23) hist_seg(ps3, dst3, E3, hist3, ideg3, b - B2, t, lh);
    else if (b < B234) hist_seg(ps4, dst4, E4, hist4, ideg4, b - B23, t, lh);
    else if (b < B2345) hist_seg(ps5, dst5, E5, hist5, ideg5, b - B234, t, lh);
    else if (b < B1end) {
        int e = (b - B2345) * 256 + t;
        if (e < E1) atomicAdd(&ideg1[dst1[e]], 1);
    } else {
        int i = (b - B1end) * 256 + t;
        if (i < n0) atomicMax(&xp1m[cl1[i]], f2mono(x0[i]));
    }
}

// ---------------- claims + bin-prefixes (wave-parallel) ----------------------
DEVINL void claim_seg(const int* __restrict__ cnt, int N, int* __restrict__ gcur,
                      int* __restrict__ ebase, int* __restrict__ cur, int bofs, int t) {
    int i = bofs * 256 + t;
    int lane = t & 63;
    int v = (i < N) ? cnt[i] : 0;
    int s = v;
#pragma unroll
    for (int st = 1; st < 64; st <<= 1) {
        int u = __shfl_up(s, st);
        if (lane >= st) s += u;
    }
    int wtot = __shfl(s, 63);
    int base = 0;
    if (lane == 0 && wtot > 0) base = atomicAdd(gcur, wtot);
    base = __shfl(base, 0);
    int start = base + s - v;
    if (i < N) {
        ebase[i] = start;
        cur[i] = start;
    }
}

__global__ void claim_all(const int* ideg1, int N1, int* g1, int* eb1, int* cur1,
                          const int* ideg2, int N2, int* g2, int* eb2, int* cur2,
                          const int* ideg3, int N3, int* g3, int* eb3, int* cur3,
                          const int* ideg4, int N4, int* g4, int* eb4, int* cur4,
                          const int* ideg5, int N5, int* g5, int* eb5, int* cur5,
                          const int* h2, int* bs2, int* cu2, int* tk2, int* tl2, int* nt2,
                          const int* h3, int* bs3, int* cu3, int* tk3, int* tl3, int* nt3,
                          const int* h4, int* bs4, int* cu4, int* tk4, int* tl4, int* nt4,
                          const int* h5, int* bs5, int* cu5, int* tk5, int* tl5, int* nt5,
                          int C1, int C12, int C123, int C1234, int C12345) {
    int b = blockIdx.x, t = threadIdx.x;
    if (b < C1) { claim_seg(ideg1, N1, g1, eb1, cur1, b, t); return; }
    if (b < C12) { claim_seg(ideg2, N2, g2, eb2, cur2, b - C1, t); return; }
    if (b < C123) { claim_seg(ideg3, N3, g3, eb3, cur3, b - C12, t); return; }
    if (b < C1234) { claim_seg(ideg4, N4, g4, eb4, cur4, b - C123, t); return; }
    if (b < C12345) { claim_seg(ideg5, N5, g5, eb5, cur5, b - C1234, t); return; }
    int s = b - C12345;
    const int* hist;
    int *bs, *cu, *tk, *tl, *ntp;
    int TMv = (s == 0) ? 64 : 32;
    if (s == 0) { hist = h2; bs = bs2; cu = cu2; tk = tk2; tl = tl2; ntp = nt2; }
    else if (s == 1) { hist = h3; bs = bs3; cu = cu3; tk = tk3; tl = tl3; ntp = nt3; }
    else if (s == 2) { hist = h4; bs = bs4; cu = cu4; tk = tk4; tl = tl4; ntp = nt4; }
    else { hist = h5; bs = bs5; cu = cu5; tk = tk5; tl = tl5; ntp = nt5; }
    int lane = t & 63, wv = t >> 6;
    int h = 0, th = 0;
    if (t < 125) {
        h = hist[t];
        th = (h + TMv - 1) / TMv;
    }
    unsigned long long v = (unsigned long long)(unsigned)h |
                           ((unsigned long long)(unsigned)th << 32);
#pragma unroll
    for (int st = 1; st < 64; st <<= 1) {
        unsigned long long u = __shfl_up(v, st);
        if (lane >= st) v += u;
    }
    __shared__ unsigned long long wtot[4];
    if (lane == 63) wtot[wv] = v;
    __syncthreads();
    unsigned long long woff = 0;
    for (int w2 = 0; w2 < wv; ++w2) woff += wtot[w2];
    unsigned long long incl = v + woff;
    int eh = (int)(incl & 0xFFFFFFFFull) - h;
    int eth = (int)(incl >> 32) - th;
    if (t < 125) {
        bs[t] = eh;
        cu[t] = eh;
        for (int j = 0; j < th; ++j) {
            tk[eth + j] = t;
            tl[eth + j] = eh + TMv * j;
        }
    }
    if (t == 124) {
        bs[125] = eh + h;
        *ntp = eth + th;
    }
}

// ---------------- batched scatter: L1 payloads + L2-5 edge records -----------
DEVINL void scat_seg(const float* __restrict__ ps, const int* __restrict__ src,
                     const int* __restrict__ dst, int E, int* __restrict__ cursor,
                     int* __restrict__ entcur, uint4* __restrict__ rec, int* __restrict__ sq,
                     int bofs, int t, int* __restrict__ lh, int* __restrict__ lbase) {
    for (int i = t; i < 125; i += 256) lh[i] = 0;
    __syncthreads();
    int e = bofs * 256 + t;
    int cid = 0, ml = 0;
    int ff[3];
    float fr[3];
    if (e < E) {
        pseudo_decode(ps, e, ff, fr);
        cid = ff[0] + 5 * ff[1] + 25 * ff[2];
        ml = atomicAdd(&lh[cid], 1);
    }
    __syncthreads();
    for (int i = t; i < 125; i += 256) {
        int c = lh[i];
        lbase[i] = c ? atomicAdd(&cursor[i], c) : 0;
    }
    __syncthreads();
    if (e < E) {
        int p = lbase[cid] + ml;
        int q = atomicAdd(&entcur[dst[e]], 1);
        uint4 v;
        v.x = (unsigned)src[e];
        v.y = __float_as_uint(fr[0]);
        v.z = __float_as_uint(fr[1]);
        v.w = __float_as_uint(fr[2]);
        rec[p] = v;
        sq[p] = q;
    }
}

__global__ void scatter_all(
    const int* dst1, const int* src1, const float* ps1, int E1, int* ecur1, uint4* psrc,
    const float* ps2, const int* src2, const int* dst2, int E2, int* cu2, int* entc2,
    uint4* rec2, int* sq2, const float* ps3, const int* src3, const int* dst3, int E3, int* cu3,
    int* entc3, uint4* rec3, int* sq3, const float* ps4, const int* src4, const int* dst4,
    int E4, int* cu4, int* entc4, uint4* rec4, int* sq4, const float* ps5, const int* src5,
    const int* dst5, int E5, int* cu5, int* entc5, uint4* rec5, int* sq5, int A1, int A12,
    int A123, int A1234) {
    __shared__ int lh[125], lbase[125];
    int b = blockIdx.x, t = threadIdx.x;
    if (b < A1) {
        int e = b * 256 + t;
        if (e < E1) {
            int q = atomicAdd(&ecur1[dst1[e]], 1);
            uint4 v;
            v.x = __float_as_uint(ps1[(size_t)e * 3 + 0]);
            v.y = __float_as_uint(ps1[(size_t)e * 3 + 1]);
            v.z = __float_as_uint(ps1[(size_t)e * 3 + 2]);
            v.w = (unsigned)src1[e];
            psrc[q] = v;
        }
    } else if (b < A12)
        scat_seg(ps2, src2, dst2, E2, cu2, entc2, rec2, sq2, b - A1, t, lh, lbase);
    else if (b < A123)
        scat_seg(ps3, src3, dst3, E3, cu3, entc3, rec3, sq3, b - A12, t, lh, lbase);
    else if (b < A1234)
        scat_seg(ps4, src4, dst4, E4, cu4, entc4, rec4, sq4, b - A123, t, lh, lbase);
    else
        scat_seg(ps5, src5, dst5, E5, cu5, entc5, rec5, sq5, b - A1234, t, lh, lbase);
}

// cell-binned GEMM: tile = TM edges of one f-cell; 8 W-slices staged in LDS
// (BPASS at a time); per edge msg = sum_b w_b (x[src] @ W_kb), fp16 row
// scatter-written to dst-claimed position sq[p].
template <int CIN, int COUT, int S, int TM, int BPASS>
__global__ __launch_bounds__(256) void bin_gemm_cell(
    const unsigned* __restrict__ xm, const float* __restrict__ W, int c0,
    const uint4* __restrict__ rec, const int* __restrict__ sq, const int* __restrict__ tk,
    const int* __restrict__ tl, const int* __restrict__ bs, const int* __restrict__ ntp,
    unsigned* __restrict__ msgs) {
    constexpr int C4 = S / 4;
    constexpr int NTR = 256 / C4;
    constexpr int RT = TM / NTR;
    constexpr int XTT = TM + RT;  // keeps float4/float2 alignment of row blocks
    constexpr int NPASS = 8 / BPASS;
    constexpr int G = 256 / TM;
    __shared__ float Wl[BPASS * CIN * S];
    __shared__ float xs_t[CIN * XTT];
    __shared__ float ws[TM * 8];
    __shared__ int kbs[8];
    int t = threadIdx.x;
    int ntiles = *ntp;
    int tc = t % C4, tr = t / C4;
    int rr = t / G, g = t % G;
    int row0 = tr * RT;
    float4* Wl4 = (float4*)Wl;
    for (int tile = blockIdx.x; tile < ntiles; tile += gridDim.x) {
        int cell = tk[tile], lo = tl[tile];
        int m = min(TM, bs[cell + 1] - lo);
        __syncthreads();  // previous tile's readers done
        if (t < 8) {
            int f0 = cell % 5, f1 = (cell / 5) % 5, f2 = cell / 25;
            int k0 = min(f0 + (t & 1), 4), k1 = min(f1 + ((t >> 1) & 1), 4),
                k2 = min(f2 + (t >> 2), 4);
            kbs[t] = k0 + 5 * k1 + 25 * k2;
        }
        if (rr < m) {
            uint4 rv = rec[lo + rr];
            if (g == 0) {
                float fr0 = __uint_as_float(rv.y), fr1 = __uint_as_float(rv.z),
                      fr2 = __uint_as_float(rv.w);
#pragma unroll
                for (int b = 0; b < 8; ++b)
                    ws[rr * 8 + b] = ((b & 1) ? fr0 : 1.f - fr0) * ((b & 2) ? fr1 : 1.f - fr1) *
                                     ((b & 4) ? fr2 : 1.f - fr2);
            }
            const uint4* xr = (const uint4*)(xm + (size_t)rv.x * CIN);
            for (int i = g; i < CIN / 4; i += G) {
                uint4 mv = xr[i];
                xs_t[(4 * i + 0) * XTT + rr] = mono2x(mv.x);
                xs_t[(4 * i + 1) * XTT + rr] = mono2x(mv.y);
                xs_t[(4 * i + 2) * XTT + rr] = mono2x(mv.z);
                xs_t[(4 * i + 3) * XTT + rr] = mono2x(mv.w);
            }
        } else if (g == 0) {
#pragma unroll
            for (int b = 0; b < 8; ++b) ws[rr * 8 + b] = 0.f;
        }
        float4 acc[RT];
#pragma unroll
        for (int r = 0; r < RT; ++r) acc[r] = make_float4(0.f, 0.f, 0.f, 0.f);
        for (int pass = 0; pass < NPASS; ++pass) {
            __syncthreads();  // staging done (pass0) / prev-pass Wl reads done
            for (int i4 = t; i4 < BPASS * CIN * C4; i4 += 256) {
                int b = i4 / (CIN * C4);
                int rem = i4 - b * (CIN * C4);
                int rw = rem / C4, cg = rem - rw * C4;
                Wl4[i4] = ((const float4*)(W + (size_t)kbs[pass * BPASS + b] * CIN * COUT +
                                           (size_t)rw * COUT + c0))[cg];
            }
            __syncthreads();
            float wsr[BPASS][RT];
#pragma unroll
            for (int b = 0; b < BPASS; ++b)
#pragma unroll
                for (int r = 0; r < RT; ++r) wsr[b][r] = ws[(row0 + r) * 8 + pass * BPASS + b];
#pragma unroll 4
            for (int i = 0; i < CIN; ++i) {
                float xf[RT];
                if constexpr (RT == 4) {
                    float4 xv = *(const float4*)&xs_t[i * XTT + row0];
                    xf[0] = xv.x; xf[1] = xv.y; xf[2] = xv.z; xf[3] = xv.w;
                } else {
                    float2 xv = *(const float2*)&xs_t[i * XTT + row0];
                    xf[0] = xv.x; xf[1] = xv.y;
                }
#pragma unroll
                for (int b = 0; b < BPASS; ++b) {
                    float4 wv = Wl4[(b * CIN + i) * C4 + tc];
#pragma unroll
                    for (int r = 0; r < RT; ++r) {
                        float mm = wsr[b][r] * xf[r];
                        acc[r].x += mm * wv.x;
                        acc[r].y += mm * wv.y;
                        acc[r].z += mm * wv.z;
                        acc[r].w += mm * wv.w;
                    }
                }
            }
        }
#pragma unroll
        for (int r = 0; r < RT; ++r) {
            int row = row0 + r;
            if (row < m) {
                int q = sq[lo + row];
                uint2 pv;
                pv.x = (unsigned)f2h(acc[r].x) | ((unsigned)f2h(acc[r].y) << 16);
                pv.y = (unsigned)f2h(acc[r].z) | ((unsigned)f2h(acc[r].w) << 16);
                ((uint2*)(msgs + (size_t)q * (S / 2)))[tc] = pv;
            }
        }
    }
}

// wave per node: contiguous claimed-range message stream (1 row per EDGE),
// butterfly reduce, deg-norm + root + bias + ELU, pool into next mono buffer.
template <int CIN, int COUT, int S>
__global__ __launch_bounds__(256) void agg_finish(
    const unsigned* __restrict__ msgsU, const int* __restrict__ ebase,
    const int* __restrict__ ideg, const unsigned* __restrict__ xm,
    const float* __restrict__ root, const float* __restrict__ bias,
    const int* __restrict__ clnext, unsigned* __restrict__ xnext, int N, int c0) {
    const unsigned short* msgs = (const unsigned short*)msgsU;
    constexpr int WPC = S / 4;
    constexpr int G = 64 / WPC;
    int t = threadIdx.x;
    int lane = t & 63;
    int wid = blockIdx.x * 4 + (t >> 6);
    int nw = gridDim.x * 4;
    int grp = lane & (WPC - 1);
    int sub = lane / WPC;
    for (int d = wid; d < N; d += nw) {
        int lo = ebase[d];
        int len = ideg[d];
        float dv = (float)max(len, 1);
        float4 acc = make_float4(0.f, 0.f, 0.f, 0.f);
        const float* rbase = root + c0 + 4 * grp;
        for (int i = sub; i < CIN; i += G) {
            float xv = mono2x(xm[(size_t)d * CIN + i]) * dv;
            const float* rp = rbase + (size_t)i * COUT;
            acc.x += xv * rp[0];
            acc.y += xv * rp[1];
            acc.z += xv * rp[2];
            acc.w += xv * rp[3];
        }
        size_t h1 = (size_t)(lo + len) * S;
        for (size_t h = (size_t)lo * S + (size_t)lane * 4; h < h1; h += 256) {
            uint2 u = *(const uint2*)(msgs + h);
            acc.x += h2f((unsigned short)(u.x & 0xFFFFu));
            acc.y += h2f((unsigned short)(u.x >> 16));
            acc.z += h2f((unsigned short)(u.y & 0xFFFFu));
            acc.w += h2f((unsigned short)(u.y >> 16));
        }
#pragma unroll
        for (int s = WPC; s < 64; s <<= 1) {
            acc.x += __shfl_xor(acc.x, s);
            acc.y += __shfl_xor(acc.y, s);
            acc.z += __shfl_xor(acc.z, s);
            acc.w += __shfl_xor(acc.w, s);
        }
        if (lane < WPC) {
            const float* bp = bias + c0 + 4 * grp;
            float4 v;
            v.x = acc.x / dv + bp[0];
            v.y = acc.y / dv + bp[1];
            v.z = acc.z / dv + bp[2];
            v.w = acc.w / dv + bp[3];
            v.x = v.x > 0.f ? v.x : expm1f(v.x);
            v.y = v.y > 0.f ? v.y : expm1f(v.y);
            v.z = v.z > 0.f ? v.z : expm1f(v.z);
            v.w = v.w > 0.f ? v.w : expm1f(v.w);
            unsigned* xp = xnext + (size_t)clnext[d] * COUT + c0 + 4 * grp;
            atomicMax(&xp[0], f2mono(v.x));
            atomicMax(&xp[1], f2mono(v.y));
            atomicMax(&xp[2], f2mono(v.z));
            atomicMax(&xp[3], f2mono(v.w));
        }
    }
}

// ---------------- level 1 (Cin=1, Cout=32): fused conv + pool into xp2m -------
__global__ __launch_bounds__(256) void l1_aggregate(
    const unsigned* __restrict__ xm, const uint4* __restrict__ psrc,
    const float* __restrict__ W, const int* __restrict__ ebase, const int* __restrict__ ideg,
    const float* __restrict__ root, const float* __restrict__ bias,
    const int* __restrict__ cl2, unsigned* __restrict__ xp2m, int N) {
    __shared__ float Wl[125 * 32];
    int t = threadIdx.x;
    {
        const float4* Wg = (const float4*)W;
        float4* Wd = (float4*)Wl;
        for (int i = t; i < 125 * 32 / 4; i += 256) Wd[i] = Wg[i];
    }
    __syncthreads();
    int lane = t & 63, c = lane & 31, half = lane >> 5;
    int wid = blockIdx.x * 4 + (t >> 6);
    int nw = gridDim.x * 4;
    for (int d = wid; d < N; d += nw) {
        int lo = ebase[d], hi = lo + ideg[d];
        float acc = 0.f;
        for (int j = lo + half; j < hi; j += 2) {
            uint4 pv = psrc[j];
            int ff[3];
            float fr[3];
            decode3(__uint_as_float(pv.x), __uint_as_float(pv.y), __uint_as_float(pv.z), ff, fr);
            float wsum = 0.f;
#pragma unroll
            for (int b = 0; b < 8; ++b) {
                float w;
                int idx;
                corner_iw(ff, fr, b, w, idx);
                wsum += w * Wl[idx * 32 + c];
            }
            acc += mono2x(xm[pv.w]) * wsum;
        }
        acc += __shfl_down(acc, 32);
        if (half == 0) {
            float dv = (float)max(hi - lo, 1);
            float v = acc / dv + mono2x(xm[d]) * root[c] + bias[c];
            v = v > 0.f ? v : expm1f(v);
            atomicMax(&xp2m[(size_t)cl2[d] * 32 + c], f2mono(v));
        }
    }
}

// fc1: [1024] @ [1024,512] + b, ELU — K-split across 8 blocks x 256 threads
__global__ __launch_bounds__(256) void fc1_kernel(const unsigned* __restrict__ xm,
                                                  const float* __restrict__ w,
                                                  const float* __restrict__ b,
                                                  float* __restrict__ out) {
    __shared__ float xsh[1024];
    __shared__ float sh[4][64];
    int t = threadIdx.x;
    for (int i = t; i < 1024; i += 256) xsh[i] = mono2x(xm[i]);
    __syncthreads();
    int ol = t & 63, kk = t >> 6;
    int o = blockIdx.x * 64 + ol;
    int i0 = kk * 256;
    float acc = 0.f;
#pragma unroll 8
    for (int i = 0; i < 256; ++i) acc += xsh[i0 + i] * w[(size_t)(i0 + i) * 512 + o];
    sh[kk][ol] = acc;
    __syncthreads();
    if (kk == 0) {
        float v = sh[0][ol] + sh[1][ol] + sh[2][ol] + sh[3][ol] + b[o];
        out[o] = v > 0.f ? v : expm1f(v);
    }
}

// fc2 (512->10) + log_softmax, parallel: thread i owns row i
__global__ __launch_bounds__(512) void fc2_lsm(const float* __restrict__ x,
                                               const float* __restrict__ w,
                                               const float* __restrict__ b,
                                               float* __restrict__ out) {
    __shared__ float red[8][10];
    int t = threadIdx.x, lane = t & 63, wv = t >> 6;
    float xv = x[t];
    const float* wr = w + (size_t)t * 10;
    float acc[10];
#pragma unroll
    for (int c = 0; c < 10; ++c) acc[c] = xv * wr[c];
#pragma unroll
    for (int s = 32; s > 0; s >>= 1) {
#pragma unroll
        for (int c = 0; c < 10; ++c) acc[c] += __shfl_down(acc[c], s);
    }
    if (lane == 0) {
#pragma unroll
        for (int c = 0; c < 10; ++c) red[wv][c] = acc[c];
    }
    __syncthreads();
    if (t == 0) {
        float z[10];
        for (int c = 0; c < 10; ++c) {
            float s2 = b[c];
            for (int w2 = 0; w2 < 8; ++w2) s2 += red[w2][c];
            z[c] = s2;
        }
        float m = z[0];
        for (int i = 1; i < 10; ++i) m = fmaxf(m, z[i]);
        float s2 = 0.f;
        for (int i = 0; i < 10; ++i) s2 += expf(z[i] - m);
        float l = logf(s2);
        for (int i = 0; i < 10; ++i) out[i] = z[i] - m - l;
    }
}

// ---------------------------------------------------------------------------

extern "C" void kernel_launch(void* const* d_in, const int* in_sizes, int n_in,
                              void* d_out, int out_size, void* d_ws, size_t ws_size,
                              hipStream_t stream) {
    (void)in_sizes; (void)n_in; (void)out_size; (void)ws_size;
    const float* x0 = (const float*)d_in[0];
    const int* cl[6];
    for (int i = 0; i < 6; ++i) cl[i] = (const int*)d_in[1 + i];
    const int* src[5];
    const int* dst[5];
    const float* ps[5];
    const float* W[5];
    const float* root[5];
    const float* bias[5];
    for (int i = 0; i < 5; ++i) {
        src[i] = (const int*)d_in[7 + 6 * i];
        dst[i] = (const int*)d_in[8 + 6 * i];
        ps[i] = (const float*)d_in[9 + 6 * i];
        W[i] = (const float*)d_in[10 + 6 * i];
        root[i] = (const float*)d_in[11 + 6 * i];
        bias[i] = (const float*)d_in[12 + 6 * i];
    }
    const float* fc1_w = (const float*)d_in[37];
    const float* fc1_b = (const float*)d_in[38];
    const float* fc2_w = (const float*)d_in[39];
    const float* fc2_b = (const float*)d_in[40];

    const int N1 = 20000, N2 = 6000, N3 = 2000, N4 = 700, N5 = 256;
    const int E1 = 160000, E2 = 48000, E3 = 16000, E4 = 5600, E5 = 2048;
    const int UB2 = E2 / 64 + 126, UB3 = E3 / 32 + 126, UB4 = E4 / 32 + 126,
              UB5 = E5 / 32 + 126;

    unsigned* base = (unsigned*)d_ws;
    size_t o = 0;
    auto alloc = [&](size_t n) { unsigned* p = base + o; o += n; return p; };
    // ---- zero block (single fill) ----
    unsigned* xp1m = alloc(N1);
    unsigned* xp2m = alloc((size_t)N2 * 32);
    unsigned* xp3m = alloc((size_t)N3 * 64);
    unsigned* xp4m = alloc((size_t)N4 * 64);
    unsigned* xp5m = alloc((size_t)N5 * 64);
    unsigned* xp6m = alloc(8 * 128);
    int* hist2 = (int*)alloc(125);
    int* hist3 = (int*)alloc(125);
    int* hist4 = (int*)alloc(125);
    int* hist5 = (int*)alloc(125);
    int* ideg1 = (int*)alloc(N1);
    int* ideg2 = (int*)alloc(N2);
    int* ideg3 = (int*)alloc(N3);
    int* ideg4 = (int*)alloc(N4);
    int* ideg5 = (int*)alloc(N5);
    int* gcur = (int*)alloc(5);
    size_t zero_words = o;
    // ---- non-zeroed dedicated ----
    int* eb1 = (int*)alloc(N1);
    int* eb2 = (int*)alloc(N2);
    int* eb3 = (int*)alloc(N3);
    int* eb4 = (int*)alloc(N4);
    int* eb5 = (int*)alloc(N5);
    int* ecur1 = (int*)alloc(N1);
    int* entc2 = (int*)alloc(N2);
    int* entc3 = (int*)alloc(N3);
    int* entc4 = (int*)alloc(N4);
    int* entc5 = (int*)alloc(N5);
    int* bs2 = (int*)alloc(126);
    int* bs3 = (int*)alloc(126);
    int* bs4 = (int*)alloc(126);
    int* bs5 = (int*)alloc(126);
    int* cu2 = (int*)alloc(125);
    int* cu3 = (int*)alloc(125);
    int* cu4 = (int*)alloc(125);
    int* cu5 = (int*)alloc(125);
    int* nt2 = (int*)alloc(1);
    int* nt3 = (int*)alloc(1);
    int* nt4 = (int*)alloc(1);
    int* nt5 = (int*)alloc(1);
    int* tk2 = (int*)alloc(UB2);
    int* tl2 = (int*)alloc(UB2);
    int* tk3 = (int*)alloc(UB3);
    int* tl3 = (int*)alloc(UB3);
    int* tk4 = (int*)alloc(UB4);
    int* tl4 = (int*)alloc(UB4);
    int* tk5 = (int*)alloc(UB5);
    int* tl5 = (int*)alloc(UB5);
    float* fc1o = (float*)alloc(512);
    o = (o + 3) & ~(size_t)3;  // 16B-align the uint4 region
    uint4* rec2 = (uint4*)alloc((size_t)4 * E2);
    int* sq2 = (int*)alloc(E2);
    uint4* rec3 = (uint4*)alloc((size_t)4 * E3);
    int* sq3 = (int*)alloc(E3);
    uint4* rec4 = (uint4*)alloc((size_t)4 * E4);
    int* sq4 = (int*)alloc(E4);
    uint4* rec5 = (uint4*)alloc((size_t)4 * E5);
    int* sq5 = (int*)alloc(E5);
    uint4* psrc = (uint4*)alloc((size_t)4 * E1);
    unsigned* msgs = alloc((size_t)E2 * 32);  // max of E_L * S/2 across levels

    // ---- 1. one fill for monos + hists + idegs + cursors ----
    fill_u32<<<((int)zero_words + 255) / 256, 256, 0, stream>>>(base, (int)zero_words, 0u);

    // ---- 2. batched hist/deg + pool0 ----
    int nb2 = (E2 + 255) / 256, nb3 = (E3 + 255) / 256, nb4 = (E4 + 255) / 256,
        nb5 = (E5 + 255) / 256, nb1 = (E1 + 255) / 256, nb0 = (80000 + 255) / 256;
    int B2 = nb2, B23 = B2 + nb3, B234 = B23 + nb4, B2345 = B234 + nb5;
    int B1end = B2345 + nb1;
    hist_all<<<B1end + nb0, 256, 0, stream>>>(ps[1], dst[1], E2, hist2, ideg2, ps[2], dst[2], E3,
                                              hist3, ideg3, ps[3], dst[3], E4, hist4, ideg4,
                                              ps[4], dst[4], E5, hist5, ideg5, dst[0], E1, ideg1,
                                              x0, cl[0], 80000, xp1m, B2, B23, B234, B2345,
                                              B1end);

    // ---- 3. claims + bin prefixes ----
    int nc1 = (N1 + 255) / 256, nc2 = (N2 + 255) / 256, nc3 = (N3 + 255) / 256,
        nc4 = (N4 + 255) / 256, nc5 = (N5 + 255) / 256;
    int C1 = nc1, C12 = C1 + nc2, C123 = C12 + nc3, C1234 = C123 + nc4, C12345 = C1234 + nc5;
    claim_all<<<C12345 + 4, 256, 0, stream>>>(
        ideg1, N1, gcur + 0, eb1, ecur1, ideg2, N2, gcur + 1, eb2, entc2, ideg3, N3, gcur + 2,
        eb3, entc3, ideg4, N4, gcur + 3, eb4, entc4, ideg5, N5, gcur + 4, eb5, entc5, hist2, bs2,
        cu2, tk2, tl2, nt2, hist3, bs3, cu3, tk3, tl3, nt3, hist4, bs4, cu4, tk4, tl4, nt4,
        hist5, bs5, cu5, tk5, tl5, nt5, C1, C12, C123, C1234, C12345);

    // ---- 4. all scatters in one dispatch ----
    int A1 = nb1, A12 = A1 + nb2, A123 = A12 + nb3, A1234 = A123 + nb4;
    scatter_all<<<A1234 + nb5, 256, 0, stream>>>(
        dst[0], src[0], ps[0], E1, ecur1, psrc, ps[1], src[1], dst[1], E2, cu2, entc2, rec2, sq2,
        ps[2], src[2], dst[2], E3, cu3, entc3, rec3, sq3, ps[3], src[3], dst[3], E4, cu4, entc4,
        rec4, sq4, ps[4], src[4], dst[4], E5, cu5, entc5, rec5, sq5, A1, A12, A123, A1234);

    // ---- level 1 ----
    l1_aggregate<<<2048, 256, 0, stream>>>(xp1m, psrc, W[0], eb1, ideg1, root[0], bias[0], cl[1],
                                           xp2m, N1);
    // ---- level 2: Cin32 Cout64 ----
    bin_gemm_cell<32, 64, 64, 64, 8><<<(UB2 < 2048 ? UB2 : 2048), 256, 0, stream>>>(
        xp2m, W[1], 0, rec2, sq2, tk2, tl2, bs2, nt2, msgs);
    agg_finish<32, 64, 64><<<(N2 + 3) / 4, 256, 0, stream>>>(msgs, eb2, ideg2, xp2m, root[1],
                                                             bias[1], cl[2], xp3m, N2, 0);
    // ---- level 3: Cin64 Cout64 ----
    bin_gemm_cell<64, 64, 64, 32, 4><<<(UB3 < 2048 ? UB3 : 2048), 256, 0, stream>>>(
        xp3m, W[2], 0, rec3, sq3, tk3, tl3, bs3, nt3, msgs);
    agg_finish<64, 64, 64><<<(N3 + 3) / 4, 256, 0, stream>>>(msgs, eb3, ideg3, xp3m, root[2],
                                                             bias[2], cl[3], xp4m, N3, 0);
    // ---- level 4: Cin64 Cout64 ----
    bin_gemm_cell<64, 64, 64, 32, 4><<<(UB4 < 2048 ? UB4 : 2048), 256, 0, stream>>>(
        xp4m, W[3], 0, rec4, sq4, tk4, tl4, bs4, nt4, msgs);
    agg_finish<64, 64, 64><<<(N4 + 3) / 4, 256, 0, stream>>>(msgs, eb4, ideg4, xp4m, root[3],
                                                             bias[3], cl[4], xp5m, N4, 0);
    // ---- level 5: Cin64 Cout128 ----
    bin_gemm_cell<64, 128, 128, 32, 2><<<(UB5 < 2048 ? UB5 : 2048), 256, 0, stream>>>(
        xp5m, W[4], 0, rec5, sq5, tk5, tl5, bs5, nt5, msgs);
    agg_finish<64, 128, 128><<<(N5 + 3) / 4, 256, 0, stream>>>(msgs, eb5, ideg5, xp5m, root[4],
                                                               bias[4], cl[5], xp6m, N5, 0);
    // ---- FC head ----
    fc1_kernel<<<8, 256, 0, stream>>>(xp6m, fc1_w, fc1_b, fc1o);
    fc2_lsm<<<1, 512, 0, stream>>>(fc1o, fc2_w, fc2_b, (float*)d_out);
}

// Round 9
// 259.052 us; speedup vs baseline: 2.4568x; 1.0780x over previous
//
#include <hip/hip_runtime.h>
#include <hip/hip_fp16.h>
#include <math.h>

#define DEVINL __device__ __forceinline__

// ---------------------------------------------------------------------------
// SplineCNN net, round 8: occupancy fix for cell-binned GEMM.
//  - W staged in LDS as fp16 (+convert on read) and Cout-sliced tiles (slice
//    folded into tile index): LDS 76KB -> 21-36KB, 2 -> 4-5 blocks/CU.
//  - L3/L4 tiles widened to TM=64 (8-matrix W stage amortized over 2x edges).
//  - everything else as round 7.
// ---------------------------------------------------------------------------

DEVINL unsigned f2mono(float f) {
    unsigned u = __float_as_uint(f);
    return (u & 0x80000000u) ? ~u : (u | 0x80000000u);
}
DEVINL float mono2x(unsigned m) {  // sentinel 0 == empty segment -> 0.0
    if (m == 0u) return 0.f;
    unsigned u = (m & 0x80000000u) ? (m & 0x7FFFFFFFu) : ~m;
    return __uint_as_float(u);
}
DEVINL unsigned short f2h(float f) {
    union { __half h; unsigned short u; } c;
    c.h = __float2half_rn(f);
    return c.u;
}
DEVINL float h2f(unsigned short s) {
    union { unsigned short u; __half h; } c;
    c.u = s;
    return __half2float(c.h);
}

__global__ void fill_u32(unsigned* __restrict__ p, int n, unsigned v) {
    int i = blockIdx.x * blockDim.x + threadIdx.x;
    if (i < n) p[i] = v;
}

DEVINL void decode3(float p0, float p1, float p2, int ff[3], float fr[3]) {
    float pp[3] = {p0 * 4.f, p1 * 4.f, p2 * 4.f};  // (K-1) = 4
#pragma unroll
    for (int d = 0; d < 3; ++d) {
        int fi = (int)floorf(pp[d]);
        fi = fi < 0 ? 0 : (fi > 4 ? 4 : fi);
        ff[d] = fi;
        fr[d] = pp[d] - (float)fi;
    }
}
DEVINL void pseudo_decode(const float* __restrict__ ps, int e, int ff[3], float fr[3]) {
    decode3(ps[(size_t)e * 3], ps[(size_t)e * 3 + 1], ps[(size_t)e * 3 + 2], ff, fr);
}

DEVINL void corner_iw(const int ff[3], const float fr[3], int bits, float& w, int& idx) {
    w = 1.f;
    idx = 0;
    int pw = 1;
#pragma unroll
    for (int d = 0; d < 3; ++d) {
        int b = (bits >> d) & 1;
        w *= b ? fr[d] : (1.f - fr[d]);
        int fd = ff[d] + b;
        fd = fd < 0 ? 0 : (fd > 4 ? 4 : fd);
        idx += fd * pw;
        pw *= 5;
    }
}

// ---------------- batched hist (cell id, L2-5) + deg (all) + pool0 -----------
DEVINL void hist_seg(const float* __restrict__ ps, const int* __restrict__ dst, int E,
                     int* __restrict__ hist, int* __restrict__ ideg, int bofs, int t,
                     int* __restrict__ lh) {
    for (int i = t; i < 125; i += 256) lh[i] = 0;
    __syncthreads();
    int e = bofs * 256 + t;
    if (e < E) {
        int ff[3];
        float fr[3];
        pseudo_decode(ps, e, ff, fr);
        int cid = ff[0] + 5 * ff[1] + 25 * ff[2];
        atomicAdd(&lh[cid], 1);
        atomicAdd(&ideg[dst[e]], 1);
    }
    __syncthreads();
    for (int i = t; i < 125; i += 256)
        if (lh[i]) atomicAdd(&hist[i], lh[i]);
}

__global__ void hist_all(const float* ps2, const int* dst2, int E2, int* hist2, int* ideg2,
                         const float* ps3, const int* dst3, int E3, int* hist3, int* ideg3,
                         const float* ps4, const int* dst4, int E4, int* hist4, int* ideg4,
                         const float* ps5, const int* dst5, int E5, int* hist5, int* ideg5,
                         const int* dst1, int E1, int* ideg1, const float* x0, const int* cl1,
                         int n0, unsigned* xp1m, int B2, int B23, int B234, int B2345,
                         int B1end) {
    __shared__ int lh[125];
    int b = blockIdx.x, t = threadIdx.x;
    if (b < B2) hist_seg(ps2, dst2, E2, hist2, ideg2, b, t, lh);
    else if (b < B23) hist_seg(ps3, dst3, E3, hist3, ideg3, b - B2, t, lh);
    else if (b < B234) hist_seg(ps4, dst4, E4, hist4, ideg4, b - B23, t, lh);
    else if (b < B2345) hist_seg(ps5, dst5, E5, hist5, ideg5, b - B234, t, lh);
    else if (b < B1end) {
        int e = (b - B2345) * 256 + t;
        if (e < E1) atomicAdd(&ideg1[dst1[e]], 1);
    } else {
        int i = (b - B1end) * 256 + t;
        if (i < n0) atomicMax(&xp1m[cl1[i]], f2mono(x0[i]));
    }
}

// ---------------- claims + bin-prefixes (wave-parallel) ----------------------
DEVINL void claim_seg(const int* __restrict__ cnt, int N, int* __restrict__ gcur,
                      int* __restrict__ ebase, int* __restrict__ cur, int bofs, int t) {
    int i = bofs * 256 + t;
    int lane = t & 63;
    int v = (i < N) ? cnt[i] : 0;
    int s = v;
#pragma unroll
    for (int st = 1; st < 64; st <<= 1) {
        int u = __shfl_up(s, st);
        if (lane >= st) s += u;
    }
    int wtot = __shfl(s, 63);
    int base = 0;
    if (lane == 0 && wtot > 0) base = atomicAdd(gcur, wtot);
    base = __shfl(base, 0);
    int start = base + s - v;
    if (i < N) {
        ebase[i] = start;
        cur[i] = start;
    }
}

__global__ void claim_all(const int* ideg1, int N1, int* g1, int* eb1, int* cur1,
                          const int* ideg2, int N2, int* g2, int* eb2, int* cur2,
                          const int* ideg3, int N3, int* g3, int* eb3, int* cur3,
                          const int* ideg4, int N4, int* g4, int* eb4, int* cur4,
                          const int* ideg5, int N5, int* g5, int* eb5, int* cur5,
                          const int* h2, int* bs2, int* cu2, int* tk2, int* tl2, int* nt2,
                          const int* h3, int* bs3, int* cu3, int* tk3, int* tl3, int* nt3,
                          const int* h4, int* bs4, int* cu4, int* tk4, int* tl4, int* nt4,
                          const int* h5, int* bs5, int* cu5, int* tk5, int* tl5, int* nt5,
                          int C1, int C12, int C123, int C1234, int C12345) {
    int b = blockIdx.x, t = threadIdx.x;
    if (b < C1) { claim_seg(ideg1, N1, g1, eb1, cur1, b, t); return; }
    if (b < C12) { claim_seg(ideg2, N2, g2, eb2, cur2, b - C1, t); return; }
    if (b < C123) { claim_seg(ideg3, N3, g3, eb3, cur3, b - C12, t); return; }
    if (b < C1234) { claim_seg(ideg4, N4, g4, eb4, cur4, b - C123, t); return; }
    if (b < C12345) { claim_seg(ideg5, N5, g5, eb5, cur5, b - C1234, t); return; }
    int s = b - C12345;
    const int* hist;
    int *bs, *cu, *tk, *tl, *ntp;
    int TMv = (s == 3) ? 32 : 64;  // L2/L3/L4 TM=64, L5 TM=32
    if (s == 0) { hist = h2; bs = bs2; cu = cu2; tk = tk2; tl = tl2; ntp = nt2; }
    else if (s == 1) { hist = h3; bs = bs3; cu = cu3; tk = tk3; tl = tl3; ntp = nt3; }
    else if (s == 2) { hist = h4; bs = bs4; cu = cu4; tk = tk4; tl = tl4; ntp = nt4; }
    else { hist = h5; bs = bs5; cu = cu5; tk = tk5; tl = tl5; ntp = nt5; }
    int lane = t & 63, wv = t >> 6;
    int h = 0, th = 0;
    if (t < 125) {
        h = hist[t];
        th = (h + TMv - 1) / TMv;
    }
    unsigned long long v = (unsigned long long)(unsigned)h |
                           ((unsigned long long)(unsigned)th << 32);
#pragma unroll
    for (int st = 1; st < 64; st <<= 1) {
        unsigned long long u = __shfl_up(v, st);
        if (lane >= st) v += u;
    }
    __shared__ unsigned long long wtot[4];
    if (lane == 63) wtot[wv] = v;
    __syncthreads();
    unsigned long long woff = 0;
    for (int w2 = 0; w2 < wv; ++w2) woff += wtot[w2];
    unsigned long long incl = v + woff;
    int eh = (int)(incl & 0xFFFFFFFFull) - h;
    int eth = (int)(incl >> 32) - th;
    if (t < 125) {
        bs[t] = eh;
        cu[t] = eh;
        for (int j = 0; j < th; ++j) {
            tk[eth + j] = t;
            tl[eth + j] = eh + TMv * j;
        }
    }
    if (t == 124) {
        bs[125] = eh + h;
        *ntp = eth + th;
    }
}

// ---------------- batched scatter: L1 payloads + L2-5 edge records -----------
DEVINL void scat_seg(const float* __restrict__ ps, const int* __restrict__ src,
                     const int* __restrict__ dst, int E, int* __restrict__ cursor,
                     int* __restrict__ entcur, uint4* __restrict__ rec, int* __restrict__ sq,
                     int bofs, int t, int* __restrict__ lh, int* __restrict__ lbase) {
    for (int i = t; i < 125; i += 256) lh[i] = 0;
    __syncthreads();
    int e = bofs * 256 + t;
    int cid = 0, ml = 0;
    int ff[3];
    float fr[3];
    if (e < E) {
        pseudo_decode(ps, e, ff, fr);
        cid = ff[0] + 5 * ff[1] + 25 * ff[2];
        ml = atomicAdd(&lh[cid], 1);
    }
    __syncthreads();
    for (int i = t; i < 125; i += 256) {
        int c = lh[i];
        lbase[i] = c ? atomicAdd(&cursor[i], c) : 0;
    }
    __syncthreads();
    if (e < E) {
        int p = lbase[cid] + ml;
        int q = atomicAdd(&entcur[dst[e]], 1);
        uint4 v;
        v.x = (unsigned)src[e];
        v.y = __float_as_uint(fr[0]);
        v.z = __float_as_uint(fr[1]);
        v.w = __float_as_uint(fr[2]);
        rec[p] = v;
        sq[p] = q;
    }
}

__global__ void scatter_all(
    const int* dst1, const int* src1, const float* ps1, int E1, int* ecur1, uint4* psrc,
    const float* ps2, const int* src2, const int* dst2, int E2, int* cu2, int* entc2,
    uint4* rec2, int* sq2, const float* ps3, const int* src3, const int* dst3, int E3, int* cu3,
    int* entc3, uint4* rec3, int* sq3, const float* ps4, const int* src4, const int* dst4,
    int E4, int* cu4, int* entc4, uint4* rec4, int* sq4, const float* ps5, const int* src5,
    const int* dst5, int E5, int* cu5, int* entc5, uint4* rec5, int* sq5, int A1, int A12,
    int A123, int A1234) {
    __shared__ int lh[125], lbase[125];
    int b = blockIdx.x, t = threadIdx.x;
    if (b < A1) {
        int e = b * 256 + t;
        if (e < E1) {
            int q = atomicAdd(&ecur1[dst1[e]], 1);
            uint4 v;
            v.x = __float_as_uint(ps1[(size_t)e * 3 + 0]);
            v.y = __float_as_uint(ps1[(size_t)e * 3 + 1]);
            v.z = __float_as_uint(ps1[(size_t)e * 3 + 2]);
            v.w = (unsigned)src1[e];
            psrc[q] = v;
        }
    } else if (b < A12)
        scat_seg(ps2, src2, dst2, E2, cu2, entc2, rec2, sq2, b - A1, t, lh, lbase);
    else if (b < A123)
        scat_seg(ps3, src3, dst3, E3, cu3, entc3, rec3, sq3, b - A12, t, lh, lbase);
    else if (b < A1234)
        scat_seg(ps4, src4, dst4, E4, cu4, entc4, rec4, sq4, b - A123, t, lh, lbase);
    else
        scat_seg(ps5, src5, dst5, E5, cu5, entc5, rec5, sq5, b - A1234, t, lh, lbase);
}

// cell-binned GEMM, Cout-sliced: tile tt -> (slice c0, cell tile). 8 W-slices
// staged in LDS as FP16 (BPASS at a time); per edge msg = sum_b w_b(x@W_kb),
// fp16 S-wide row chunk scatter-written to dst-claimed position sq[p].
template <int CIN, int COUT, int S, int TM, int BPASS>
__global__ __launch_bounds__(256) void bin_gemm_cell(
    const unsigned* __restrict__ xm, const float* __restrict__ W, const uint4* __restrict__ rec,
    const int* __restrict__ sq, const int* __restrict__ tk, const int* __restrict__ tl,
    const int* __restrict__ bs, const int* __restrict__ ntp, unsigned* __restrict__ msgs) {
    constexpr int C4 = S / 4;        // uint2 (4 fp16 cols) groups
    constexpr int NTR = 256 / C4;
    constexpr int RT = TM / NTR;     // rows per thread (2 in all configs)
    constexpr int XTT = TM + 2;
    constexpr int NPASS = 8 / BPASS;
    constexpr int G = 256 / TM;
    __shared__ unsigned Wl[BPASS * CIN * C4 * 2];  // fp16 pairs
    __shared__ float xs_t[CIN * XTT];
    __shared__ float ws[TM * 8];
    __shared__ int kbs[8];
    int t = threadIdx.x;
    int ntiles = *ntp;
    int ntot = ntiles * (COUT / S);
    int tc = t % C4, tr = t / C4;
    int rr = t / G, g = t % G;
    int row0 = tr * RT;
    uint2* Wl2 = (uint2*)Wl;
    for (int tt = blockIdx.x; tt < ntot; tt += gridDim.x) {
        int sl = tt / ntiles;
        int tile = tt - sl * ntiles;
        int c0 = sl * S;
        int cell = tk[tile], lo = tl[tile];
        int m = min(TM, bs[cell + 1] - lo);
        __syncthreads();  // previous tile's readers done
        if (t < 8) {
            int f0 = cell % 5, f1 = (cell / 5) % 5, f2 = cell / 25;
            int k0 = min(f0 + (t & 1), 4), k1 = min(f1 + ((t >> 1) & 1), 4),
                k2 = min(f2 + (t >> 2), 4);
            kbs[t] = k0 + 5 * k1 + 25 * k2;
        }
        if (rr < m) {
            uint4 rv = rec[lo + rr];
            if (g == 0) {
                float fr0 = __uint_as_float(rv.y), fr1 = __uint_as_float(rv.z),
                      fr2 = __uint_as_float(rv.w);
#pragma unroll
                for (int b = 0; b < 8; ++b)
                    ws[rr * 8 + b] = ((b & 1) ? fr0 : 1.f - fr0) * ((b & 2) ? fr1 : 1.f - fr1) *
                                     ((b & 4) ? fr2 : 1.f - fr2);
            }
            const uint4* xr = (const uint4*)(xm + (size_t)rv.x * CIN);
            for (int i = g; i < CIN / 4; i += G) {
                uint4 mv = xr[i];
                xs_t[(4 * i + 0) * XTT + rr] = mono2x(mv.x);
                xs_t[(4 * i + 1) * XTT + rr] = mono2x(mv.y);
                xs_t[(4 * i + 2) * XTT + rr] = mono2x(mv.z);
                xs_t[(4 * i + 3) * XTT + rr] = mono2x(mv.w);
            }
        } else if (g == 0) {
#pragma unroll
            for (int b = 0; b < 8; ++b) ws[rr * 8 + b] = 0.f;
        }
        float4 acc[RT];
#pragma unroll
        for (int r = 0; r < RT; ++r) acc[r] = make_float4(0.f, 0.f, 0.f, 0.f);
        for (int pass = 0; pass < NPASS; ++pass) {
            __syncthreads();  // staging done (pass0) / prev-pass Wl reads done
            for (int i2 = t; i2 < BPASS * CIN * C4; i2 += 256) {
                int b = i2 / (CIN * C4);
                int rem = i2 - b * (CIN * C4);
                int rw = rem / C4, cg = rem - rw * C4;
                float4 wv = ((const float4*)(W + (size_t)kbs[pass * BPASS + b] * CIN * COUT +
                                             (size_t)rw * COUT + c0))[cg];
                uint2 pk;
                pk.x = (unsigned)f2h(wv.x) | ((unsigned)f2h(wv.y) << 16);
                pk.y = (unsigned)f2h(wv.z) | ((unsigned)f2h(wv.w) << 16);
                Wl2[i2] = pk;
            }
            __syncthreads();
            float wsr[BPASS][RT];
#pragma unroll
            for (int b = 0; b < BPASS; ++b)
#pragma unroll
                for (int r = 0; r < RT; ++r) wsr[b][r] = ws[(row0 + r) * 8 + pass * BPASS + b];
#pragma unroll 4
            for (int i = 0; i < CIN; ++i) {
                float2 xv = *(const float2*)&xs_t[i * XTT + row0];
                float xf[RT];
                xf[0] = xv.x;
                if constexpr (RT == 2) xf[1] = xv.y;
#pragma unroll
                for (int b = 0; b < BPASS; ++b) {
                    uint2 pk = Wl2[(b * CIN + i) * C4 + tc];
                    float4 wv;
                    wv.x = h2f((unsigned short)(pk.x & 0xFFFFu));
                    wv.y = h2f((unsigned short)(pk.x >> 16));
                    wv.z = h2f((unsigned short)(pk.y & 0xFFFFu));
                    wv.w = h2f((unsigned short)(pk.y >> 16));
#pragma unroll
                    for (int r = 0; r < RT; ++r) {
                        float mm = wsr[b][r] * xf[r];
                        acc[r].x += mm * wv.x;
                        acc[r].y += mm * wv.y;
                        acc[r].z += mm * wv.z;
                        acc[r].w += mm * wv.w;
                    }
                }
            }
        }
#pragma unroll
        for (int r = 0; r < RT; ++r) {
            int row = row0 + r;
            if (row < m) {
                int q = sq[lo + row];
                uint2 pv;
                pv.x = (unsigned)f2h(acc[r].x) | ((unsigned)f2h(acc[r].y) << 16);
                pv.y = (unsigned)f2h(acc[r].z) | ((unsigned)f2h(acc[r].w) << 16);
                ((uint2*)(msgs + (size_t)q * (COUT / 2)))[c0 / 4 + tc] = pv;
            }
        }
    }
}

// wave per node: contiguous claimed-range message stream (1 row per EDGE),
// butterfly reduce, deg-norm + root + bias + ELU, pool into next mono buffer.
template <int CIN, int COUT, int S>
__global__ __launch_bounds__(256) void agg_finish(
    const unsigned* __restrict__ msgsU, const int* __restrict__ ebase,
    const int* __restrict__ ideg, const unsigned* __restrict__ xm,
    const float* __restrict__ root, const float* __restrict__ bias,
    const int* __restrict__ clnext, unsigned* __restrict__ xnext, int N, int c0) {
    const unsigned short* msgs = (const unsigned short*)msgsU;
    constexpr int WPC = S / 4;
    constexpr int G = 64 / WPC;
    int t = threadIdx.x;
    int lane = t & 63;
    int wid = blockIdx.x * 4 + (t >> 6);
    int nw = gridDim.x * 4;
    int grp = lane & (WPC - 1);
    int sub = lane / WPC;
    for (int d = wid; d < N; d += nw) {
        int lo = ebase[d];
        int len = ideg[d];
        float dv = (float)max(len, 1);
        float4 acc = make_float4(0.f, 0.f, 0.f, 0.f);
        const float* rbase = root + c0 + 4 * grp;
        for (int i = sub; i < CIN; i += G) {
            float xv = mono2x(xm[(size_t)d * CIN + i]) * dv;
            const float* rp = rbase + (size_t)i * COUT;
            acc.x += xv * rp[0];
            acc.y += xv * rp[1];
            acc.z += xv * rp[2];
            acc.w += xv * rp[3];
        }
        size_t h1 = (size_t)(lo + len) * S;
        for (size_t h = (size_t)lo * S + (size_t)lane * 4; h < h1; h += 256) {
            uint2 u = *(const uint2*)(msgs + h);
            acc.x += h2f((unsigned short)(u.x & 0xFFFFu));
            acc.y += h2f((unsigned short)(u.x >> 16));
            acc.z += h2f((unsigned short)(u.y & 0xFFFFu));
            acc.w += h2f((unsigned short)(u.y >> 16));
        }
#pragma unroll
        for (int s = WPC; s < 64; s <<= 1) {
            acc.x += __shfl_xor(acc.x, s);
            acc.y += __shfl_xor(acc.y, s);
            acc.z += __shfl_xor(acc.z, s);
            acc.w += __shfl_xor(acc.w, s);
        }
        if (lane < WPC) {
            const float* bp = bias + c0 + 4 * grp;
            float4 v;
            v.x = acc.x / dv + bp[0];
            v.y = acc.y / dv + bp[1];
            v.z = acc.z / dv + bp[2];
            v.w = acc.w / dv + bp[3];
            v.x = v.x > 0.f ? v.x : expm1f(v.x);
            v.y = v.y > 0.f ? v.y : expm1f(v.y);
            v.z = v.z > 0.f ? v.z : expm1f(v.z);
            v.w = v.w > 0.f ? v.w : expm1f(v.w);
            unsigned* xp = xnext + (size_t)clnext[d] * COUT + c0 + 4 * grp;
            atomicMax(&xp[0], f2mono(v.x));
            atomicMax(&xp[1], f2mono(v.y));
            atomicMax(&xp[2], f2mono(v.z));
            atomicMax(&xp[3], f2mono(v.w));
        }
    }
}

// ---------------- level 1 (Cin=1, Cout=32): fused conv + pool into xp2m -------
__global__ __launch_bounds__(256) void l1_aggregate(
    const unsigned* __restrict__ xm, const uint4* __restrict__ psrc,
    const float* __restrict__ W, const int* __restrict__ ebase, const int* __restrict__ ideg,
    const float* __restrict__ root, const float* __restrict__ bias,
    const int* __restrict__ cl2, unsigned* __restrict__ xp2m, int N) {
    __shared__ float Wl[125 * 32];
    int t = threadIdx.x;
    {
        const float4* Wg = (const float4*)W;
        float4* Wd = (float4*)Wl;
        for (int i = t; i < 125 * 32 / 4; i += 256) Wd[i] = Wg[i];
    }
    __syncthreads();
    int lane = t & 63, c = lane & 31, half = lane >> 5;
    int wid = blockIdx.x * 4 + (t >> 6);
    int nw = gridDim.x * 4;
    for (int d = wid; d < N; d += nw) {
        int lo = ebase[d], hi = lo + ideg[d];
        float acc = 0.f;
        for (int j = lo + half; j < hi; j += 2) {
            uint4 pv = psrc[j];
            int ff[3];
            float fr[3];
            decode3(__uint_as_float(pv.x), __uint_as_float(pv.y), __uint_as_float(pv.z), ff, fr);
            float wsum = 0.f;
#pragma unroll
            for (int b = 0; b < 8; ++b) {
                float w;
                int idx;
                corner_iw(ff, fr, b, w, idx);
                wsum += w * Wl[idx * 32 + c];
            }
            acc += mono2x(xm[pv.w]) * wsum;
        }
        acc += __shfl_down(acc, 32);
        if (half == 0) {
            float dv = (float)max(hi - lo, 1);
            float v = acc / dv + mono2x(xm[d]) * root[c] + bias[c];
            v = v > 0.f ? v : expm1f(v);
            atomicMax(&xp2m[(size_t)cl2[d] * 32 + c], f2mono(v));
        }
    }
}

// fc1: [1024] @ [1024,512] + b, ELU — K-split across 8 blocks x 256 threads
__global__ __launch_bounds__(256) void fc1_kernel(const unsigned* __restrict__ xm,
                                                  const float* __restrict__ w,
                                                  const float* __restrict__ b,
                                                  float* __restrict__ out) {
    __shared__ float xsh[1024];
    __shared__ float sh[4][64];
    int t = threadIdx.x;
    for (int i = t; i < 1024; i += 256) xsh[i] = mono2x(xm[i]);
    __syncthreads();
    int ol = t & 63, kk = t >> 6;
    int o = blockIdx.x * 64 + ol;
    int i0 = kk * 256;
    float acc = 0.f;
#pragma unroll 8
    for (int i = 0; i < 256; ++i) acc += xsh[i0 + i] * w[(size_t)(i0 + i) * 512 + o];
    sh[kk][ol] = acc;
    __syncthreads();
    if (kk == 0) {
        float v = sh[0][ol] + sh[1][ol] + sh[2][ol] + sh[3][ol] + b[o];
        out[o] = v > 0.f ? v : expm1f(v);
    }
}

// fc2 (512->10) + log_softmax, parallel: thread i owns row i
__global__ __launch_bounds__(512) void fc2_lsm(const float* __restrict__ x,
                                               const float* __restrict__ w,
                                               const float* __restrict__ b,
                                               float* __restrict__ out) {
    __shared__ float red[8][10];
    int t = threadIdx.x, lane = t & 63, wv = t >> 6;
    float xv = x[t];
    const float* wr = w + (size_t)t * 10;
    float acc[10];
#pragma unroll
    for (int c = 0; c < 10; ++c) acc[c] = xv * wr[c];
#pragma unroll
    for (int s = 32; s > 0; s >>= 1) {
#pragma unroll
        for (int c = 0; c < 10; ++c) acc[c] += __shfl_down(acc[c], s);
    }
    if (lane == 0) {
#pragma unroll
        for (int c = 0; c < 10; ++c) red[wv][c] = acc[c];
    }
    __syncthreads();
    if (t == 0) {
        float z[10];
        for (int c = 0; c < 10; ++c) {
            float s2 = b[c];
            for (int w2 = 0; w2 < 8; ++w2) s2 += red[w2][c];
            z[c] = s2;
        }
        float m = z[0];
        for (int i = 1; i < 10; ++i) m = fmaxf(m, z[i]);
        float s2 = 0.f;
        for (int i = 0; i < 10; ++i) s2 += expf(z[i] - m);
        float l = logf(s2);
        for (int i = 0; i < 10; ++i) out[i] = z[i] - m - l;
    }
}

// ---------------------------------------------------------------------------

extern "C" void kernel_launch(void* const* d_in, const int* in_sizes, int n_in,
                              void* d_out, int out_size, void* d_ws, size_t ws_size,
                              hipStream_t stream) {
    (void)in_sizes; (void)n_in; (void)out_size; (void)ws_size;
    const float* x0 = (const float*)d_in[0];
    const int* cl[6];
    for (int i = 0; i < 6; ++i) cl[i] = (const int*)d_in[1 + i];
    const int* src[5];
    const int* dst[5];
    const float* ps[5];
    const float* W[5];
    const float* root[5];
    const float* bias[5];
    for (int i = 0; i < 5; ++i) {
        src[i] = (const int*)d_in[7 + 6 * i];
        dst[i] = (const int*)d_in[8 + 6 * i];
        ps[i] = (const float*)d_in[9 + 6 * i];
        W[i] = (const float*)d_in[10 + 6 * i];
        root[i] = (const float*)d_in[11 + 6 * i];
        bias[i] = (const float*)d_in[12 + 6 * i];
    }
    const float* fc1_w = (const float*)d_in[37];
    const float* fc1_b = (const float*)d_in[38];
    const float* fc2_w = (const float*)d_in[39];
    const float* fc2_b = (const float*)d_in[40];

    const int N1 = 20000, N2 = 6000, N3 = 2000, N4 = 700, N5 = 256;
    const int E1 = 160000, E2 = 48000, E3 = 16000, E4 = 5600, E5 = 2048;
    const int UB2 = E2 / 64 + 126, UB3 = E3 / 64 + 126, UB4 = E4 / 64 + 126,
              UB5 = E5 / 32 + 126;

    unsigned* base = (unsigned*)d_ws;
    size_t o = 0;
    auto alloc = [&](size_t n) { unsigned* p = base + o; o += n; return p; };
    // ---- zero block (single fill) ----
    unsigned* xp1m = alloc(N1);
    unsigned* xp2m = alloc((size_t)N2 * 32);
    unsigned* xp3m = alloc((size_t)N3 * 64);
    unsigned* xp4m = alloc((size_t)N4 * 64);
    unsigned* xp5m = alloc((size_t)N5 * 64);
    unsigned* xp6m = alloc(8 * 128);
    int* hist2 = (int*)alloc(125);
    int* hist3 = (int*)alloc(125);
    int* hist4 = (int*)alloc(125);
    int* hist5 = (int*)alloc(125);
    int* ideg1 = (int*)alloc(N1);
    int* ideg2 = (int*)alloc(N2);
    int* ideg3 = (int*)alloc(N3);
    int* ideg4 = (int*)alloc(N4);
    int* ideg5 = (int*)alloc(N5);
    int* gcur = (int*)alloc(5);
    size_t zero_words = o;
    // ---- non-zeroed dedicated ----
    int* eb1 = (int*)alloc(N1);
    int* eb2 = (int*)alloc(N2);
    int* eb3 = (int*)alloc(N3);
    int* eb4 = (int*)alloc(N4);
    int* eb5 = (int*)alloc(N5);
    int* ecur1 = (int*)alloc(N1);
    int* entc2 = (int*)alloc(N2);
    int* entc3 = (int*)alloc(N3);
    int* entc4 = (int*)alloc(N4);
    int* entc5 = (int*)alloc(N5);
    int* bs2 = (int*)alloc(126);
    int* bs3 = (int*)alloc(126);
    int* bs4 = (int*)alloc(126);
    int* bs5 = (int*)alloc(126);
    int* cu2 = (int*)alloc(125);
    int* cu3 = (int*)alloc(125);
    int* cu4 = (int*)alloc(125);
    int* cu5 = (int*)alloc(125);
    int* nt2 = (int*)alloc(1);
    int* nt3 = (int*)alloc(1);
    int* nt4 = (int*)alloc(1);
    int* nt5 = (int*)alloc(1);
    int* tk2 = (int*)alloc(UB2);
    int* tl2 = (int*)alloc(UB2);
    int* tk3 = (int*)alloc(UB3);
    int* tl3 = (int*)alloc(UB3);
    int* tk4 = (int*)alloc(UB4);
    int* tl4 = (int*)alloc(UB4);
    int* tk5 = (int*)alloc(UB5);
    int* tl5 = (int*)alloc(UB5);
    float* fc1o = (float*)alloc(512);
    o = (o + 3) & ~(size_t)3;  // 16B-align the uint4 region
    uint4* rec2 = (uint4*)alloc((size_t)4 * E2);
    int* sq2 = (int*)alloc(E2);
    uint4* rec3 = (uint4*)alloc((size_t)4 * E3);
    int* sq3 = (int*)alloc(E3);
    uint4* rec4 = (uint4*)alloc((size_t)4 * E4);
    int* sq4 = (int*)alloc(E4);
    uint4* rec5 = (uint4*)alloc((size_t)4 * E5);
    int* sq5 = (int*)alloc(E5);
    uint4* psrc = (uint4*)alloc((size_t)4 * E1);
    unsigned* msgs = alloc((size_t)E2 * 32);  // max of E_L * COUT/2 across levels

    // ---- 1. one fill for monos + hists + idegs + cursors ----
    fill_u32<<<((int)zero_words + 255) / 256, 256, 0, stream>>>(base, (int)zero_words, 0u);

    // ---- 2. batched hist/deg + pool0 ----
    int nb2 = (E2 + 255) / 256, nb3 = (E3 + 255) / 256, nb4 = (E4 + 255) / 256,
        nb5 = (E5 + 255) / 256, nb1 = (E1 + 255) / 256, nb0 = (80000 + 255) / 256;
    int B2 = nb2, B23 = B2 + nb3, B234 = B23 + nb4, B2345 = B234 + nb5;
    int B1end = B2345 + nb1;
    hist_all<<<B1end + nb0, 256, 0, stream>>>(ps[1], dst[1], E2, hist2, ideg2, ps[2], dst[2], E3,
                                              hist3, ideg3, ps[3], dst[3], E4, hist4, ideg4,
                                              ps[4], dst[4], E5, hist5, ideg5, dst[0], E1, ideg1,
                                              x0, cl[0], 80000, xp1m, B2, B23, B234, B2345,
                                              B1end);

    // ---- 3. claims + bin prefixes ----
    int nc1 = (N1 + 255) / 256, nc2 = (N2 + 255) / 256, nc3 = (N3 + 255) / 256,
        nc4 = (N4 + 255) / 256, nc5 = (N5 + 255) / 256;
    int C1 = nc1, C12 = C1 + nc2, C123 = C12 + nc3, C1234 = C123 + nc4, C12345 = C1234 + nc5;
    claim_all<<<C12345 + 4, 256, 0, stream>>>(
        ideg1, N1, gcur + 0, eb1, ecur1, ideg2, N2, gcur + 1, eb2, entc2, ideg3, N3, gcur + 2,
        eb3, entc3, ideg4, N4, gcur + 3, eb4, entc4, ideg5, N5, gcur + 4, eb5, entc5, hist2, bs2,
        cu2, tk2, tl2, nt2, hist3, bs3, cu3, tk3, tl3, nt3, hist4, bs4, cu4, tk4, tl4, nt4,
        hist5, bs5, cu5, tk5, tl5, nt5, C1, C12, C123, C1234, C12345);

    // ---- 4. all scatters in one dispatch ----
    int A1 = nb1, A12 = A1 + nb2, A123 = A12 + nb3, A1234 = A123 + nb4;
    scatter_all<<<A1234 + nb5, 256, 0, stream>>>(
        dst[0], src[0], ps[0], E1, ecur1, psrc, ps[1], src[1], dst[1], E2, cu2, entc2, rec2, sq2,
        ps[2], src[2], dst[2], E3, cu3, entc3, rec3, sq3, ps[3], src[3], dst[3], E4, cu4, entc4,
        rec4, sq4, ps[4], src[4], dst[4], E5, cu5, entc5, rec5, sq5, A1, A12, A123, A1234);

    // ---- level 1 ----
    l1_aggregate<<<2048, 256, 0, stream>>>(xp1m, psrc, W[0], eb1, ideg1, root[0], bias[0], cl[1],
                                           xp2m, N1);
    // ---- level 2: Cin32 Cout64, S=32 slices ----
    bin_gemm_cell<32, 64, 32, 64, 8><<<2 * UB2, 256, 0, stream>>>(xp2m, W[1], rec2, sq2, tk2,
                                                                  tl2, bs2, nt2, msgs);
    agg_finish<32, 64, 64><<<(N2 + 3) / 4, 256, 0, stream>>>(msgs, eb2, ideg2, xp2m, root[1],
                                                             bias[1], cl[2], xp3m, N2, 0);
    // ---- level 3: Cin64 Cout64, S=32 slices ----
    bin_gemm_cell<64, 64, 32, 64, 4><<<2 * UB3, 256, 0, stream>>>(xp3m, W[2], rec3, sq3, tk3,
                                                                  tl3, bs3, nt3, msgs);
    agg_finish<64, 64, 64><<<(N3 + 3) / 4, 256, 0, stream>>>(msgs, eb3, ideg3, xp3m, root[2],
                                                             bias[2], cl[3], xp4m, N3, 0);
    // ---- level 4: Cin64 Cout64, S=32 slices ----
    bin_gemm_cell<64, 64, 32, 64, 4><<<2 * UB4, 256, 0, stream>>>(xp4m, W[3], rec4, sq4, tk4,
                                                                  tl4, bs4, nt4, msgs);
    agg_finish<64, 64, 64><<<(N4 + 3) / 4, 256, 0, stream>>>(msgs, eb4, ideg4, xp4m, root[3],
                                                             bias[3], cl[4], xp5m, N4, 0);
    // ---- level 5: Cin64 Cout128, S=64 slices ----
    bin_gemm_cell<64, 128, 64, 32, 2><<<2 * UB5, 256, 0, stream>>>(xp5m, W[4], rec5, sq5, tk5,
                                                                   tl5, bs5, nt5, msgs);
    agg_finish<64, 128, 128><<<(N5 + 3) / 4, 256, 0, stream>>>(msgs, eb5, ideg5, xp5m, root[4],
                                                               bias[4], cl[5], xp6m, N5, 0);
    // ---- FC head ----
    fc1_kernel<<<8, 256, 0, stream>>>(xp6m, fc1_w, fc1_b, fc1o);
    fc2_lsm<<<1, 512, 0, stream>>>(fc1o, fc2_w, fc2_b, (float*)d_out);
}